// Round 20
// 1045.252 us; speedup vs baseline: 1.8605x; 1.0006x over previous
//
#include <hip/hip_runtime.h>
#include <math.h>
#include <stdint.h>

#define LL 2
#define HH 4
#define DHH 64
#define DD 256
#define BB 8
#define NI 8192
#define ND 4096
#define NROW 12288
#define KPOOL 768
#define EC 65536
#define EI 32768
#define EO 32768
#define EK 8192
#define EHGT (EC+EI+EO+EK)

typedef unsigned short u16;
typedef short bf16x8 __attribute__((ext_vector_type(8)));
typedef float f32x4 __attribute__((ext_vector_type(4)));
typedef unsigned short u16x4 __attribute__((ext_vector_type(4)));

__device__ inline float gelu_f(float x){ return 0.5f*x*(1.f+erff(x*0.70710678118654752f)); }
__device__ inline u16 f2b(float x){ uint32_t u=__float_as_uint(x); return (u16)((u + 0x7fffu + ((u>>16)&1u))>>16); }
__device__ inline float b2f(u16 h){ return __uint_as_float(((uint32_t)h)<<16); }

// ---------------- generic fill ----------------
__global__ void fill_u32(uint32_t* p, uint32_t v, int n){
    int i = blockIdx.x*256 + threadIdx.x;
    if(i<n) p[i]=v;
}

// ---------------- activation split-convert ----------------
__global__ void cvt_split(const float* __restrict__ A, int nA, const float* __restrict__ B, int nB,
                          u16* __restrict__ oh, u16* __restrict__ ol){
    int i = (blockIdx.x*256 + threadIdx.x)*4;
    int tot = nA + nB;
    if(i >= tot) return;
    float4 v = (i < nA) ? *(const float4*)(A + i) : *(const float4*)(B + (i - nA));
    float vv[4] = {v.x, v.y, v.z, v.w};
    u16x4 h4, l4;
    #pragma unroll
    for(int j=0;j<4;j++){
        float x = vv[j];
        u16 h = f2b(x);
        h4[j] = h;
        l4[j] = f2b(x - b2f(h));
    }
    *(u16x4*)(oh + i) = h4;
    *(u16x4*)(ol + i) = l4;
}

// ---------------- weight transpose + split ----------------
struct WCArgs { const float* in[8]; u16* oh[8]; u16* ol[8]; int cnt[8]; int nr; };
__global__ void wcvt_split(WCArgs a){
    int mat = blockIdx.y, ri = 0;
    while(ri < a.nr-1 && mat >= a.cnt[ri]){ mat -= a.cnt[ri]; ri++; }
    const float* in = a.in[ri] + (size_t)mat*65536;
    u16* oh = a.oh[ri] + (size_t)mat*65536;
    u16* ol = a.ol[ri] + (size_t)mat*65536;
    int n = blockIdx.x, k = threadIdx.x;
    float x = in[(size_t)k*DD + n];
    u16 h = f2b(x);
    oh[n*DD + k] = h;
    ol[n*DD + k] = f2b(x - b2f(h));
}

// ---------------- MFMA batched GEMM with fused, LDS-restaged epilogues ----------------
// prec=0: split hi/lo (3 MFMA/step); prec=1: hi-only (1 MFMA/step, half staging)
// mode 0: C=f32   mode 1: Oh/Ol=split bf16   mode 4: Oh=plain bf16
// mode 2: Xacc = 0.5*(g*acc + (1-g)*X)
// mode 3: v=relu(Xacc + 0.5*(g*acc+(1-g)*X)); C=v; Oh/Ol=split(v)
struct GDesc { const u16* Ah; const u16* Al; const u16* Bh; const u16* Bl;
               float* C; u16* Oh; u16* Ol;
               const float* X; float* Xacc; const float* skipp;
               int mblks; int mode; int prec; };
struct GArgs { GDesc d[10]; int nd; };

__global__ __launch_bounds__(256) void gemm_mfma(GArgs ga){
    __shared__ u16 SBUF[2*128*64];
    char* Abuf = (char*)SBUF;
    char* Bbuf = (char*)(SBUF + 128*64);
    int mb = blockIdx.x, di = 0;
    while(di < ga.nd-1 && mb >= ga.d[di].mblks){ mb -= ga.d[di].mblks; di++; }
    GDesc g = ga.d[di];
    const int prec = g.prec;
    const int m0 = mb*128, n0 = blockIdx.y*128;
    const int tid = threadIdx.x;
    const int lane = tid & 63, wid = tid >> 6;
    const int wm = (wid>>1)*64, wn = (wid&1)*64;
    const int l15 = lane & 15, l4 = lane >> 4;
    const int srow = tid >> 1, hf = tid & 1;
    const int ssw = (srow&7)<<4;
    const int c0 = (hf*32) ^ ssw;
    const int c1 = (hf*32+16) ^ ssw;
    const int c2 = (64+hf*32) ^ ssw;
    const int c3 = (64+hf*32+16) ^ ssw;
    const int rbyte = srow*128;
    const u16* __restrict__ Aph = g.Ah + (size_t)(m0 + srow)*DD + hf*16;
    const u16* __restrict__ Apl = g.Al + (size_t)(m0 + srow)*DD + hf*16;
    const u16* __restrict__ Bph = g.Bh + (size_t)(n0 + srow)*DD + hf*16;
    const u16* __restrict__ Bpl = g.Bl + (size_t)(n0 + srow)*DD + hf*16;
    f32x4 acc[4][4] = {};
    bf16x8 r0, r1, r2, r3, r4, r5, r6, r7;
    r0 = *(const bf16x8*)(Aph);
    r1 = *(const bf16x8*)(Aph + 8);
    r4 = *(const bf16x8*)(Bph);
    r5 = *(const bf16x8*)(Bph + 8);
    if(!prec){
        r2 = *(const bf16x8*)(Apl);
        r3 = *(const bf16x8*)(Apl + 8);
        r6 = *(const bf16x8*)(Bpl);
        r7 = *(const bf16x8*)(Bpl + 8);
    }
    #pragma unroll
    for(int k0=0;k0<DD;k0+=32){
        __syncthreads();
        *(bf16x8*)(Abuf + rbyte + c0) = r0; *(bf16x8*)(Abuf + rbyte + c1) = r1;
        *(bf16x8*)(Bbuf + rbyte + c0) = r4; *(bf16x8*)(Bbuf + rbyte + c1) = r5;
        if(!prec){
            *(bf16x8*)(Abuf + rbyte + c2) = r2; *(bf16x8*)(Abuf + rbyte + c3) = r3;
            *(bf16x8*)(Bbuf + rbyte + c2) = r6; *(bf16x8*)(Bbuf + rbyte + c3) = r7;
        }
        __syncthreads();
        if(k0 + 32 < DD){
            int kn = k0 + 32;
            r0 = *(const bf16x8*)(Aph + kn);     r1 = *(const bf16x8*)(Aph + kn + 8);
            r4 = *(const bf16x8*)(Bph + kn);     r5 = *(const bf16x8*)(Bph + kn + 8);
            if(!prec){
                r2 = *(const bf16x8*)(Apl + kn); r3 = *(const bf16x8*)(Apl + kn + 8);
                r6 = *(const bf16x8*)(Bpl + kn); r7 = *(const bf16x8*)(Bpl + kn + 8);
            }
        }
        bf16x8 afh[4], bfh[4];
        #pragma unroll
        for(int i=0;i<4;i++){
            int ar = wm + i*16 + l15;
            int abase = ar*128;
            afh[i] = *(const bf16x8*)(Abuf + abase + ((l4*16) ^ ((ar&7)<<4)));
            int br = wn + i*16 + l15;
            int bbase = br*128;
            bfh[i] = *(const bf16x8*)(Bbuf + bbase + ((l4*16) ^ ((br&7)<<4)));
        }
        #pragma unroll
        for(int i=0;i<4;i++)
            #pragma unroll
            for(int j=0;j<4;j++)
                acc[i][j] = __builtin_amdgcn_mfma_f32_16x16x32_bf16(afh[i], bfh[j], acc[i][j], 0,0,0);
        if(!prec){
            bf16x8 afl[4], bfl[4];
            #pragma unroll
            for(int i=0;i<4;i++){
                int ar = wm + i*16 + l15;
                int abase = ar*128;
                afl[i] = *(const bf16x8*)(Abuf + abase + ((64 + l4*16) ^ ((ar&7)<<4)));
                int br = wn + i*16 + l15;
                int bbase = br*128;
                bfl[i] = *(const bf16x8*)(Bbuf + bbase + ((64 + l4*16) ^ ((br&7)<<4)));
            }
            #pragma unroll
            for(int i=0;i<4;i++)
                #pragma unroll
                for(int j=0;j<4;j++){
                    acc[i][j] = __builtin_amdgcn_mfma_f32_16x16x32_bf16(afh[i], bfl[j], acc[i][j], 0,0,0);
                    acc[i][j] = __builtin_amdgcn_mfma_f32_16x16x32_bf16(afl[i], bfh[j], acc[i][j], 0,0,0);
                }
        }
    }
    // ---- coalesced epilogue via LDS restage (two 64-row passes) ----
    const int mode = g.mode;
    float gg = 0.f;
    if(mode == 2 || mode == 3) gg = 1.f/(1.f + expf(-*g.skipp));
    float* LDSf = (float*)SBUF;
    const int lrow = tid >> 5;
    const int cc4 = (tid & 31)*4;
    #pragma unroll
    for(int half=0; half<2; half++){
        __syncthreads();
        if((wid>>1) == half){
            #pragma unroll
            for(int i=0;i<4;i++)
                #pragma unroll
                for(int j=0;j<4;j++)
                    #pragma unroll
                    for(int r=0;r<4;r++)
                        LDSf[(i*16 + l4*4 + r)*128 + wn + j*16 + l15] = acc[i][j][r];
        }
        __syncthreads();
        #pragma unroll
        for(int k=0;k<8;k++){
            int row = lrow + k*8;
            size_t o = (size_t)(m0 + half*64 + row)*DD + n0 + cc4;
            float4 v = *(const float4*)&LDSf[row*128 + cc4];
            float vv[4] = {v.x, v.y, v.z, v.w};
            if(mode==0){
                *(float4*)(g.C + o) = v;
            } else if(mode==4){
                u16x4 h4;
                #pragma unroll
                for(int j=0;j<4;j++) h4[j] = f2b(vv[j]);
                *(u16x4*)(g.Oh + o) = h4;
            } else if(mode==1){
                u16x4 h4, lo4;
                #pragma unroll
                for(int j=0;j<4;j++){
                    u16 hh = f2b(vv[j]); h4[j]=hh; lo4[j]=f2b(vv[j]-b2f(hh));
                }
                *(u16x4*)(g.Oh + o) = h4;
                *(u16x4*)(g.Ol + o) = lo4;
            } else if(mode==2){
                float4 x = *(const float4*)(g.X + o);
                float xx[4] = {x.x, x.y, x.z, x.w};
                float4 w;
                float* ww = (float*)&w;
                #pragma unroll
                for(int j=0;j<4;j++) ww[j] = 0.5f*(gg*vv[j] + (1.f-gg)*xx[j]);
                *(float4*)(g.Xacc + o) = w;
            } else {
                float4 x = *(const float4*)(g.X + o);
                float4 xa = *(const float4*)(g.Xacc + o);
                float xx[4] = {x.x, x.y, x.z, x.w};
                float aa[4] = {xa.x, xa.y, xa.z, xa.w};
                float4 cv;
                float* cvv = (float*)&cv;
                u16x4 h4, lo4;
                #pragma unroll
                for(int j=0;j<4;j++){
                    float v3 = aa[j] + 0.5f*(gg*vv[j] + (1.f-gg)*xx[j]);
                    v3 = v3 > 0.f ? v3 : 0.f;
                    cvv[j] = v3;
                    u16 hh = f2b(v3); h4[j]=hh; lo4[j]=f2b(v3-b2f(hh));
                }
                *(float4*)(g.C + o) = cv;
                *(u16x4*)(g.Oh + o) = h4;
                *(u16x4*)(g.Ol + o) = lo4;
            }
        }
    }
}

// ---------- combine ----------
__global__ void combine_all(const float* __restrict__ Wk, const float* __restrict__ Wv,
                            const float* __restrict__ Ra, const float* __restrict__ Rm,
                            float* __restrict__ wtk, float* __restrict__ wtv){
    const int st_tab[2][4] = {{0,1,0,0},{0,0,1,0}};
    int combo = blockIdx.y;
    int idx = combo >> 1, kv = combo & 1;
    int r = idx & 3, wb = idx >> 2, dir = wb & 1;
    int st = st_tab[dir][r];
    const float* W = (kv ? Wv : Wk) + (size_t)(wb*2 + st)*65536;
    const float* R = (kv ? Rm : Ra) + (size_t)idx*16384;
    float* o = (kv ? wtv : wtk) + (size_t)idx*65536;
    int d = blockIdx.x, c = threadIdx.x;
    int h = c >> 6, f = c & 63;
    const float* Wrow = W + d*DD + h*64;
    const float* Rh = R + h*4096 + f;
    float s = 0.f;
    #pragma unroll 8
    for(int k=0;k<64;k++) s += Wrow[k]*Rh[k*64];
    o[d*DD + c] = s;
}

// ---------------- CSR build (both directions in one pass) ----------------
__device__ inline void edge_decode(int e, int& r, int& el){
    if(e < EC){ r=0; el=e; }
    else if(e < EC+EI){ r=1; el=e-EC; }
    else if(e < EC+EI+EO){ r=2; el=e-(EC+EI); }
    else { r=3; el=e-(EC+EI+EO); }
}

struct CB2 {
    const int* row[8]; const int* col[8];
    int dt[8]; int st[8];
    uint32_t* cnt; uint32_t* rowptr; uint32_t* einfo;
};

__global__ void csr_hist2(CB2 a){
    int ge = blockIdx.x*256 + threadIdx.x;
    if(ge >= 2*EHGT) return;
    int dir = ge >= EHGT;
    int e = ge - dir*EHGT;
    int r, el; edge_decode(e, r, el);
    int idx = dir*4 + r;
    int c = a.col[idx][el];
    int dst = dir*NROW + (a.dt[idx] ? (NI + c) : c);
    atomicAdd(&a.cnt[dst], 1u);
}

__global__ __launch_bounds__(1024) void scan_rowptr2(uint32_t* cnt, uint32_t* rowptr){
    __shared__ uint32_t part[1024];
    int t = threadIdx.x;
    int base = t*24;
    uint32_t lpre[24];
    uint32_t sum = 0;
    #pragma unroll
    for(int i=0;i<24;i++){
        uint32_t c = cnt[base+i];
        lpre[i] = sum; sum += c;
        cnt[base+i] = 0;
    }
    part[t] = sum;
    __syncthreads();
    for(int offs=1; offs<1024; offs<<=1){
        uint32_t v = (t>=offs) ? part[t-offs] : 0u;
        __syncthreads();
        part[t] += v;
        __syncthreads();
    }
    uint32_t pre = (t==0) ? 0u : part[t-1];
    #pragma unroll
    for(int i=0;i<24;i++) rowptr[base+i] = pre + lpre[i];
    if(t==1023) rowptr[2*NROW] = part[1023];
}

__global__ void csr_scatter2(CB2 a){
    int ge = blockIdx.x*256 + threadIdx.x;
    if(ge >= 2*EHGT) return;
    int dir = ge >= EHGT;
    int e = ge - dir*EHGT;
    int r, el; edge_decode(e, r, el);
    int idx = dir*4 + r;
    int c = a.col[idx][el];
    int dst = dir*NROW + (a.dt[idx] ? (NI + c) : c);
    int src = a.row[idx][el];
    uint32_t p = a.rowptr[dst] + atomicAdd(&a.cnt[dst], 1u);
    uint32_t vmidx = (uint32_t)(r*NI + src);
    uint32_t hom = a.st[idx] ? (uint32_t)(NI + src) : (uint32_t)src;
    a.einfo[p] = vmidx | (hom << 16);
}

// ---------------- fused HGT edge phase: wave per dst, all 4 heads, online softmax ----------------
__global__ __launch_bounds__(256) void hgt_fused(const uint32_t* __restrict__ rowptr,
                                                 const uint32_t* __restrict__ einfo,
                                                 const float* __restrict__ q_i,
                                                 const float* __restrict__ q_d,
                                                 const u16* __restrict__ ka,
                                                 const u16* __restrict__ vm,
                                                 const float* __restrict__ prel,
                                                 u16* __restrict__ bagg_h,
                                                 u16* __restrict__ bagg_l){
    int wv = threadIdx.x >> 6, lane = threadIdx.x & 63;
    int rowi = blockIdx.x*4 + wv;
    uint32_t p0 = rowptr[rowi], p1 = rowptr[rowi+1];
    int h = lane >> 4;
    const float* qrow = (rowi < NI) ? (q_i + (size_t)rowi*DD) : (q_d + (size_t)(rowi-NI)*DD);
    float4 q4 = *(const float4*)(qrow + lane*4);
    float pr0 = prel[0*HH+h]*0.125f, pr1 = prel[1*HH+h]*0.125f;
    float pr2 = prel[2*HH+h]*0.125f, pr3 = prel[3*HH+h]*0.125f;
    float m = -INFINITY, den = 0.f;
    float4 o4 = {0.f,0.f,0.f,0.f};
    for(uint32_t p = p0; p < p1; p++){
        uint32_t vmidx = einfo[p] & 0xffffu;
        int r = vmidx >> 13;
        uint2 kr = *(const uint2*)(ka + (size_t)vmidx*DD + lane*4);
        uint2 vr = *(const uint2*)(vm + (size_t)vmidx*DD + lane*4);
        float k0 = __uint_as_float(kr.x << 16), k1 = __uint_as_float(kr.x & 0xffff0000u);
        float k2 = __uint_as_float(kr.y << 16), k3 = __uint_as_float(kr.y & 0xffff0000u);
        float v0 = __uint_as_float(vr.x << 16), v1 = __uint_as_float(vr.x & 0xffff0000u);
        float v2 = __uint_as_float(vr.y << 16), v3 = __uint_as_float(vr.y & 0xffff0000u);
        float d = q4.x*k0 + q4.y*k1 + q4.z*k2 + q4.w*k3;
        d += __shfl_xor(d, 1); d += __shfl_xor(d, 2);
        d += __shfl_xor(d, 4); d += __shfl_xor(d, 8);
        float pf = (r==0) ? pr0 : (r==1) ? pr1 : (r==2) ? pr2 : pr3;
        float s = d * pf;
        float nm = fmaxf(m, s);
        float sc_ = expf(m - nm);
        float pe = expf(s - nm);
        den = den*sc_ + pe;
        o4.x = o4.x*sc_ + pe*v0;
        o4.y = o4.y*sc_ + pe*v1;
        o4.z = o4.z*sc_ + pe*v2;
        o4.w = o4.w*sc_ + pe*v3;
        m = nm;
    }
    float inv = 1.f/(den + 1e-16f);
    float vals[4] = {o4.x*inv, o4.y*inv, o4.z*inv, o4.w*inv};
    u16x4 h4, l4;
    #pragma unroll
    for(int j=0;j<4;j++){
        float g = gelu_f(vals[j]);
        u16 hh = f2b(g);
        h4[j] = hh;
        l4[j] = f2b(g - b2f(hh));
    }
    size_t ob = (size_t)rowi*DD + lane*4;
    *(u16x4*)(bagg_h + ob) = h4;
    *(u16x4*)(bagg_l + ob) = l4;
}

// ---------------- pooling ----------------
__global__ void pool_h2(const float* __restrict__ xi, const float* __restrict__ xd,
                        const float* __restrict__ w, float* __restrict__ h){
    int node = blockIdx.x*4 + (threadIdx.x>>6);
    int lane = threadIdx.x & 63;
    const float* xr = (node < NI) ? (xi + (size_t)node*DD) : (xd + (size_t)(node-NI)*DD);
    float s = 0.f;
    for(int j=lane;j<DD;j+=64) s += xr[j]*w[j];
    for(int m=32;m;m>>=1) s += __shfl_xor(s, m);
    if(lane==0) h[node] = s;
}

// GAT-style pooling score via fwd CSR + implicit self-loop; wave per dst node
__global__ __launch_bounds__(256) void pool_csr(const uint32_t* __restrict__ rowptr,
                                                const uint32_t* __restrict__ einfo,
                                                const float* __restrict__ h,
                                                const float* __restrict__ att,
                                                float* __restrict__ score){
    int w = blockIdx.x*4 + (threadIdx.x >> 6);
    int lane = threadIdx.x & 63;
    if(w >= NROW) return;
    uint32_t p0 = rowptr[w], p1 = rowptr[w+1];
    float a0 = att[0], a1 = att[1];
    float hn = h[w];
    float es = a0*hn + a1*hn;
    es = es >= 0.f ? es : 0.2f*es;
    float m = -INFINITY;
    for(uint32_t p = p0+lane; p < p1; p += 64){
        float hs = h[einfo[p] >> 16];
        float e = a0*hs + a1*hn;
        e = e >= 0.f ? e : 0.2f*e;
        m = fmaxf(m, e);
    }
    #pragma unroll
    for(int s=32;s;s>>=1) m = fmaxf(m, __shfl_xor(m, s));
    m = fmaxf(m, es);
    float lden = 0.f, lnum = 0.f;
    for(uint32_t p = p0+lane; p < p1; p += 64){
        float hs = h[einfo[p] >> 16];
        float e = a0*hs + a1*hn;
        e = e >= 0.f ? e : 0.2f*e;
        float a = expf(e - m);
        lden += a; lnum += a*hs;
    }
    #pragma unroll
    for(int s=32;s;s>>=1){ lden += __shfl_xor(lden, s); lnum += __shfl_xor(lnum, s); }
    float aself = expf(es - m);
    lden += aself; lnum += aself*hn;
    if(lane==0) score[w] = lnum/(lden + 1e-16f);
}

// ---------------- top-768 of 1536 per graph via exact rank selection ----------------
__global__ __launch_bounds__(256) void topk_rank(const float* __restrict__ score,
                                                 const float* __restrict__ bias,
                                                 int* __restrict__ sel_node,
                                                 float* __restrict__ sel_scale){
    __shared__ float keys[1536];
    int b = blockIdx.y;
    for(int t=threadIdx.x; t<1536; t+=256){
        int node = (t<1024) ? (b*1024 + t) : (NI + b*512 + (t-1024));
        keys[t] = score[node];
    }
    __syncthreads();
    int i = blockIdx.x*256 + threadIdx.x;
    float ki = keys[i];
    int r0=0, r1=0, r2=0, r3=0;
    #pragma unroll 4
    for(int j=0;j<1536;j+=4){
        float4 k4 = *(const float4*)&keys[j];
        r0 += (k4.x > ki) || (k4.x == ki && (j+0) < i);
        r1 += (k4.y > ki) || (k4.y == ki && (j+1) < i);
        r2 += (k4.z > ki) || (k4.z == ki && (j+2) < i);
        r3 += (k4.w > ki) || (k4.w == ki && (j+3) < i);
    }
    int rank = r0 + r1 + r2 + r3;
    if(rank < KPOOL){
        int node = (i<1024) ? (b*1024 + i) : (NI + b*512 + (i-1024));
        sel_node[b*KPOOL + rank] = node;
        sel_scale[b*KPOOL + rank] = tanhf(ki + bias[0]);
    }
}

__global__ void gather_xp(const int* __restrict__ sel, const float* __restrict__ scale,
                          const float* __restrict__ xi, const float* __restrict__ xd,
                          float* __restrict__ xp, u16* __restrict__ bh, u16* __restrict__ bl){
    int i = blockIdx.x*256 + threadIdx.x;
    int rowp = i >> 8, c = i & 255;
    int node = sel[rowp];
    float s = scale[rowp];
    float v = (node < NI) ? xi[(size_t)node*DD + c] : xd[(size_t)(node-NI)*DD + c];
    float x = v*s;
    xp[i] = x;
    u16 hh = f2b(x);
    bh[i] = hh;
    bl[i] = f2b(x - b2f(hh));
}

// ---------------- MFMA flash attention: block per (bh, 64 q rows), plain-bf16 QKV ----------------
__global__ __launch_bounds__(256) void attn_mfma(const u16* __restrict__ Qh,
                                                 const u16* __restrict__ Kh,
                                                 const u16* __restrict__ Vh,
                                                 u16* __restrict__ aoh, u16* __restrict__ aol){
    __shared__ u16 KhS[64*64], VtS[64*64];
    char* KhB = (char*)KhS; char* VtB = (char*)VtS;
    int bh = blockIdx.x;
    int b = bh >> 2, h = bh & 3;
    int q0 = blockIdx.y * 64;
    int tid = threadIdx.x;
    int lane = tid & 63;
    int w = tid >> 6;
    int l15 = lane & 15, l4 = lane >> 4;
    size_t qrow = (size_t)(b*KPOOL + q0 + w*16 + l15);
    bf16x8 qh[2];
    #pragma unroll
    for(int c=0;c<2;c++)
        qh[c] = *(const bf16x8*)(Qh + qrow*DD + h*64 + c*32 + l4*8);
    float mreg = -INFINITY, lreg = 0.f;
    f32x4 O[4] = {};
    for(int k0=0;k0<KPOOL;k0+=64){
        __syncthreads();
        {
            int row = tid >> 2, q4 = tid & 3;
            size_t gbase = ((size_t)(b*KPOOL + k0 + row))*DD + h*64 + q4*16;
            bf16x8 k0v = *(const bf16x8*)(Kh + gbase);
            bf16x8 k1v = *(const bf16x8*)(Kh + gbase + 8);
            int sw = (row&7)<<4;
            int colb = q4*32;
            *(bf16x8*)(KhB + row*128 + (colb ^ sw))      = k0v;
            *(bf16x8*)(KhB + row*128 + ((colb+16) ^ sw)) = k1v;
            int row0 = (tid >> 3)*2, dhg = (tid & 7)*8;
            size_t vbase = ((size_t)(b*KPOOL + k0 + row0))*DD + h*64 + dhg;
            bf16x8 va = *(const bf16x8*)(Vh + vbase);
            bf16x8 vb = *(const bf16x8*)(Vh + vbase + DD);
            #pragma unroll
            for(int j=0;j<8;j++){
                int dh = dhg + j;
                uint32_t pk = (uint32_t)(u16)(short)va[j] | ((uint32_t)(u16)(short)vb[j] << 16);
                *(uint32_t*)(VtB + dh*128 + ((row0*2) ^ ((dh&7)<<4))) = pk;
            }
        }
        __syncthreads();
        f32x4 s[4] = {};
        #pragma unroll
        for(int t=0;t<4;t++){
            int arow = t*16 + l15;
            int sw = (arow&7)<<4;
            const char* bh_ = KhB + arow*128;
            bf16x8 kh0 = *(const bf16x8*)(bh_ + ((l4*16) ^ sw));
            bf16x8 kh1 = *(const bf16x8*)(bh_ + ((l4*16 + 64) ^ sw));
            s[t] = __builtin_amdgcn_mfma_f32_16x16x32_bf16(kh0, qh[0], s[t], 0,0,0);
            s[t] = __builtin_amdgcn_mfma_f32_16x16x32_bf16(kh1, qh[1], s[t], 0,0,0);
        }
        float cm = -INFINITY;
        #pragma unroll
        for(int t=0;t<4;t++)
            #pragma unroll
            for(int r=0;r<4;r++){ s[t][r] *= 0.125f; cm = fmaxf(cm, s[t][r]); }
        cm = fmaxf(cm, __shfl_xor(cm,16));
        cm = fmaxf(cm, __shfl_xor(cm,32));
        float nm = fmaxf(mreg, cm);
        float es = expf(mreg - nm);
        float ps = 0.f;
        #pragma unroll
        for(int t=0;t<4;t++)
            #pragma unroll
            for(int r=0;r<4;r++){ float pv = expf(s[t][r] - nm); s[t][r] = pv; ps += pv; }
        ps += __shfl_xor(ps,16);
        ps += __shfl_xor(ps,32);
        lreg = lreg*es + ps;
        mreg = nm;
        #pragma unroll
        for(int d=0;d<4;d++){ O[d][0]*=es; O[d][1]*=es; O[d][2]*=es; O[d][3]*=es; }
        #pragma unroll
        for(int c32=0;c32<2;c32++){
            bf16x8 pb;
            #pragma unroll
            for(int j=0;j<8;j++){
                int srcl = ((((lane>>4)*2 + (j>>2)) & 3) << 4) | l15;
                float v0 = __shfl(s[c32*2+0][j&3], srcl, 64);
                float v1 = __shfl(s[c32*2+1][j&3], srcl, 64);
                float v = (lane < 32) ? v0 : v1;
                pb[j] = (short)f2b(v);
            }
            #pragma unroll
            for(int dhb=0; dhb<4; dhb++){
                int vrow = dhb*16 + l15;
                bf16x8 va = *(const bf16x8*)(VtB + vrow*128 + ((c32*64 + l4*16) ^ ((vrow&7)<<4)));
                O[dhb] = __builtin_amdgcn_mfma_f32_16x16x32_bf16(va, pb, O[dhb], 0,0,0);
            }
        }
    }
    float inv = 1.f/lreg;
    #pragma unroll
    for(int dhb=0;dhb<4;dhb++)
        #pragma unroll
        for(int r=0;r<4;r++){
            float val = O[dhb][r]*inv;
            size_t o = qrow*DD + h*64 + dhb*16 + l4*4 + r;
            u16 hh = f2b(val);
            aoh[o] = hh;
            aol[o] = f2b(val - b2f(hh));
        }
}

// layernorm row kernel
__global__ __launch_bounds__(256) void ln_kernel(const float* __restrict__ xp, const float* __restrict__ o2,
                                                 const float* __restrict__ lg, const float* __restrict__ lb,
                                                 float* __restrict__ gatt){
    __shared__ float red[256];
    int r = blockIdx.x, c = threadIdx.x;
    float y = xp[(size_t)r*DD + c] + o2[(size_t)r*DD + c];
    red[c] = y; __syncthreads();
    for(int s=128;s;s>>=1){ if(c<s) red[c] += red[c+s]; __syncthreads(); }
    float mu = red[0]*(1.f/DD);
    __syncthreads();
    float d = y - mu;
    red[c] = d*d; __syncthreads();
    for(int s=128;s;s>>=1){ if(c<s) red[c] += red[c+s]; __syncthreads(); }
    float var = red[0]*(1.f/DD);
    gatt[(size_t)r*DD + c] = lg[c]*d/sqrtf(var+1e-5f) + lb[c];
}

__global__ void feat_reduce2(const float* __restrict__ xp, const float* __restrict__ gatt,
                             float* __restrict__ out){
    int b = blockIdx.x, c = threadIdx.x;
    int j0 = blockIdx.y*64;
    float s1=0.f, s2=0.f;
    for(int j=j0;j<j0+64;j++){
        size_t base = ((size_t)(b*KPOOL + j))*DD + c;
        s1 += xp[base];
        s2 += gatt[base];
    }
    atomicAdd(&out[b*512 + c], s1);
    atomicAdd(&out[b*512 + 256 + c], s2);
}

__global__ void cosine_kernel(const float* __restrict__ u, const float* __restrict__ v,
                              float* __restrict__ out){
    int b = blockIdx.x, t = threadIdx.x;
    float du=0.f, nu=0.f, nv=0.f;
    for(int j=t;j<512;j+=64){
        float a = u[b*512+j], bb = v[b*512+j];
        du += a*bb; nu += a*a; nv += bb*bb;
    }
    for(int m=32;m;m>>=1){
        du += __shfl_xor(du,m); nu += __shfl_xor(nu,m); nv += __shfl_xor(nv,m);
    }
    if(t==0) out[b] = du / (fmaxf(sqrtf(nu),1e-8f)*fmaxf(sqrtf(nv),1e-8f));
}

// =======================================================================
extern "C" void kernel_launch(void* const* d_in, const int* in_sizes, int n_in,
                              void* d_out, int out_size, void* d_ws, size_t ws_size,
                              hipStream_t stream){
    (void)in_sizes; (void)n_in; (void)out_size; (void)ws_size;
    const float* hgt_Wk   = (const float*)d_in[12];
    const float* hgt_Wq   = (const float*)d_in[13];
    const float* hgt_Wv   = (const float*)d_in[14];
    const float* hgt_Wo   = (const float*)d_in[15];
    const float* hgt_arel = (const float*)d_in[16];
    const float* hgt_mrel = (const float*)d_in[17];
    const float* hgt_prel = (const float*)d_in[18];
    const float* hgt_skip = (const float*)d_in[19];
    const float* pool_W   = (const float*)d_in[20];
    const float* pool_att = (const float*)d_in[21];
    const float* pool_bias= (const float*)d_in[22];
    const float* t_wq     = (const float*)d_in[23];
    const float* t_wk     = (const float*)d_in[24];
    const float* t_wv     = (const float*)d_in[25];
    const float* t_wo     = (const float*)d_in[26];
    const float* ln_g     = (const float*)d_in[27];
    const float* ln_b     = (const float*)d_in[28];
    float* out = (float*)d_out;

    char* base = (char*)d_ws;
    size_t off = 0;
    auto allocb = [&](size_t nbytes)->void*{
        void* p = (void*)(base + off);
        off += ((nbytes + 255) & ~(size_t)255);
        return p;
    };
    const size_t MAT = 65536;
    // ---- persistent ----
    u16* bwtk_h = (u16*)allocb(16*MAT*2); u16* bwtk_l = (u16*)allocb(16*MAT*2);
    u16* bwtv_h = (u16*)allocb(16*MAT*2); u16* bwtv_l = (u16*)allocb(16*MAT*2);
    u16* bwq_h  = (u16*)allocb(8*MAT*2);  u16* bwq_l  = (u16*)allocb(8*MAT*2);
    u16* bwo_h  = (u16*)allocb(8*MAT*2);  u16* bwo_l  = (u16*)allocb(8*MAT*2);
    u16* btw_h  = (u16*)allocb(4*MAT*2);  u16* btw_l  = (u16*)allocb(4*MAT*2);
    float* ubuf = (float*)allocb(BB*512*4);
    float* vbuf = (float*)allocb(BB*512*4);
    float* xa_i = (float*)allocb((size_t)NI*DD*4);
    float* xa_d = (float*)allocb((size_t)ND*DD*4);
    float* xb_i = (float*)allocb((size_t)NI*DD*4);
    float* xb_d = (float*)allocb((size_t)ND*DD*4);
    // ---- per-branch CSR ----
    uint32_t* ccnt   = (uint32_t*)allocb((size_t)2*NROW*4);
    uint32_t* rowptr = (uint32_t*)allocb((size_t)(2*NROW+1)*4);
    uint32_t* einfo  = (uint32_t*)allocb((size_t)2*EHGT*4);
    size_t region = off;
    // ---- conv scratch ----
    float* q_i  = (float*)allocb((size_t)NI*DD*4);
    float* q_d  = (float*)allocb((size_t)ND*DD*4);
    u16* ka16 = (u16*)allocb((size_t)4*NI*DD*2);   // bf16 KA; also combine f32 temp
    u16* vm16 = (u16*)allocb((size_t)4*NI*DD*2);
    float* xacc_i= (float*)allocb((size_t)NI*DD*4);
    float* xacc_d= (float*)allocb((size_t)ND*DD*4);
    u16* bcur_h = (u16*)allocb((size_t)NROW*DD*2);
    u16* bcur_l = (u16*)allocb((size_t)NROW*DD*2);
    u16* bagg_h = (u16*)allocb((size_t)NROW*DD*2);
    u16* bagg_l = (u16*)allocb((size_t)NROW*DD*2);
    // ---- pooling/transformer overlay ----
    off = region;
    float* hvec = (float*)allocb(NROW*4);
    float* pscore = (float*)allocb(NROW*4);
    int* seln   = (int*)allocb(BB*KPOOL*4);
    float* sels = (float*)allocb(BB*KPOOL*4);
    float* xp   = (float*)allocb((size_t)BB*KPOOL*DD*4);
    float* o2   = (float*)allocb((size_t)BB*KPOOL*DD*4);
    float* gatt = (float*)allocb((size_t)BB*KPOOL*DD*4);
    u16* bxp_h = (u16*)allocb((size_t)BB*KPOOL*DD*2);
    u16* bxp_l = (u16*)allocb((size_t)BB*KPOOL*DD*2);
    u16* qbh = (u16*)allocb((size_t)BB*KPOOL*DD*2);
    u16* kbh = (u16*)allocb((size_t)BB*KPOOL*DD*2);
    u16* vbh = (u16*)allocb((size_t)BB*KPOOL*DD*2);
    u16* bao_h = (u16*)allocb((size_t)BB*KPOOL*DD*2);
    u16* bao_l = (u16*)allocb((size_t)BB*KPOOL*DD*2);

    const int st_tab[2][4] = {{0,1,0,0},{0,0,1,0}};
    const int dt_tab[2][4] = {{0,0,1,0},{0,1,0,0}};
    const int MR = BB*KPOOL;

    fill_u32<<<(2*BB*512+255)/256,256,0,stream>>>((uint32_t*)ubuf, 0u, 2*BB*512);
    float* wtkF = (float*)ka16;
    float* wtvF = (float*)ka16 + 16*MAT;
    combine_all<<<dim3(256,32),256,0,stream>>>(hgt_Wk, hgt_Wv, hgt_arel, hgt_mrel, wtkF, wtvF);
    WCArgs wc;
    wc.in[0]=wtkF;   wc.oh[0]=bwtk_h; wc.ol[0]=bwtk_l; wc.cnt[0]=16;
    wc.in[1]=wtvF;   wc.oh[1]=bwtv_h; wc.ol[1]=bwtv_l; wc.cnt[1]=16;
    wc.in[2]=hgt_Wq; wc.oh[2]=bwq_h;  wc.ol[2]=bwq_l;  wc.cnt[2]=8;
    wc.in[3]=hgt_Wo; wc.oh[3]=bwo_h;  wc.ol[3]=bwo_l;  wc.cnt[3]=8;
    wc.in[4]=t_wq;   wc.oh[4]=btw_h;          wc.ol[4]=btw_l;          wc.cnt[4]=1;
    wc.in[5]=t_wk;   wc.oh[5]=btw_h+1*MAT;    wc.ol[5]=btw_l+1*MAT;    wc.cnt[5]=1;
    wc.in[6]=t_wv;   wc.oh[6]=btw_h+2*MAT;    wc.ol[6]=btw_l+2*MAT;    wc.cnt[6]=1;
    wc.in[7]=t_wo;   wc.oh[7]=btw_h+3*MAT;    wc.ol[7]=btw_l+3*MAT;    wc.cnt[7]=1;
    wc.nr = 8;
    wcvt_split<<<dim3(256,52),256,0,stream>>>(wc);

    for(int bi=0;bi<2;bi++){
        int ib = bi*6;
        const float* x_inst = (const float*)d_in[ib+0];
        const float* x_data = (const float*)d_in[ib+1];
        const int* ecp = (const int*)d_in[ib+2];
        const int* eip = (const int*)d_in[ib+3];
        const int* eop = (const int*)d_in[ib+4];
        const int* ekp = (const int*)d_in[ib+5];
        const int* rows_f[4] = {ecp, eip, eop, ekp};
        const int* cols_f[4] = {ecp+EC, eip+EI, eop+EO, ekp+EK};

        // ---- CSR build (both dirs, one pass) ----
        CB2 cb;
        for(int r=0;r<4;r++){
            cb.row[r]   = rows_f[r]; cb.col[r]   = cols_f[r]; cb.dt[r]   = dt_tab[0][r]; cb.st[r]   = st_tab[0][r];
            cb.row[4+r] = cols_f[r]; cb.col[4+r] = rows_f[r]; cb.dt[4+r] = dt_tab[1][r]; cb.st[4+r] = st_tab[1][r];
        }
        cb.cnt = ccnt; cb.rowptr = rowptr; cb.einfo = einfo;
        fill_u32<<<(2*NROW+255)/256,256,0,stream>>>(ccnt, 0u, 2*NROW);
        csr_hist2<<<(2*EHGT+255)/256,256,0,stream>>>(cb);
        scan_rowptr2<<<1,1024,0,stream>>>(ccnt, rowptr);
        csr_scatter2<<<(2*EHGT+255)/256,256,0,stream>>>(cb);

        const float* cur_i = x_inst;
        const float* cur_d = x_data;
        cvt_split<<<((NROW*DD/4)+255)/256,256,0,stream>>>(cur_i, NI*DD, cur_d, ND*DD, bcur_h, bcur_l);
        for(int l=0;l<LL;l++){
            float* nxt_i = (l==0) ? xa_i : xb_i;
            float* nxt_d = (l==0) ? xa_d : xb_d;
            for(int dir=0;dir<2;dir++){
                int wb = l*2 + dir;

                // --- mega GEMM: Q(2, f32, split) + KA(4, bf16, prec=1) + VM(4, bf16, prec=1) ---
                GArgs g1; int nb1 = 0, ndx = 0;
                auto addg = [&](int srctype, const u16* Bh, const u16* Bl, float* Cm, u16* Om, int M, int mode, int prec){
                    GDesc& d = g1.d[ndx];
                    size_t ao = srctype ? (size_t)NI*DD : 0;
                    d.Ah = bcur_h + ao; d.Al = bcur_l + ao;
                    d.Bh = Bh; d.Bl = Bl; d.C = Cm;
                    d.Oh = Om; d.Ol = nullptr; d.X = nullptr; d.Xacc = nullptr; d.skipp = nullptr;
                    d.mblks = M/128; d.mode = mode; d.prec = prec;
                    nb1 += M/128; ndx++;
                };
                addg(0, bwq_h + (size_t)(wb*2+0)*MAT, bwq_l + (size_t)(wb*2+0)*MAT, q_i, nullptr, NI, 0, 0);
                addg(1, bwq_h + (size_t)(wb*2+1)*MAT, bwq_l + (size_t)(wb*2+1)*MAT, q_d, nullptr, ND, 0, 0);
                for(int r=0;r<4;r++){
                    int st = st_tab[dir][r];
                    addg(st, bwtk_h + (size_t)(wb*4+r)*MAT, bwtk_l + (size_t)(wb*4+r)*MAT,
                         nullptr, ka16 + (size_t)r*NI*DD, st ? ND : NI, 4, 1);
                }
                for(int r=0;r<4;r++){
                    int st = st_tab[dir][r];
                    addg(st, bwtv_h + (size_t)(wb*4+r)*MAT, bwtv_l + (size_t)(wb*4+r)*MAT,
                         nullptr, vm16 + (size_t)r*NI*DD, st ? ND : NI, 4, 1);
                }
                g1.nd = ndx;
                gemm_mfma<<<dim3(nb1,2),256,0,stream>>>(g1);

                // --- fused edge phase ---
                hgt_fused<<<NROW/4,256,0,stream>>>(rowptr + (size_t)dir*NROW, einfo,
                    q_i, q_d, ka16, vm16, hgt_prel + (size_t)wb*4*HH, bagg_h, bagg_l);

                // --- Wo GEMMs with fused skip/relu epilogue (split) ---
                GArgs g3; g3.nd = 2;
                for(int t=0;t<2;t++){
                    GDesc& d = g3.d[t];
                    size_t ao = t ? (size_t)NI*DD : 0;
                    d.Ah = bagg_h + ao; d.Al = bagg_l + ao;
                    d.Bh = bwo_h + (size_t)(wb*2+t)*MAT; d.Bl = bwo_l + (size_t)(wb*2+t)*MAT;
                    d.C = t ? nxt_d : nxt_i;
                    d.Oh = bcur_h + ao; d.Ol = bcur_l + ao;
                    d.X = t ? cur_d : cur_i;
                    d.Xacc = t ? xacc_d : xacc_i;
                    d.skipp = hgt_skip + wb*2 + t;
                    d.mblks = (t ? ND : NI)/128;
                    d.mode = dir ? 3 : 2;
                    d.prec = 0;
                }
                gemm_mfma<<<dim3(NI/128 + ND/128,2),256,0,stream>>>(g3);
            }
            cur_i = nxt_i;
            cur_d = nxt_d;
        }

        // -------- SAGPooling (CSR-based, no atomics) --------
        pool_h2<<<NROW/4,256,0,stream>>>(cur_i, cur_d, pool_W, hvec);
        pool_csr<<<NROW/4,256,0,stream>>>(rowptr, einfo, hvec, pool_att, pscore);
        topk_rank<<<dim3(6,BB),256,0,stream>>>(pscore, pool_bias, seln, sels);
        gather_xp<<<BB*KPOOL,256,0,stream>>>(seln, sels, cur_i, cur_d, xp, bxp_h, bxp_l);

        // -------- transformer --------
        GArgs g4; g4.nd = 3;
        for(int t=0;t<3;t++){
            GDesc& d = g4.d[t];
            d.Ah=bxp_h; d.Al=bxp_l;
            d.Bh=btw_h + (size_t)t*MAT; d.Bl=btw_l + (size_t)t*MAT;
            d.C = nullptr;
            d.Oh = (t==0)? qbh : (t==1)? kbh : vbh;
            d.Ol = nullptr;
            d.X = nullptr; d.Xacc = nullptr; d.skipp = nullptr;
            d.mblks = MR/128; d.mode = 4; d.prec = 0;
        }
        gemm_mfma<<<dim3(3*(MR/128),2),256,0,stream>>>(g4);
        attn_mfma<<<dim3(BB*HH, KPOOL/64),256,0,stream>>>(qbh, kbh, vbh, bao_h, bao_l);
        GArgs g5; g5.nd = 1;
        {
            GDesc& d = g5.d[0];
            d.Ah=bao_h; d.Al=bao_l;
            d.Bh=btw_h + (size_t)3*MAT; d.Bl=btw_l + (size_t)3*MAT;
            d.C=o2; d.Oh=nullptr; d.Ol=nullptr; d.X=nullptr; d.Xacc=nullptr; d.skipp=nullptr;
            d.mblks=MR/128; d.mode=0; d.prec=0;
        }
        gemm_mfma<<<dim3(MR/128,2),256,0,stream>>>(g5);
        ln_kernel<<<MR,256,0,stream>>>(xp, o2, ln_g, ln_b, gatt);
        feat_reduce2<<<dim3(BB,12),256,0,stream>>>(xp, gatt, bi ? vbuf : ubuf);
    }

    cosine_kernel<<<BB,64,0,stream>>>(ubuf, vbuf, out);
}

// Round 21
// 976.325 us; speedup vs baseline: 1.9919x; 1.0706x over previous
//
#include <hip/hip_runtime.h>
#include <math.h>
#include <stdint.h>

#define LL 2
#define HH 4
#define DHH 64
#define DD 256
#define BB 8
#define NI 8192
#define ND 4096
#define NROW 12288
#define KPOOL 768
#define EC 65536
#define EI 32768
#define EO 32768
#define EK 8192
#define EHGT (EC+EI+EO+EK)

typedef unsigned short u16;
typedef short bf16x8 __attribute__((ext_vector_type(8)));
typedef float f32x4 __attribute__((ext_vector_type(4)));
typedef unsigned short u16x4 __attribute__((ext_vector_type(4)));

__device__ inline float gelu_f(float x){ return 0.5f*x*(1.f+erff(x*0.70710678118654752f)); }
__device__ inline u16 f2b(float x){ uint32_t u=__float_as_uint(x); return (u16)((u + 0x7fffu + ((u>>16)&1u))>>16); }
__device__ inline float b2f(u16 h){ return __uint_as_float(((uint32_t)h)<<16); }

// ---------------- generic fill ----------------
__global__ void fill_u32(uint32_t* p, uint32_t v, int n){
    int i = blockIdx.x*256 + threadIdx.x;
    if(i<n) p[i]=v;
}

// ---------------- activation split-convert ----------------
__global__ void cvt_split(const float* __restrict__ A, int nA, const float* __restrict__ B, int nB,
                          u16* __restrict__ oh, u16* __restrict__ ol){
    int i = (blockIdx.x*256 + threadIdx.x)*4;
    int tot = nA + nB;
    if(i >= tot) return;
    float4 v = (i < nA) ? *(const float4*)(A + i) : *(const float4*)(B + (i - nA));
    float vv[4] = {v.x, v.y, v.z, v.w};
    u16x4 h4, l4;
    #pragma unroll
    for(int j=0;j<4;j++){
        float x = vv[j];
        u16 h = f2b(x);
        h4[j] = h;
        l4[j] = f2b(x - b2f(h));
    }
    *(u16x4*)(oh + i) = h4;
    *(u16x4*)(ol + i) = l4;
}

// ---------------- weight transpose + split ----------------
struct WCArgs { const float* in[8]; u16* oh[8]; u16* ol[8]; int cnt[8]; int nr; };
__global__ void wcvt_split(WCArgs a){
    int mat = blockIdx.y, ri = 0;
    while(ri < a.nr-1 && mat >= a.cnt[ri]){ mat -= a.cnt[ri]; ri++; }
    const float* in = a.in[ri] + (size_t)mat*65536;
    u16* oh = a.oh[ri] + (size_t)mat*65536;
    u16* ol = a.ol[ri] + (size_t)mat*65536;
    int n = blockIdx.x, k = threadIdx.x;
    float x = in[(size_t)k*DD + n];
    u16 h = f2b(x);
    oh[n*DD + k] = h;
    ol[n*DD + k] = f2b(x - b2f(h));
}

// ---------------- MFMA batched GEMM with fused, LDS-restaged epilogues ----------------
// prec=0: split hi/lo (3 MFMA/step); prec=1: hi-only (1 MFMA/step, half staging)
// mode 0: C=f32   mode 1: Oh/Ol=split bf16   mode 4: Oh=plain bf16
// mode 2: Xacc = 0.5*(g*acc + (1-g)*X)
// mode 3: v=relu(Xacc + 0.5*(g*acc+(1-g)*X)); C=v; Oh/Ol=split(v)
struct GDesc { const u16* Ah; const u16* Al; const u16* Bh; const u16* Bl;
               float* C; u16* Oh; u16* Ol;
               const float* X; float* Xacc; const float* skipp;
               int mblks; int mode; int prec; };
struct GArgs { GDesc d[10]; int nd; };

__global__ __launch_bounds__(256) void gemm_mfma(GArgs ga){
    __shared__ u16 SBUF[2*128*64];
    char* Abuf = (char*)SBUF;
    char* Bbuf = (char*)(SBUF + 128*64);
    int mb = blockIdx.x, di = 0;
    while(di < ga.nd-1 && mb >= ga.d[di].mblks){ mb -= ga.d[di].mblks; di++; }
    GDesc g = ga.d[di];
    const int prec = g.prec;
    const int m0 = mb*128, n0 = blockIdx.y*128;
    const int tid = threadIdx.x;
    const int lane = tid & 63, wid = tid >> 6;
    const int wm = (wid>>1)*64, wn = (wid&1)*64;
    const int l15 = lane & 15, l4 = lane >> 4;
    const int srow = tid >> 1, hf = tid & 1;
    const int ssw = (srow&7)<<4;
    const int c0 = (hf*32) ^ ssw;
    const int c1 = (hf*32+16) ^ ssw;
    const int c2 = (64+hf*32) ^ ssw;
    const int c3 = (64+hf*32+16) ^ ssw;
    const int rbyte = srow*128;
    const u16* __restrict__ Aph = g.Ah + (size_t)(m0 + srow)*DD + hf*16;
    const u16* __restrict__ Apl = g.Al + (size_t)(m0 + srow)*DD + hf*16;
    const u16* __restrict__ Bph = g.Bh + (size_t)(n0 + srow)*DD + hf*16;
    const u16* __restrict__ Bpl = g.Bl + (size_t)(n0 + srow)*DD + hf*16;
    f32x4 acc[4][4] = {};
    bf16x8 r0, r1, r2, r3, r4, r5, r6, r7;
    r0 = *(const bf16x8*)(Aph);
    r1 = *(const bf16x8*)(Aph + 8);
    r4 = *(const bf16x8*)(Bph);
    r5 = *(const bf16x8*)(Bph + 8);
    if(!prec){
        r2 = *(const bf16x8*)(Apl);
        r3 = *(const bf16x8*)(Apl + 8);
        r6 = *(const bf16x8*)(Bpl);
        r7 = *(const bf16x8*)(Bpl + 8);
    }
    #pragma unroll
    for(int k0=0;k0<DD;k0+=32){
        __syncthreads();
        *(bf16x8*)(Abuf + rbyte + c0) = r0; *(bf16x8*)(Abuf + rbyte + c1) = r1;
        *(bf16x8*)(Bbuf + rbyte + c0) = r4; *(bf16x8*)(Bbuf + rbyte + c1) = r5;
        if(!prec){
            *(bf16x8*)(Abuf + rbyte + c2) = r2; *(bf16x8*)(Abuf + rbyte + c3) = r3;
            *(bf16x8*)(Bbuf + rbyte + c2) = r6; *(bf16x8*)(Bbuf + rbyte + c3) = r7;
        }
        __syncthreads();
        if(k0 + 32 < DD){
            int kn = k0 + 32;
            r0 = *(const bf16x8*)(Aph + kn);     r1 = *(const bf16x8*)(Aph + kn + 8);
            r4 = *(const bf16x8*)(Bph + kn);     r5 = *(const bf16x8*)(Bph + kn + 8);
            if(!prec){
                r2 = *(const bf16x8*)(Apl + kn); r3 = *(const bf16x8*)(Apl + kn + 8);
                r6 = *(const bf16x8*)(Bpl + kn); r7 = *(const bf16x8*)(Bpl + kn + 8);
            }
        }
        bf16x8 afh[4], bfh[4];
        #pragma unroll
        for(int i=0;i<4;i++){
            int ar = wm + i*16 + l15;
            int abase = ar*128;
            afh[i] = *(const bf16x8*)(Abuf + abase + ((l4*16) ^ ((ar&7)<<4)));
            int br = wn + i*16 + l15;
            int bbase = br*128;
            bfh[i] = *(const bf16x8*)(Bbuf + bbase + ((l4*16) ^ ((br&7)<<4)));
        }
        #pragma unroll
        for(int i=0;i<4;i++)
            #pragma unroll
            for(int j=0;j<4;j++)
                acc[i][j] = __builtin_amdgcn_mfma_f32_16x16x32_bf16(afh[i], bfh[j], acc[i][j], 0,0,0);
        if(!prec){
            bf16x8 afl[4], bfl[4];
            #pragma unroll
            for(int i=0;i<4;i++){
                int ar = wm + i*16 + l15;
                int abase = ar*128;
                afl[i] = *(const bf16x8*)(Abuf + abase + ((64 + l4*16) ^ ((ar&7)<<4)));
                int br = wn + i*16 + l15;
                int bbase = br*128;
                bfl[i] = *(const bf16x8*)(Bbuf + bbase + ((64 + l4*16) ^ ((br&7)<<4)));
            }
            #pragma unroll
            for(int i=0;i<4;i++)
                #pragma unroll
                for(int j=0;j<4;j++){
                    acc[i][j] = __builtin_amdgcn_mfma_f32_16x16x32_bf16(afh[i], bfl[j], acc[i][j], 0,0,0);
                    acc[i][j] = __builtin_amdgcn_mfma_f32_16x16x32_bf16(afl[i], bfh[j], acc[i][j], 0,0,0);
                }
        }
    }
    // ---- coalesced epilogue via LDS restage (two 64-row passes) ----
    const int mode = g.mode;
    float gg = 0.f;
    if(mode == 2 || mode == 3) gg = 1.f/(1.f + expf(-*g.skipp));
    float* LDSf = (float*)SBUF;
    const int lrow = tid >> 5;
    const int cc4 = (tid & 31)*4;
    #pragma unroll
    for(int half=0; half<2; half++){
        __syncthreads();
        if((wid>>1) == half){
            #pragma unroll
            for(int i=0;i<4;i++)
                #pragma unroll
                for(int j=0;j<4;j++)
                    #pragma unroll
                    for(int r=0;r<4;r++)
                        LDSf[(i*16 + l4*4 + r)*128 + wn + j*16 + l15] = acc[i][j][r];
        }
        __syncthreads();
        #pragma unroll
        for(int k=0;k<8;k++){
            int row = lrow + k*8;
            size_t o = (size_t)(m0 + half*64 + row)*DD + n0 + cc4;
            float4 v = *(const float4*)&LDSf[row*128 + cc4];
            float vv[4] = {v.x, v.y, v.z, v.w};
            if(mode==0){
                *(float4*)(g.C + o) = v;
            } else if(mode==4){
                u16x4 h4;
                #pragma unroll
                for(int j=0;j<4;j++) h4[j] = f2b(vv[j]);
                *(u16x4*)(g.Oh + o) = h4;
            } else if(mode==1){
                u16x4 h4, lo4;
                #pragma unroll
                for(int j=0;j<4;j++){
                    u16 hh = f2b(vv[j]); h4[j]=hh; lo4[j]=f2b(vv[j]-b2f(hh));
                }
                *(u16x4*)(g.Oh + o) = h4;
                *(u16x4*)(g.Ol + o) = lo4;
            } else if(mode==2){
                float4 x = *(const float4*)(g.X + o);
                float xx[4] = {x.x, x.y, x.z, x.w};
                float4 w;
                float* ww = (float*)&w;
                #pragma unroll
                for(int j=0;j<4;j++) ww[j] = 0.5f*(gg*vv[j] + (1.f-gg)*xx[j]);
                *(float4*)(g.Xacc + o) = w;
            } else {
                float4 x = *(const float4*)(g.X + o);
                float4 xa = *(const float4*)(g.Xacc + o);
                float xx[4] = {x.x, x.y, x.z, x.w};
                float aa[4] = {xa.x, xa.y, xa.z, xa.w};
                float4 cv;
                float* cvv = (float*)&cv;
                u16x4 h4, lo4;
                #pragma unroll
                for(int j=0;j<4;j++){
                    float v3 = aa[j] + 0.5f*(gg*vv[j] + (1.f-gg)*xx[j]);
                    v3 = v3 > 0.f ? v3 : 0.f;
                    cvv[j] = v3;
                    u16 hh = f2b(v3); h4[j]=hh; lo4[j]=f2b(v3-b2f(hh));
                }
                *(float4*)(g.C + o) = cv;
                *(u16x4*)(g.Oh + o) = h4;
                *(u16x4*)(g.Ol + o) = lo4;
            }
        }
    }
}

// ---------- combine ----------
__global__ void combine_all(const float* __restrict__ Wk, const float* __restrict__ Wv,
                            const float* __restrict__ Ra, const float* __restrict__ Rm,
                            float* __restrict__ wtk, float* __restrict__ wtv){
    const int st_tab[2][4] = {{0,1,0,0},{0,0,1,0}};
    int combo = blockIdx.y;
    int idx = combo >> 1, kv = combo & 1;
    int r = idx & 3, wb = idx >> 2, dir = wb & 1;
    int st = st_tab[dir][r];
    const float* W = (kv ? Wv : Wk) + (size_t)(wb*2 + st)*65536;
    const float* R = (kv ? Rm : Ra) + (size_t)idx*16384;
    float* o = (kv ? wtv : wtk) + (size_t)idx*65536;
    int d = blockIdx.x, c = threadIdx.x;
    int h = c >> 6, f = c & 63;
    const float* Wrow = W + d*DD + h*64;
    const float* Rh = R + h*4096 + f;
    float s = 0.f;
    #pragma unroll 8
    for(int k=0;k<64;k++) s += Wrow[k]*Rh[k*64];
    o[d*DD + c] = s;
}

// ---------------- CSR build (both directions in one pass) ----------------
__device__ inline void edge_decode(int e, int& r, int& el){
    if(e < EC){ r=0; el=e; }
    else if(e < EC+EI){ r=1; el=e-EC; }
    else if(e < EC+EI+EO){ r=2; el=e-(EC+EI); }
    else { r=3; el=e-(EC+EI+EO); }
}

struct CB2 {
    const int* row[8]; const int* col[8];
    int dt[8]; int st[8];
    uint32_t* cnt; uint32_t* rowptr; uint32_t* einfo;
};

__global__ void csr_hist2(CB2 a){
    int ge = blockIdx.x*256 + threadIdx.x;
    if(ge >= 2*EHGT) return;
    int dir = ge >= EHGT;
    int e = ge - dir*EHGT;
    int r, el; edge_decode(e, r, el);
    int idx = dir*4 + r;
    int c = a.col[idx][el];
    int dst = dir*NROW + (a.dt[idx] ? (NI + c) : c);
    atomicAdd(&a.cnt[dst], 1u);
}

__global__ __launch_bounds__(1024) void scan_rowptr2(uint32_t* cnt, uint32_t* rowptr){
    __shared__ uint32_t part[1024];
    int t = threadIdx.x;
    int base = t*24;
    uint32_t lpre[24];
    uint32_t sum = 0;
    #pragma unroll
    for(int i=0;i<24;i++){
        uint32_t c = cnt[base+i];
        lpre[i] = sum; sum += c;
        cnt[base+i] = 0;
    }
    part[t] = sum;
    __syncthreads();
    for(int offs=1; offs<1024; offs<<=1){
        uint32_t v = (t>=offs) ? part[t-offs] : 0u;
        __syncthreads();
        part[t] += v;
        __syncthreads();
    }
    uint32_t pre = (t==0) ? 0u : part[t-1];
    #pragma unroll
    for(int i=0;i<24;i++) rowptr[base+i] = pre + lpre[i];
    if(t==1023) rowptr[2*NROW] = part[1023];
}

__global__ void csr_scatter2(CB2 a){
    int ge = blockIdx.x*256 + threadIdx.x;
    if(ge >= 2*EHGT) return;
    int dir = ge >= EHGT;
    int e = ge - dir*EHGT;
    int r, el; edge_decode(e, r, el);
    int idx = dir*4 + r;
    int c = a.col[idx][el];
    int dst = dir*NROW + (a.dt[idx] ? (NI + c) : c);
    int src = a.row[idx][el];
    uint32_t p = a.rowptr[dst] + atomicAdd(&a.cnt[dst], 1u);
    uint32_t vmidx = (uint32_t)(r*NI + src);
    uint32_t hom = a.st[idx] ? (uint32_t)(NI + src) : (uint32_t)src;
    a.einfo[p] = vmidx | (hom << 16);
}

// ---------------- fused HGT edge phase: wave per dst, all 4 heads, online softmax ----------------
__global__ __launch_bounds__(256) void hgt_fused(const uint32_t* __restrict__ rowptr,
                                                 const uint32_t* __restrict__ einfo,
                                                 const float* __restrict__ q_i,
                                                 const float* __restrict__ q_d,
                                                 const u16* __restrict__ ka,
                                                 const u16* __restrict__ vm,
                                                 const float* __restrict__ prel,
                                                 u16* __restrict__ bagg_h,
                                                 u16* __restrict__ bagg_l){
    int wv = threadIdx.x >> 6, lane = threadIdx.x & 63;
    int rowi = blockIdx.x*4 + wv;
    uint32_t p0 = rowptr[rowi], p1 = rowptr[rowi+1];
    int h = lane >> 4;
    const float* qrow = (rowi < NI) ? (q_i + (size_t)rowi*DD) : (q_d + (size_t)(rowi-NI)*DD);
    float4 q4 = *(const float4*)(qrow + lane*4);
    float pr0 = prel[0*HH+h]*0.125f, pr1 = prel[1*HH+h]*0.125f;
    float pr2 = prel[2*HH+h]*0.125f, pr3 = prel[3*HH+h]*0.125f;
    float m = -INFINITY, den = 0.f;
    float4 o4 = {0.f,0.f,0.f,0.f};
    for(uint32_t p = p0; p < p1; p++){
        uint32_t vmidx = einfo[p] & 0xffffu;
        int r = vmidx >> 13;
        uint2 kr = *(const uint2*)(ka + (size_t)vmidx*DD + lane*4);
        uint2 vr = *(const uint2*)(vm + (size_t)vmidx*DD + lane*4);
        float k0 = __uint_as_float(kr.x << 16), k1 = __uint_as_float(kr.x & 0xffff0000u);
        float k2 = __uint_as_float(kr.y << 16), k3 = __uint_as_float(kr.y & 0xffff0000u);
        float v0 = __uint_as_float(vr.x << 16), v1 = __uint_as_float(vr.x & 0xffff0000u);
        float v2 = __uint_as_float(vr.y << 16), v3 = __uint_as_float(vr.y & 0xffff0000u);
        float d = q4.x*k0 + q4.y*k1 + q4.z*k2 + q4.w*k3;
        d += __shfl_xor(d, 1); d += __shfl_xor(d, 2);
        d += __shfl_xor(d, 4); d += __shfl_xor(d, 8);
        float pf = (r==0) ? pr0 : (r==1) ? pr1 : (r==2) ? pr2 : pr3;
        float s = d * pf;
        float nm = fmaxf(m, s);
        float sc_ = expf(m - nm);
        float pe = expf(s - nm);
        den = den*sc_ + pe;
        o4.x = o4.x*sc_ + pe*v0;
        o4.y = o4.y*sc_ + pe*v1;
        o4.z = o4.z*sc_ + pe*v2;
        o4.w = o4.w*sc_ + pe*v3;
        m = nm;
    }
    float inv = 1.f/(den + 1e-16f);
    float vals[4] = {o4.x*inv, o4.y*inv, o4.z*inv, o4.w*inv};
    u16x4 h4, l4;
    #pragma unroll
    for(int j=0;j<4;j++){
        float g = gelu_f(vals[j]);
        u16 hh = f2b(g);
        h4[j] = hh;
        l4[j] = f2b(g - b2f(hh));
    }
    size_t ob = (size_t)rowi*DD + lane*4;
    *(u16x4*)(bagg_h + ob) = h4;
    *(u16x4*)(bagg_l + ob) = l4;
}

// ---------------- pooling ----------------
__global__ void pool_h2(const float* __restrict__ xi, const float* __restrict__ xd,
                        const float* __restrict__ w, float* __restrict__ h){
    int node = blockIdx.x*4 + (threadIdx.x>>6);
    int lane = threadIdx.x & 63;
    const float* xr = (node < NI) ? (xi + (size_t)node*DD) : (xd + (size_t)(node-NI)*DD);
    float s = 0.f;
    for(int j=lane;j<DD;j+=64) s += xr[j]*w[j];
    for(int m=32;m;m>>=1) s += __shfl_xor(s, m);
    if(lane==0) h[node] = s;
}

// GAT-style pooling score via fwd CSR + implicit self-loop; wave per dst node
__global__ __launch_bounds__(256) void pool_csr(const uint32_t* __restrict__ rowptr,
                                                const uint32_t* __restrict__ einfo,
                                                const float* __restrict__ h,
                                                const float* __restrict__ att,
                                                float* __restrict__ score){
    int w = blockIdx.x*4 + (threadIdx.x >> 6);
    int lane = threadIdx.x & 63;
    if(w >= NROW) return;
    uint32_t p0 = rowptr[w], p1 = rowptr[w+1];
    float a0 = att[0], a1 = att[1];
    float hn = h[w];
    float es = a0*hn + a1*hn;
    es = es >= 0.f ? es : 0.2f*es;
    float m = -INFINITY;
    for(uint32_t p = p0+lane; p < p1; p += 64){
        float hs = h[einfo[p] >> 16];
        float e = a0*hs + a1*hn;
        e = e >= 0.f ? e : 0.2f*e;
        m = fmaxf(m, e);
    }
    #pragma unroll
    for(int s=32;s;s>>=1) m = fmaxf(m, __shfl_xor(m, s));
    m = fmaxf(m, es);
    float lden = 0.f, lnum = 0.f;
    for(uint32_t p = p0+lane; p < p1; p += 64){
        float hs = h[einfo[p] >> 16];
        float e = a0*hs + a1*hn;
        e = e >= 0.f ? e : 0.2f*e;
        float a = expf(e - m);
        lden += a; lnum += a*hs;
    }
    #pragma unroll
    for(int s=32;s;s>>=1){ lden += __shfl_xor(lden, s); lnum += __shfl_xor(lnum, s); }
    float aself = expf(es - m);
    lden += aself; lnum += aself*hn;
    if(lane==0) score[w] = lnum/(lden + 1e-16f);
}

// ---------------- top-768 of 1536 per graph: wave-per-candidate rank selection ----------------
// grid (384, BB), 256 thr = 4 waves; wave handles candidate i = bx*4+wid.
// Lanes scan 1536 keys in 24 coalesced independent global loads (L1/L2-hit),
// rank reduced via shfl. Same descending/index tie-break as jax.lax.top_k.
__global__ __launch_bounds__(256) void topk_rank(const float* __restrict__ score,
                                                 const float* __restrict__ bias,
                                                 int* __restrict__ sel_node,
                                                 float* __restrict__ sel_scale){
    int b = blockIdx.y;
    int wid = threadIdx.x >> 6, lane = threadIdx.x & 63;
    int i = blockIdx.x*4 + wid;
    int nodei = (i<1024) ? (b*1024 + i) : (NI + b*512 + (i-1024));
    float ki = score[nodei];
    int r = 0;
    #pragma unroll
    for(int s=0;s<24;s++){
        int j = s*64 + lane;
        int nodej = (j<1024) ? (b*1024 + j) : (NI + b*512 + (j-1024));
        float kj = score[nodej];
        r += (kj > ki) || (kj == ki && j < i);
    }
    #pragma unroll
    for(int m=32;m;m>>=1) r += __shfl_xor(r, m);
    if(lane==0 && r < KPOOL){
        sel_node[b*KPOOL + r] = nodei;
        sel_scale[b*KPOOL + r] = tanhf(ki + bias[0]);
    }
}

__global__ void gather_xp(const int* __restrict__ sel, const float* __restrict__ scale,
                          const float* __restrict__ xi, const float* __restrict__ xd,
                          float* __restrict__ xp, u16* __restrict__ bh, u16* __restrict__ bl){
    int i = blockIdx.x*256 + threadIdx.x;
    int rowp = i >> 8, c = i & 255;
    int node = sel[rowp];
    float s = scale[rowp];
    float v = (node < NI) ? xi[(size_t)node*DD + c] : xd[(size_t)(node-NI)*DD + c];
    float x = v*s;
    xp[i] = x;
    u16 hh = f2b(x);
    bh[i] = hh;
    bl[i] = f2b(x - b2f(hh));
}

// ---------------- MFMA flash attention: block per (bh, 64 q rows), plain-bf16 QKV ----------------
__global__ __launch_bounds__(256) void attn_mfma(const u16* __restrict__ Qh,
                                                 const u16* __restrict__ Kh,
                                                 const u16* __restrict__ Vh,
                                                 u16* __restrict__ aoh, u16* __restrict__ aol){
    __shared__ u16 KhS[64*64], VtS[64*64];
    char* KhB = (char*)KhS; char* VtB = (char*)VtS;
    int bh = blockIdx.x;
    int b = bh >> 2, h = bh & 3;
    int q0 = blockIdx.y * 64;
    int tid = threadIdx.x;
    int lane = tid & 63;
    int w = tid >> 6;
    int l15 = lane & 15, l4 = lane >> 4;
    size_t qrow = (size_t)(b*KPOOL + q0 + w*16 + l15);
    bf16x8 qh[2];
    #pragma unroll
    for(int c=0;c<2;c++)
        qh[c] = *(const bf16x8*)(Qh + qrow*DD + h*64 + c*32 + l4*8);
    float mreg = -INFINITY, lreg = 0.f;
    f32x4 O[4] = {};
    for(int k0=0;k0<KPOOL;k0+=64){
        __syncthreads();
        {
            int row = tid >> 2, q4 = tid & 3;
            size_t gbase = ((size_t)(b*KPOOL + k0 + row))*DD + h*64 + q4*16;
            bf16x8 k0v = *(const bf16x8*)(Kh + gbase);
            bf16x8 k1v = *(const bf16x8*)(Kh + gbase + 8);
            int sw = (row&7)<<4;
            int colb = q4*32;
            *(bf16x8*)(KhB + row*128 + (colb ^ sw))      = k0v;
            *(bf16x8*)(KhB + row*128 + ((colb+16) ^ sw)) = k1v;
            int row0 = (tid >> 3)*2, dhg = (tid & 7)*8;
            size_t vbase = ((size_t)(b*KPOOL + k0 + row0))*DD + h*64 + dhg;
            bf16x8 va = *(const bf16x8*)(Vh + vbase);
            bf16x8 vb = *(const bf16x8*)(Vh + vbase + DD);
            #pragma unroll
            for(int j=0;j<8;j++){
                int dh = dhg + j;
                uint32_t pk = (uint32_t)(u16)(short)va[j] | ((uint32_t)(u16)(short)vb[j] << 16);
                *(uint32_t*)(VtB + dh*128 + ((row0*2) ^ ((dh&7)<<4))) = pk;
            }
        }
        __syncthreads();
        f32x4 s[4] = {};
        #pragma unroll
        for(int t=0;t<4;t++){
            int arow = t*16 + l15;
            int sw = (arow&7)<<4;
            const char* bh_ = KhB + arow*128;
            bf16x8 kh0 = *(const bf16x8*)(bh_ + ((l4*16) ^ sw));
            bf16x8 kh1 = *(const bf16x8*)(bh_ + ((l4*16 + 64) ^ sw));
            s[t] = __builtin_amdgcn_mfma_f32_16x16x32_bf16(kh0, qh[0], s[t], 0,0,0);
            s[t] = __builtin_amdgcn_mfma_f32_16x16x32_bf16(kh1, qh[1], s[t], 0,0,0);
        }
        float cm = -INFINITY;
        #pragma unroll
        for(int t=0;t<4;t++)
            #pragma unroll
            for(int r=0;r<4;r++){ s[t][r] *= 0.125f; cm = fmaxf(cm, s[t][r]); }
        cm = fmaxf(cm, __shfl_xor(cm,16));
        cm = fmaxf(cm, __shfl_xor(cm,32));
        float nm = fmaxf(mreg, cm);
        float es = expf(mreg - nm);
        float ps = 0.f;
        #pragma unroll
        for(int t=0;t<4;t++)
            #pragma unroll
            for(int r=0;r<4;r++){ float pv = expf(s[t][r] - nm); s[t][r] = pv; ps += pv; }
        ps += __shfl_xor(ps,16);
        ps += __shfl_xor(ps,32);
        lreg = lreg*es + ps;
        mreg = nm;
        #pragma unroll
        for(int d=0;d<4;d++){ O[d][0]*=es; O[d][1]*=es; O[d][2]*=es; O[d][3]*=es; }
        #pragma unroll
        for(int c32=0;c32<2;c32++){
            bf16x8 pb;
            #pragma unroll
            for(int j=0;j<8;j++){
                int srcl = ((((lane>>4)*2 + (j>>2)) & 3) << 4) | l15;
                float v0 = __shfl(s[c32*2+0][j&3], srcl, 64);
                float v1 = __shfl(s[c32*2+1][j&3], srcl, 64);
                float v = (lane < 32) ? v0 : v1;
                pb[j] = (short)f2b(v);
            }
            #pragma unroll
            for(int dhb=0; dhb<4; dhb++){
                int vrow = dhb*16 + l15;
                bf16x8 va = *(const bf16x8*)(VtB + vrow*128 + ((c32*64 + l4*16) ^ ((vrow&7)<<4)));
                O[dhb] = __builtin_amdgcn_mfma_f32_16x16x32_bf16(va, pb, O[dhb], 0,0,0);
            }
        }
    }
    float inv = 1.f/lreg;
    #pragma unroll
    for(int dhb=0;dhb<4;dhb++)
        #pragma unroll
        for(int r=0;r<4;r++){
            float val = O[dhb][r]*inv;
            size_t o = qrow*DD + h*64 + dhb*16 + l4*4 + r;
            u16 hh = f2b(val);
            aoh[o] = hh;
            aol[o] = f2b(val - b2f(hh));
        }
}

// layernorm row kernel
__global__ __launch_bounds__(256) void ln_kernel(const float* __restrict__ xp, const float* __restrict__ o2,
                                                 const float* __restrict__ lg, const float* __restrict__ lb,
                                                 float* __restrict__ gatt){
    __shared__ float red[256];
    int r = blockIdx.x, c = threadIdx.x;
    float y = xp[(size_t)r*DD + c] + o2[(size_t)r*DD + c];
    red[c] = y; __syncthreads();
    for(int s=128;s;s>>=1){ if(c<s) red[c] += red[c+s]; __syncthreads(); }
    float mu = red[0]*(1.f/DD);
    __syncthreads();
    float d = y - mu;
    red[c] = d*d; __syncthreads();
    for(int s=128;s;s>>=1){ if(c<s) red[c] += red[c+s]; __syncthreads(); }
    float var = red[0]*(1.f/DD);
    gatt[(size_t)r*DD + c] = lg[c]*d/sqrtf(var+1e-5f) + lb[c];
}

__global__ void feat_reduce2(const float* __restrict__ xp, const float* __restrict__ gatt,
                             float* __restrict__ out){
    int b = blockIdx.x, c = threadIdx.x;
    int j0 = blockIdx.y*64;
    float s1=0.f, s2=0.f;
    for(int j=j0;j<j0+64;j++){
        size_t base = ((size_t)(b*KPOOL + j))*DD + c;
        s1 += xp[base];
        s2 += gatt[base];
    }
    atomicAdd(&out[b*512 + c], s1);
    atomicAdd(&out[b*512 + 256 + c], s2);
}

__global__ void cosine_kernel(const float* __restrict__ u, const float* __restrict__ v,
                              float* __restrict__ out){
    int b = blockIdx.x, t = threadIdx.x;
    float du=0.f, nu=0.f, nv=0.f;
    for(int j=t;j<512;j+=64){
        float a = u[b*512+j], bb = v[b*512+j];
        du += a*bb; nu += a*a; nv += bb*bb;
    }
    for(int m=32;m;m>>=1){
        du += __shfl_xor(du,m); nu += __shfl_xor(nu,m); nv += __shfl_xor(nv,m);
    }
    if(t==0) out[b] = du / (fmaxf(sqrtf(nu),1e-8f)*fmaxf(sqrtf(nv),1e-8f));
}

// =======================================================================
extern "C" void kernel_launch(void* const* d_in, const int* in_sizes, int n_in,
                              void* d_out, int out_size, void* d_ws, size_t ws_size,
                              hipStream_t stream){
    (void)in_sizes; (void)n_in; (void)out_size; (void)ws_size;
    const float* hgt_Wk   = (const float*)d_in[12];
    const float* hgt_Wq   = (const float*)d_in[13];
    const float* hgt_Wv   = (const float*)d_in[14];
    const float* hgt_Wo   = (const float*)d_in[15];
    const float* hgt_arel = (const float*)d_in[16];
    const float* hgt_mrel = (const float*)d_in[17];
    const float* hgt_prel = (const float*)d_in[18];
    const float* hgt_skip = (const float*)d_in[19];
    const float* pool_W   = (const float*)d_in[20];
    const float* pool_att = (const float*)d_in[21];
    const float* pool_bias= (const float*)d_in[22];
    const float* t_wq     = (const float*)d_in[23];
    const float* t_wk     = (const float*)d_in[24];
    const float* t_wv     = (const float*)d_in[25];
    const float* t_wo     = (const float*)d_in[26];
    const float* ln_g     = (const float*)d_in[27];
    const float* ln_b     = (const float*)d_in[28];
    float* out = (float*)d_out;

    char* base = (char*)d_ws;
    size_t off = 0;
    auto allocb = [&](size_t nbytes)->void*{
        void* p = (void*)(base + off);
        off += ((nbytes + 255) & ~(size_t)255);
        return p;
    };
    const size_t MAT = 65536;
    // ---- persistent ----
    u16* bwtk_h = (u16*)allocb(16*MAT*2); u16* bwtk_l = (u16*)allocb(16*MAT*2);
    u16* bwtv_h = (u16*)allocb(16*MAT*2); u16* bwtv_l = (u16*)allocb(16*MAT*2);
    u16* bwq_h  = (u16*)allocb(8*MAT*2);  u16* bwq_l  = (u16*)allocb(8*MAT*2);
    u16* bwo_h  = (u16*)allocb(8*MAT*2);  u16* bwo_l  = (u16*)allocb(8*MAT*2);
    u16* btw_h  = (u16*)allocb(4*MAT*2);  u16* btw_l  = (u16*)allocb(4*MAT*2);
    float* ubuf = (float*)allocb(BB*512*4);
    float* vbuf = (float*)allocb(BB*512*4);
    float* xa_i = (float*)allocb((size_t)NI*DD*4);
    float* xa_d = (float*)allocb((size_t)ND*DD*4);
    float* xb_i = (float*)allocb((size_t)NI*DD*4);
    float* xb_d = (float*)allocb((size_t)ND*DD*4);
    // ---- per-branch CSR ----
    uint32_t* ccnt   = (uint32_t*)allocb((size_t)2*NROW*4);
    uint32_t* rowptr = (uint32_t*)allocb((size_t)(2*NROW+1)*4);
    uint32_t* einfo  = (uint32_t*)allocb((size_t)2*EHGT*4);
    size_t region = off;
    // ---- conv scratch ----
    float* q_i  = (float*)allocb((size_t)NI*DD*4);
    float* q_d  = (float*)allocb((size_t)ND*DD*4);
    u16* ka16 = (u16*)allocb((size_t)4*NI*DD*2);   // bf16 KA; also combine f32 temp
    u16* vm16 = (u16*)allocb((size_t)4*NI*DD*2);
    float* xacc_i= (float*)allocb((size_t)NI*DD*4);
    float* xacc_d= (float*)allocb((size_t)ND*DD*4);
    u16* bcur_h = (u16*)allocb((size_t)NROW*DD*2);
    u16* bcur_l = (u16*)allocb((size_t)NROW*DD*2);
    u16* bagg_h = (u16*)allocb((size_t)NROW*DD*2);
    u16* bagg_l = (u16*)allocb((size_t)NROW*DD*2);
    // ---- pooling/transformer overlay ----
    off = region;
    float* hvec = (float*)allocb(NROW*4);
    float* pscore = (float*)allocb(NROW*4);
    int* seln   = (int*)allocb(BB*KPOOL*4);
    float* sels = (float*)allocb(BB*KPOOL*4);
    float* xp   = (float*)allocb((size_t)BB*KPOOL*DD*4);
    float* o2   = (float*)allocb((size_t)BB*KPOOL*DD*4);
    float* gatt = (float*)allocb((size_t)BB*KPOOL*DD*4);
    u16* bxp_h = (u16*)allocb((size_t)BB*KPOOL*DD*2);
    u16* bxp_l = (u16*)allocb((size_t)BB*KPOOL*DD*2);
    u16* qbh = (u16*)allocb((size_t)BB*KPOOL*DD*2);
    u16* kbh = (u16*)allocb((size_t)BB*KPOOL*DD*2);
    u16* vbh = (u16*)allocb((size_t)BB*KPOOL*DD*2);
    u16* bao_h = (u16*)allocb((size_t)BB*KPOOL*DD*2);
    u16* bao_l = (u16*)allocb((size_t)BB*KPOOL*DD*2);

    const int st_tab[2][4] = {{0,1,0,0},{0,0,1,0}};
    const int dt_tab[2][4] = {{0,0,1,0},{0,1,0,0}};
    const int MR = BB*KPOOL;

    fill_u32<<<(2*BB*512+255)/256,256,0,stream>>>((uint32_t*)ubuf, 0u, 2*BB*512);
    float* wtkF = (float*)ka16;
    float* wtvF = (float*)ka16 + 16*MAT;
    combine_all<<<dim3(256,32),256,0,stream>>>(hgt_Wk, hgt_Wv, hgt_arel, hgt_mrel, wtkF, wtvF);
    WCArgs wc;
    wc.in[0]=wtkF;   wc.oh[0]=bwtk_h; wc.ol[0]=bwtk_l; wc.cnt[0]=16;
    wc.in[1]=wtvF;   wc.oh[1]=bwtv_h; wc.ol[1]=bwtv_l; wc.cnt[1]=16;
    wc.in[2]=hgt_Wq; wc.oh[2]=bwq_h;  wc.ol[2]=bwq_l;  wc.cnt[2]=8;
    wc.in[3]=hgt_Wo; wc.oh[3]=bwo_h;  wc.ol[3]=bwo_l;  wc.cnt[3]=8;
    wc.in[4]=t_wq;   wc.oh[4]=btw_h;          wc.ol[4]=btw_l;          wc.cnt[4]=1;
    wc.in[5]=t_wk;   wc.oh[5]=btw_h+1*MAT;    wc.ol[5]=btw_l+1*MAT;    wc.cnt[5]=1;
    wc.in[6]=t_wv;   wc.oh[6]=btw_h+2*MAT;    wc.ol[6]=btw_l+2*MAT;    wc.cnt[6]=1;
    wc.in[7]=t_wo;   wc.oh[7]=btw_h+3*MAT;    wc.ol[7]=btw_l+3*MAT;    wc.cnt[7]=1;
    wc.nr = 8;
    wcvt_split<<<dim3(256,52),256,0,stream>>>(wc);

    for(int bi=0;bi<2;bi++){
        int ib = bi*6;
        const float* x_inst = (const float*)d_in[ib+0];
        const float* x_data = (const float*)d_in[ib+1];
        const int* ecp = (const int*)d_in[ib+2];
        const int* eip = (const int*)d_in[ib+3];
        const int* eop = (const int*)d_in[ib+4];
        const int* ekp = (const int*)d_in[ib+5];
        const int* rows_f[4] = {ecp, eip, eop, ekp};
        const int* cols_f[4] = {ecp+EC, eip+EI, eop+EO, ekp+EK};

        // ---- CSR build (both dirs, one pass) ----
        CB2 cb;
        for(int r=0;r<4;r++){
            cb.row[r]   = rows_f[r]; cb.col[r]   = cols_f[r]; cb.dt[r]   = dt_tab[0][r]; cb.st[r]   = st_tab[0][r];
            cb.row[4+r] = cols_f[r]; cb.col[4+r] = rows_f[r]; cb.dt[4+r] = dt_tab[1][r]; cb.st[4+r] = st_tab[1][r];
        }
        cb.cnt = ccnt; cb.rowptr = rowptr; cb.einfo = einfo;
        fill_u32<<<(2*NROW+255)/256,256,0,stream>>>(ccnt, 0u, 2*NROW);
        csr_hist2<<<(2*EHGT+255)/256,256,0,stream>>>(cb);
        scan_rowptr2<<<1,1024,0,stream>>>(ccnt, rowptr);
        csr_scatter2<<<(2*EHGT+255)/256,256,0,stream>>>(cb);

        const float* cur_i = x_inst;
        const float* cur_d = x_data;
        cvt_split<<<((NROW*DD/4)+255)/256,256,0,stream>>>(cur_i, NI*DD, cur_d, ND*DD, bcur_h, bcur_l);
        for(int l=0;l<LL;l++){
            float* nxt_i = (l==0) ? xa_i : xb_i;
            float* nxt_d = (l==0) ? xa_d : xb_d;
            for(int dir=0;dir<2;dir++){
                int wb = l*2 + dir;

                // --- mega GEMM: Q(2, f32, split) + KA(4, bf16, prec=1) + VM(4, bf16, prec=1) ---
                GArgs g1; int nb1 = 0, ndx = 0;
                auto addg = [&](int srctype, const u16* Bh, const u16* Bl, float* Cm, u16* Om, int M, int mode, int prec){
                    GDesc& d = g1.d[ndx];
                    size_t ao = srctype ? (size_t)NI*DD : 0;
                    d.Ah = bcur_h + ao; d.Al = bcur_l + ao;
                    d.Bh = Bh; d.Bl = Bl; d.C = Cm;
                    d.Oh = Om; d.Ol = nullptr; d.X = nullptr; d.Xacc = nullptr; d.skipp = nullptr;
                    d.mblks = M/128; d.mode = mode; d.prec = prec;
                    nb1 += M/128; ndx++;
                };
                addg(0, bwq_h + (size_t)(wb*2+0)*MAT, bwq_l + (size_t)(wb*2+0)*MAT, q_i, nullptr, NI, 0, 0);
                addg(1, bwq_h + (size_t)(wb*2+1)*MAT, bwq_l + (size_t)(wb*2+1)*MAT, q_d, nullptr, ND, 0, 0);
                for(int r=0;r<4;r++){
                    int st = st_tab[dir][r];
                    addg(st, bwtk_h + (size_t)(wb*4+r)*MAT, bwtk_l + (size_t)(wb*4+r)*MAT,
                         nullptr, ka16 + (size_t)r*NI*DD, st ? ND : NI, 4, 1);
                }
                for(int r=0;r<4;r++){
                    int st = st_tab[dir][r];
                    addg(st, bwtv_h + (size_t)(wb*4+r)*MAT, bwtv_l + (size_t)(wb*4+r)*MAT,
                         nullptr, vm16 + (size_t)r*NI*DD, st ? ND : NI, 4, 1);
                }
                g1.nd = ndx;
                gemm_mfma<<<dim3(nb1,2),256,0,stream>>>(g1);

                // --- fused edge phase ---
                hgt_fused<<<NROW/4,256,0,stream>>>(rowptr + (size_t)dir*NROW, einfo,
                    q_i, q_d, ka16, vm16, hgt_prel + (size_t)wb*4*HH, bagg_h, bagg_l);

                // --- Wo GEMMs with fused skip/relu epilogue (split) ---
                GArgs g3; g3.nd = 2;
                for(int t=0;t<2;t++){
                    GDesc& d = g3.d[t];
                    size_t ao = t ? (size_t)NI*DD : 0;
                    d.Ah = bagg_h + ao; d.Al = bagg_l + ao;
                    d.Bh = bwo_h + (size_t)(wb*2+t)*MAT; d.Bl = bwo_l + (size_t)(wb*2+t)*MAT;
                    d.C = t ? nxt_d : nxt_i;
                    d.Oh = bcur_h + ao; d.Ol = bcur_l + ao;
                    d.X = t ? cur_d : cur_i;
                    d.Xacc = t ? xacc_d : xacc_i;
                    d.skipp = hgt_skip + wb*2 + t;
                    d.mblks = (t ? ND : NI)/128;
                    d.mode = dir ? 3 : 2;
                    d.prec = 0;
                }
                gemm_mfma<<<dim3(NI/128 + ND/128,2),256,0,stream>>>(g3);
            }
            cur_i = nxt_i;
            cur_d = nxt_d;
        }

        // -------- SAGPooling (CSR-based, no atomics) --------
        pool_h2<<<NROW/4,256,0,stream>>>(cur_i, cur_d, pool_W, hvec);
        pool_csr<<<NROW/4,256,0,stream>>>(rowptr, einfo, hvec, pool_att, pscore);
        topk_rank<<<dim3(384,BB),256,0,stream>>>(pscore, pool_bias, seln, sels);
        gather_xp<<<BB*KPOOL,256,0,stream>>>(seln, sels, cur_i, cur_d, xp, bxp_h, bxp_l);

        // -------- transformer --------
        GArgs g4; g4.nd = 3;
        for(int t=0;t<3;t++){
            GDesc& d = g4.d[t];
            d.Ah=bxp_h; d.Al=bxp_l;
            d.Bh=btw_h + (size_t)t*MAT; d.Bl=btw_l + (size_t)t*MAT;
            d.C = nullptr;
            d.Oh = (t==0)? qbh : (t==1)? kbh : vbh;
            d.Ol = nullptr;
            d.X = nullptr; d.Xacc = nullptr; d.skipp = nullptr;
            d.mblks = MR/128; d.mode = 4; d.prec = 0;
        }
        gemm_mfma<<<dim3(3*(MR/128),2),256,0,stream>>>(g4);
        attn_mfma<<<dim3(BB*HH, KPOOL/64),256,0,stream>>>(qbh, kbh, vbh, bao_h, bao_l);
        GArgs g5; g5.nd = 1;
        {
            GDesc& d = g5.d[0];
            d.Ah=bao_h; d.Al=bao_l;
            d.Bh=btw_h + (size_t)3*MAT; d.Bl=btw_l + (size_t)3*MAT;
            d.C=o2; d.Oh=nullptr; d.Ol=nullptr; d.X=nullptr; d.Xacc=nullptr; d.skipp=nullptr;
            d.mblks=MR/128; d.mode=0; d.prec=0;
        }
        gemm_mfma<<<dim3(MR/128,2),256,0,stream>>>(g5);
        ln_kernel<<<MR,256,0,stream>>>(xp, o2, ln_g, ln_b, gatt);
        feat_reduce2<<<dim3(BB,12),256,0,stream>>>(xp, gatt, bi ? vbuf : ubuf);
    }

    cosine_kernel<<<BB,64,0,stream>>>(ubuf, vbuf, out);
}

// Round 22
// 951.033 us; speedup vs baseline: 2.0448x; 1.0266x over previous
//
#include <hip/hip_runtime.h>
#include <math.h>
#include <stdint.h>

#define LL 2
#define HH 4
#define DHH 64
#define DD 256
#define BB 8
#define NI 8192
#define ND 4096
#define NROW 12288
#define KPOOL 768
#define EC 65536
#define EI 32768
#define EO 32768
#define EK 8192
#define EHGT (EC+EI+EO+EK)

typedef unsigned short u16;
typedef short bf16x8 __attribute__((ext_vector_type(8)));
typedef float f32x4 __attribute__((ext_vector_type(4)));
typedef unsigned short u16x4 __attribute__((ext_vector_type(4)));

__device__ inline float gelu_f(float x){ return 0.5f*x*(1.f+erff(x*0.70710678118654752f)); }
__device__ inline u16 f2b(float x){ uint32_t u=__float_as_uint(x); return (u16)((u + 0x7fffu + ((u>>16)&1u))>>16); }
__device__ inline float b2f(u16 h){ return __uint_as_float(((uint32_t)h)<<16); }

// ---------------- generic fill ----------------
__global__ void fill_u32(uint32_t* p, uint32_t v, int n){
    int i = blockIdx.x*256 + threadIdx.x;
    if(i<n) p[i]=v;
}

// ---------------- activation split-convert ----------------
__global__ void cvt_split(const float* __restrict__ A, int nA, const float* __restrict__ B, int nB,
                          u16* __restrict__ oh, u16* __restrict__ ol){
    int i = (blockIdx.x*256 + threadIdx.x)*4;
    int tot = nA + nB;
    if(i >= tot) return;
    float4 v = (i < nA) ? *(const float4*)(A + i) : *(const float4*)(B + (i - nA));
    float vv[4] = {v.x, v.y, v.z, v.w};
    u16x4 h4, l4;
    #pragma unroll
    for(int j=0;j<4;j++){
        float x = vv[j];
        u16 h = f2b(x);
        h4[j] = h;
        l4[j] = f2b(x - b2f(h));
    }
    *(u16x4*)(oh + i) = h4;
    *(u16x4*)(ol + i) = l4;
}

// ---------------- weight transpose + split ----------------
struct WCArgs { const float* in[8]; u16* oh[8]; u16* ol[8]; int cnt[8]; int nr; };
__global__ void wcvt_split(WCArgs a){
    int mat = blockIdx.y, ri = 0;
    while(ri < a.nr-1 && mat >= a.cnt[ri]){ mat -= a.cnt[ri]; ri++; }
    const float* in = a.in[ri] + (size_t)mat*65536;
    u16* oh = a.oh[ri] + (size_t)mat*65536;
    u16* ol = a.ol[ri] + (size_t)mat*65536;
    int n = blockIdx.x, k = threadIdx.x;
    float x = in[(size_t)k*DD + n];
    u16 h = f2b(x);
    oh[n*DD + k] = h;
    ol[n*DD + k] = f2b(x - b2f(h));
}

// ---------------- MFMA batched GEMM with fused, LDS-restaged epilogues ----------------
// prec=0: split hi/lo (3 MFMA/step); prec=1: hi-only (1 MFMA/step, half staging)
// mode 0: C=f32   mode 1: Oh/Ol=split bf16   mode 4: Oh=plain bf16
// mode 2: Xacc = 0.5*(g*acc + (1-g)*X)
// mode 3: v=relu(Xacc + 0.5*(g*acc+(1-g)*X)); C=v; Oh/Ol=split(v)
struct GDesc { const u16* Ah; const u16* Al; const u16* Bh; const u16* Bl;
               float* C; u16* Oh; u16* Ol;
               const float* X; float* Xacc; const float* skipp;
               int mblks; int mode; int prec; };
struct GArgs { GDesc d[20]; int nd; };

__global__ __launch_bounds__(256) void gemm_mfma(GArgs ga){
    __shared__ u16 SBUF[2*128*64];
    char* Abuf = (char*)SBUF;
    char* Bbuf = (char*)(SBUF + 128*64);
    int mb = blockIdx.x, di = 0;
    while(di < ga.nd-1 && mb >= ga.d[di].mblks){ mb -= ga.d[di].mblks; di++; }
    GDesc g = ga.d[di];
    const int prec = g.prec;
    const int m0 = mb*128, n0 = blockIdx.y*128;
    const int tid = threadIdx.x;
    const int lane = tid & 63, wid = tid >> 6;
    const int wm = (wid>>1)*64, wn = (wid&1)*64;
    const int l15 = lane & 15, l4 = lane >> 4;
    const int srow = tid >> 1, hf = tid & 1;
    const int ssw = (srow&7)<<4;
    const int c0 = (hf*32) ^ ssw;
    const int c1 = (hf*32+16) ^ ssw;
    const int c2 = (64+hf*32) ^ ssw;
    const int c3 = (64+hf*32+16) ^ ssw;
    const int rbyte = srow*128;
    const u16* __restrict__ Aph = g.Ah + (size_t)(m0 + srow)*DD + hf*16;
    const u16* __restrict__ Apl = g.Al + (size_t)(m0 + srow)*DD + hf*16;
    const u16* __restrict__ Bph = g.Bh + (size_t)(n0 + srow)*DD + hf*16;
    const u16* __restrict__ Bpl = g.Bl + (size_t)(n0 + srow)*DD + hf*16;
    f32x4 acc[4][4] = {};
    bf16x8 r0, r1, r2, r3, r4, r5, r6, r7;
    r0 = *(const bf16x8*)(Aph);
    r1 = *(const bf16x8*)(Aph + 8);
    r4 = *(const bf16x8*)(Bph);
    r5 = *(const bf16x8*)(Bph + 8);
    if(!prec){
        r2 = *(const bf16x8*)(Apl);
        r3 = *(const bf16x8*)(Apl + 8);
        r6 = *(const bf16x8*)(Bpl);
        r7 = *(const bf16x8*)(Bpl + 8);
    }
    #pragma unroll
    for(int k0=0;k0<DD;k0+=32){
        __syncthreads();
        *(bf16x8*)(Abuf + rbyte + c0) = r0; *(bf16x8*)(Abuf + rbyte + c1) = r1;
        *(bf16x8*)(Bbuf + rbyte + c0) = r4; *(bf16x8*)(Bbuf + rbyte + c1) = r5;
        if(!prec){
            *(bf16x8*)(Abuf + rbyte + c2) = r2; *(bf16x8*)(Abuf + rbyte + c3) = r3;
            *(bf16x8*)(Bbuf + rbyte + c2) = r6; *(bf16x8*)(Bbuf + rbyte + c3) = r7;
        }
        __syncthreads();
        if(k0 + 32 < DD){
            int kn = k0 + 32;
            r0 = *(const bf16x8*)(Aph + kn);     r1 = *(const bf16x8*)(Aph + kn + 8);
            r4 = *(const bf16x8*)(Bph + kn);     r5 = *(const bf16x8*)(Bph + kn + 8);
            if(!prec){
                r2 = *(const bf16x8*)(Apl + kn); r3 = *(const bf16x8*)(Apl + kn + 8);
                r6 = *(const bf16x8*)(Bpl + kn); r7 = *(const bf16x8*)(Bpl + kn + 8);
            }
        }
        bf16x8 afh[4], bfh[4];
        #pragma unroll
        for(int i=0;i<4;i++){
            int ar = wm + i*16 + l15;
            int abase = ar*128;
            afh[i] = *(const bf16x8*)(Abuf + abase + ((l4*16) ^ ((ar&7)<<4)));
            int br = wn + i*16 + l15;
            int bbase = br*128;
            bfh[i] = *(const bf16x8*)(Bbuf + bbase + ((l4*16) ^ ((br&7)<<4)));
        }
        #pragma unroll
        for(int i=0;i<4;i++)
            #pragma unroll
            for(int j=0;j<4;j++)
                acc[i][j] = __builtin_amdgcn_mfma_f32_16x16x32_bf16(afh[i], bfh[j], acc[i][j], 0,0,0);
        if(!prec){
            bf16x8 afl[4], bfl[4];
            #pragma unroll
            for(int i=0;i<4;i++){
                int ar = wm + i*16 + l15;
                int abase = ar*128;
                afl[i] = *(const bf16x8*)(Abuf + abase + ((64 + l4*16) ^ ((ar&7)<<4)));
                int br = wn + i*16 + l15;
                int bbase = br*128;
                bfl[i] = *(const bf16x8*)(Bbuf + bbase + ((64 + l4*16) ^ ((br&7)<<4)));
            }
            #pragma unroll
            for(int i=0;i<4;i++)
                #pragma unroll
                for(int j=0;j<4;j++){
                    acc[i][j] = __builtin_amdgcn_mfma_f32_16x16x32_bf16(afh[i], bfl[j], acc[i][j], 0,0,0);
                    acc[i][j] = __builtin_amdgcn_mfma_f32_16x16x32_bf16(afl[i], bfh[j], acc[i][j], 0,0,0);
                }
        }
    }
    // ---- coalesced epilogue via LDS restage (two 64-row passes) ----
    const int mode = g.mode;
    float gg = 0.f;
    if(mode == 2 || mode == 3) gg = 1.f/(1.f + expf(-*g.skipp));
    float* LDSf = (float*)SBUF;
    const int lrow = tid >> 5;
    const int cc4 = (tid & 31)*4;
    #pragma unroll
    for(int half=0; half<2; half++){
        __syncthreads();
        if((wid>>1) == half){
            #pragma unroll
            for(int i=0;i<4;i++)
                #pragma unroll
                for(int j=0;j<4;j++)
                    #pragma unroll
                    for(int r=0;r<4;r++)
                        LDSf[(i*16 + l4*4 + r)*128 + wn + j*16 + l15] = acc[i][j][r];
        }
        __syncthreads();
        #pragma unroll
        for(int k=0;k<8;k++){
            int row = lrow + k*8;
            size_t o = (size_t)(m0 + half*64 + row)*DD + n0 + cc4;
            float4 v = *(const float4*)&LDSf[row*128 + cc4];
            float vv[4] = {v.x, v.y, v.z, v.w};
            if(mode==0){
                *(float4*)(g.C + o) = v;
            } else if(mode==4){
                u16x4 h4;
                #pragma unroll
                for(int j=0;j<4;j++) h4[j] = f2b(vv[j]);
                *(u16x4*)(g.Oh + o) = h4;
            } else if(mode==1){
                u16x4 h4, lo4;
                #pragma unroll
                for(int j=0;j<4;j++){
                    u16 hh = f2b(vv[j]); h4[j]=hh; lo4[j]=f2b(vv[j]-b2f(hh));
                }
                *(u16x4*)(g.Oh + o) = h4;
                *(u16x4*)(g.Ol + o) = lo4;
            } else if(mode==2){
                float4 x = *(const float4*)(g.X + o);
                float xx[4] = {x.x, x.y, x.z, x.w};
                float4 w;
                float* ww = (float*)&w;
                #pragma unroll
                for(int j=0;j<4;j++) ww[j] = 0.5f*(gg*vv[j] + (1.f-gg)*xx[j]);
                *(float4*)(g.Xacc + o) = w;
            } else {
                float4 x = *(const float4*)(g.X + o);
                float4 xa = *(const float4*)(g.Xacc + o);
                float xx[4] = {x.x, x.y, x.z, x.w};
                float aa[4] = {xa.x, xa.y, xa.z, xa.w};
                float4 cv;
                float* cvv = (float*)&cv;
                u16x4 h4, lo4;
                #pragma unroll
                for(int j=0;j<4;j++){
                    float v3 = aa[j] + 0.5f*(gg*vv[j] + (1.f-gg)*xx[j]);
                    v3 = v3 > 0.f ? v3 : 0.f;
                    cvv[j] = v3;
                    u16 hh = f2b(v3); h4[j]=hh; lo4[j]=f2b(v3-b2f(hh));
                }
                *(float4*)(g.C + o) = cv;
                *(u16x4*)(g.Oh + o) = h4;
                *(u16x4*)(g.Ol + o) = lo4;
            }
        }
    }
}

// ---------- combine ----------
__global__ void combine_all(const float* __restrict__ Wk, const float* __restrict__ Wv,
                            const float* __restrict__ Ra, const float* __restrict__ Rm,
                            float* __restrict__ wtk, float* __restrict__ wtv){
    const int st_tab[2][4] = {{0,1,0,0},{0,0,1,0}};
    int combo = blockIdx.y;
    int idx = combo >> 1, kv = combo & 1;
    int r = idx & 3, wb = idx >> 2, dir = wb & 1;
    int st = st_tab[dir][r];
    const float* W = (kv ? Wv : Wk) + (size_t)(wb*2 + st)*65536;
    const float* R = (kv ? Rm : Ra) + (size_t)idx*16384;
    float* o = (kv ? wtv : wtk) + (size_t)idx*65536;
    int d = blockIdx.x, c = threadIdx.x;
    int h = c >> 6, f = c & 63;
    const float* Wrow = W + d*DD + h*64;
    const float* Rh = R + h*4096 + f;
    float s = 0.f;
    #pragma unroll 8
    for(int k=0;k<64;k++) s += Wrow[k]*Rh[k*64];
    o[d*DD + c] = s;
}

// ---------------- CSR build (both directions in one pass) ----------------
__device__ inline void edge_decode(int e, int& r, int& el){
    if(e < EC){ r=0; el=e; }
    else if(e < EC+EI){ r=1; el=e-EC; }
    else if(e < EC+EI+EO){ r=2; el=e-(EC+EI); }
    else { r=3; el=e-(EC+EI+EO); }
}

struct CB2 {
    const int* row[8]; const int* col[8];
    int dt[8]; int st[8];
    uint32_t* cnt; uint32_t* rowptr; uint32_t* einfo;
};

__global__ void csr_hist2(CB2 a){
    int ge = blockIdx.x*256 + threadIdx.x;
    if(ge >= 2*EHGT) return;
    int dir = ge >= EHGT;
    int e = ge - dir*EHGT;
    int r, el; edge_decode(e, r, el);
    int idx = dir*4 + r;
    int c = a.col[idx][el];
    int dst = dir*NROW + (a.dt[idx] ? (NI + c) : c);
    atomicAdd(&a.cnt[dst], 1u);
}

__global__ __launch_bounds__(1024) void scan_rowptr2(uint32_t* cnt, uint32_t* rowptr){
    __shared__ uint32_t part[1024];
    int t = threadIdx.x;
    int base = t*24;
    uint32_t lpre[24];
    uint32_t sum = 0;
    #pragma unroll
    for(int i=0;i<24;i++){
        uint32_t c = cnt[base+i];
        lpre[i] = sum; sum += c;
        cnt[base+i] = 0;
    }
    part[t] = sum;
    __syncthreads();
    for(int offs=1; offs<1024; offs<<=1){
        uint32_t v = (t>=offs) ? part[t-offs] : 0u;
        __syncthreads();
        part[t] += v;
        __syncthreads();
    }
    uint32_t pre = (t==0) ? 0u : part[t-1];
    #pragma unroll
    for(int i=0;i<24;i++) rowptr[base+i] = pre + lpre[i];
    if(t==1023) rowptr[2*NROW] = part[1023];
}

__global__ void csr_scatter2(CB2 a){
    int ge = blockIdx.x*256 + threadIdx.x;
    if(ge >= 2*EHGT) return;
    int dir = ge >= EHGT;
    int e = ge - dir*EHGT;
    int r, el; edge_decode(e, r, el);
    int idx = dir*4 + r;
    int c = a.col[idx][el];
    int dst = dir*NROW + (a.dt[idx] ? (NI + c) : c);
    int src = a.row[idx][el];
    uint32_t p = a.rowptr[dst] + atomicAdd(&a.cnt[dst], 1u);
    uint32_t vmidx = (uint32_t)(r*NI + src);
    uint32_t hom = a.st[idx] ? (uint32_t)(NI + src) : (uint32_t)src;
    a.einfo[p] = vmidx | (hom << 16);
}

// ---------------- fused HGT edge phase: wave per dst, all 4 heads, online softmax ----------------
__global__ __launch_bounds__(256) void hgt_fused(const uint32_t* __restrict__ rowptr,
                                                 const uint32_t* __restrict__ einfo,
                                                 const float* __restrict__ q_i,
                                                 const float* __restrict__ q_d,
                                                 const u16* __restrict__ ka,
                                                 const u16* __restrict__ vm,
                                                 const float* __restrict__ prel,
                                                 u16* __restrict__ bagg_h,
                                                 u16* __restrict__ bagg_l){
    int wv = threadIdx.x >> 6, lane = threadIdx.x & 63;
    int rowi = blockIdx.x*4 + wv;
    uint32_t p0 = rowptr[rowi], p1 = rowptr[rowi+1];
    int h = lane >> 4;
    const float* qrow = (rowi < NI) ? (q_i + (size_t)rowi*DD) : (q_d + (size_t)(rowi-NI)*DD);
    float4 q4 = *(const float4*)(qrow + lane*4);
    float pr0 = prel[0*HH+h]*0.125f, pr1 = prel[1*HH+h]*0.125f;
    float pr2 = prel[2*HH+h]*0.125f, pr3 = prel[3*HH+h]*0.125f;
    float m = -INFINITY, den = 0.f;
    float4 o4 = {0.f,0.f,0.f,0.f};
    for(uint32_t p = p0; p < p1; p++){
        uint32_t vmidx = einfo[p] & 0xffffu;
        int r = vmidx >> 13;
        uint2 kr = *(const uint2*)(ka + (size_t)vmidx*DD + lane*4);
        uint2 vr = *(const uint2*)(vm + (size_t)vmidx*DD + lane*4);
        float k0 = __uint_as_float(kr.x << 16), k1 = __uint_as_float(kr.x & 0xffff0000u);
        float k2 = __uint_as_float(kr.y << 16), k3 = __uint_as_float(kr.y & 0xffff0000u);
        float v0 = __uint_as_float(vr.x << 16), v1 = __uint_as_float(vr.x & 0xffff0000u);
        float v2 = __uint_as_float(vr.y << 16), v3 = __uint_as_float(vr.y & 0xffff0000u);
        float d = q4.x*k0 + q4.y*k1 + q4.z*k2 + q4.w*k3;
        d += __shfl_xor(d, 1); d += __shfl_xor(d, 2);
        d += __shfl_xor(d, 4); d += __shfl_xor(d, 8);
        float pf = (r==0) ? pr0 : (r==1) ? pr1 : (r==2) ? pr2 : pr3;
        float s = d * pf;
        float nm = fmaxf(m, s);
        float sc_ = expf(m - nm);
        float pe = expf(s - nm);
        den = den*sc_ + pe;
        o4.x = o4.x*sc_ + pe*v0;
        o4.y = o4.y*sc_ + pe*v1;
        o4.z = o4.z*sc_ + pe*v2;
        o4.w = o4.w*sc_ + pe*v3;
        m = nm;
    }
    float inv = 1.f/(den + 1e-16f);
    float vals[4] = {o4.x*inv, o4.y*inv, o4.z*inv, o4.w*inv};
    u16x4 h4, l4;
    #pragma unroll
    for(int j=0;j<4;j++){
        float g = gelu_f(vals[j]);
        u16 hh = f2b(g);
        h4[j] = hh;
        l4[j] = f2b(g - b2f(hh));
    }
    size_t ob = (size_t)rowi*DD + lane*4;
    *(u16x4*)(bagg_h + ob) = h4;
    *(u16x4*)(bagg_l + ob) = l4;
}

// ---------------- pooling ----------------
__global__ void pool_h2(const float* __restrict__ xi, const float* __restrict__ xd,
                        const float* __restrict__ w, float* __restrict__ h){
    int node = blockIdx.x*4 + (threadIdx.x>>6);
    int lane = threadIdx.x & 63;
    const float* xr = (node < NI) ? (xi + (size_t)node*DD) : (xd + (size_t)(node-NI)*DD);
    float s = 0.f;
    for(int j=lane;j<DD;j+=64) s += xr[j]*w[j];
    for(int m=32;m;m>>=1) s += __shfl_xor(s, m);
    if(lane==0) h[node] = s;
}

// GAT-style pooling score via fwd CSR + implicit self-loop; wave per dst node
__global__ __launch_bounds__(256) void pool_csr(const uint32_t* __restrict__ rowptr,
                                                const uint32_t* __restrict__ einfo,
                                                const float* __restrict__ h,
                                                const float* __restrict__ att,
                                                float* __restrict__ score){
    int w = blockIdx.x*4 + (threadIdx.x >> 6);
    int lane = threadIdx.x & 63;
    if(w >= NROW) return;
    uint32_t p0 = rowptr[w], p1 = rowptr[w+1];
    float a0 = att[0], a1 = att[1];
    float hn = h[w];
    float es = a0*hn + a1*hn;
    es = es >= 0.f ? es : 0.2f*es;
    float m = -INFINITY;
    for(uint32_t p = p0+lane; p < p1; p += 64){
        float hs = h[einfo[p] >> 16];
        float e = a0*hs + a1*hn;
        e = e >= 0.f ? e : 0.2f*e;
        m = fmaxf(m, e);
    }
    #pragma unroll
    for(int s=32;s;s>>=1) m = fmaxf(m, __shfl_xor(m, s));
    m = fmaxf(m, es);
    float lden = 0.f, lnum = 0.f;
    for(uint32_t p = p0+lane; p < p1; p += 64){
        float hs = h[einfo[p] >> 16];
        float e = a0*hs + a1*hn;
        e = e >= 0.f ? e : 0.2f*e;
        float a = expf(e - m);
        lden += a; lnum += a*hs;
    }
    #pragma unroll
    for(int s=32;s;s>>=1){ lden += __shfl_xor(lden, s); lnum += __shfl_xor(lnum, s); }
    float aself = expf(es - m);
    lden += aself; lnum += aself*hn;
    if(lane==0) score[w] = lnum/(lden + 1e-16f);
}

// ---------------- top-768 of 1536 per graph: wave-per-candidate rank selection ----------------
__global__ __launch_bounds__(256) void topk_rank(const float* __restrict__ score,
                                                 const float* __restrict__ bias,
                                                 int* __restrict__ sel_node,
                                                 float* __restrict__ sel_scale){
    int b = blockIdx.y;
    int wid = threadIdx.x >> 6, lane = threadIdx.x & 63;
    int i = blockIdx.x*4 + wid;
    int nodei = (i<1024) ? (b*1024 + i) : (NI + b*512 + (i-1024));
    float ki = score[nodei];
    int r = 0;
    #pragma unroll
    for(int s=0;s<24;s++){
        int j = s*64 + lane;
        int nodej = (j<1024) ? (b*1024 + j) : (NI + b*512 + (j-1024));
        float kj = score[nodej];
        r += (kj > ki) || (kj == ki && j < i);
    }
    #pragma unroll
    for(int m=32;m;m>>=1) r += __shfl_xor(r, m);
    if(lane==0 && r < KPOOL){
        sel_node[b*KPOOL + r] = nodei;
        sel_scale[b*KPOOL + r] = tanhf(ki + bias[0]);
    }
}

__global__ void gather_xp(const int* __restrict__ sel, const float* __restrict__ scale,
                          const float* __restrict__ xi, const float* __restrict__ xd,
                          float* __restrict__ xp, u16* __restrict__ bh, u16* __restrict__ bl){
    int i = blockIdx.x*256 + threadIdx.x;
    int rowp = i >> 8, c = i & 255;
    int node = sel[rowp];
    float s = scale[rowp];
    float v = (node < NI) ? xi[(size_t)node*DD + c] : xd[(size_t)(node-NI)*DD + c];
    float x = v*s;
    xp[i] = x;
    u16 hh = f2b(x);
    bh[i] = hh;
    bl[i] = f2b(x - b2f(hh));
}

// ---------------- MFMA flash attention: block per (bh, 64 q rows), plain-bf16 QKV ----------------
__global__ __launch_bounds__(256) void attn_mfma(const u16* __restrict__ Qh,
                                                 const u16* __restrict__ Kh,
                                                 const u16* __restrict__ Vh,
                                                 u16* __restrict__ aoh, u16* __restrict__ aol){
    __shared__ u16 KhS[64*64], VtS[64*64];
    char* KhB = (char*)KhS; char* VtB = (char*)VtS;
    int bh = blockIdx.x;
    int b = bh >> 2, h = bh & 3;
    int q0 = blockIdx.y * 64;
    int tid = threadIdx.x;
    int lane = tid & 63;
    int w = tid >> 6;
    int l15 = lane & 15, l4 = lane >> 4;
    size_t qrow = (size_t)(b*KPOOL + q0 + w*16 + l15);
    bf16x8 qh[2];
    #pragma unroll
    for(int c=0;c<2;c++)
        qh[c] = *(const bf16x8*)(Qh + qrow*DD + h*64 + c*32 + l4*8);
    float mreg = -INFINITY, lreg = 0.f;
    f32x4 O[4] = {};
    for(int k0=0;k0<KPOOL;k0+=64){
        __syncthreads();
        {
            int row = tid >> 2, q4 = tid & 3;
            size_t gbase = ((size_t)(b*KPOOL + k0 + row))*DD + h*64 + q4*16;
            bf16x8 k0v = *(const bf16x8*)(Kh + gbase);
            bf16x8 k1v = *(const bf16x8*)(Kh + gbase + 8);
            int sw = (row&7)<<4;
            int colb = q4*32;
            *(bf16x8*)(KhB + row*128 + (colb ^ sw))      = k0v;
            *(bf16x8*)(KhB + row*128 + ((colb+16) ^ sw)) = k1v;
            int row0 = (tid >> 3)*2, dhg = (tid & 7)*8;
            size_t vbase = ((size_t)(b*KPOOL + k0 + row0))*DD + h*64 + dhg;
            bf16x8 va = *(const bf16x8*)(Vh + vbase);
            bf16x8 vb = *(const bf16x8*)(Vh + vbase + DD);
            #pragma unroll
            for(int j=0;j<8;j++){
                int dh = dhg + j;
                uint32_t pk = (uint32_t)(u16)(short)va[j] | ((uint32_t)(u16)(short)vb[j] << 16);
                *(uint32_t*)(VtB + dh*128 + ((row0*2) ^ ((dh&7)<<4))) = pk;
            }
        }
        __syncthreads();
        f32x4 s[4] = {};
        #pragma unroll
        for(int t=0;t<4;t++){
            int arow = t*16 + l15;
            int sw = (arow&7)<<4;
            const char* bh_ = KhB + arow*128;
            bf16x8 kh0 = *(const bf16x8*)(bh_ + ((l4*16) ^ sw));
            bf16x8 kh1 = *(const bf16x8*)(bh_ + ((l4*16 + 64) ^ sw));
            s[t] = __builtin_amdgcn_mfma_f32_16x16x32_bf16(kh0, qh[0], s[t], 0,0,0);
            s[t] = __builtin_amdgcn_mfma_f32_16x16x32_bf16(kh1, qh[1], s[t], 0,0,0);
        }
        float cm = -INFINITY;
        #pragma unroll
        for(int t=0;t<4;t++)
            #pragma unroll
            for(int r=0;r<4;r++){ s[t][r] *= 0.125f; cm = fmaxf(cm, s[t][r]); }
        cm = fmaxf(cm, __shfl_xor(cm,16));
        cm = fmaxf(cm, __shfl_xor(cm,32));
        float nm = fmaxf(mreg, cm);
        float es = expf(mreg - nm);
        float ps = 0.f;
        #pragma unroll
        for(int t=0;t<4;t++)
            #pragma unroll
            for(int r=0;r<4;r++){ float pv = expf(s[t][r] - nm); s[t][r] = pv; ps += pv; }
        ps += __shfl_xor(ps,16);
        ps += __shfl_xor(ps,32);
        lreg = lreg*es + ps;
        mreg = nm;
        #pragma unroll
        for(int d=0;d<4;d++){ O[d][0]*=es; O[d][1]*=es; O[d][2]*=es; O[d][3]*=es; }
        #pragma unroll
        for(int c32=0;c32<2;c32++){
            bf16x8 pb;
            #pragma unroll
            for(int j=0;j<8;j++){
                int srcl = ((((lane>>4)*2 + (j>>2)) & 3) << 4) | l15;
                float v0 = __shfl(s[c32*2+0][j&3], srcl, 64);
                float v1 = __shfl(s[c32*2+1][j&3], srcl, 64);
                float v = (lane < 32) ? v0 : v1;
                pb[j] = (short)f2b(v);
            }
            #pragma unroll
            for(int dhb=0; dhb<4; dhb++){
                int vrow = dhb*16 + l15;
                bf16x8 va = *(const bf16x8*)(VtB + vrow*128 + ((c32*64 + l4*16) ^ ((vrow&7)<<4)));
                O[dhb] = __builtin_amdgcn_mfma_f32_16x16x32_bf16(va, pb, O[dhb], 0,0,0);
            }
        }
    }
    float inv = 1.f/lreg;
    #pragma unroll
    for(int dhb=0;dhb<4;dhb++)
        #pragma unroll
        for(int r=0;r<4;r++){
            float val = O[dhb][r]*inv;
            size_t o = qrow*DD + h*64 + dhb*16 + l4*4 + r;
            u16 hh = f2b(val);
            aoh[o] = hh;
            aol[o] = f2b(val - b2f(hh));
        }
}

// layernorm row kernel
__global__ __launch_bounds__(256) void ln_kernel(const float* __restrict__ xp, const float* __restrict__ o2,
                                                 const float* __restrict__ lg, const float* __restrict__ lb,
                                                 float* __restrict__ gatt){
    __shared__ float red[256];
    int r = blockIdx.x, c = threadIdx.x;
    float y = xp[(size_t)r*DD + c] + o2[(size_t)r*DD + c];
    red[c] = y; __syncthreads();
    for(int s=128;s;s>>=1){ if(c<s) red[c] += red[c+s]; __syncthreads(); }
    float mu = red[0]*(1.f/DD);
    __syncthreads();
    float d = y - mu;
    red[c] = d*d; __syncthreads();
    for(int s=128;s;s>>=1){ if(c<s) red[c] += red[c+s]; __syncthreads(); }
    float var = red[0]*(1.f/DD);
    gatt[(size_t)r*DD + c] = lg[c]*d/sqrtf(var+1e-5f) + lb[c];
}

__global__ void feat_reduce2(const float* __restrict__ xp, const float* __restrict__ gatt,
                             float* __restrict__ out){
    int b = blockIdx.x, c = threadIdx.x;
    int j0 = blockIdx.y*64;
    float s1=0.f, s2=0.f;
    for(int j=j0;j<j0+64;j++){
        size_t base = ((size_t)(b*KPOOL + j))*DD + c;
        s1 += xp[base];
        s2 += gatt[base];
    }
    atomicAdd(&out[b*512 + c], s1);
    atomicAdd(&out[b*512 + 256 + c], s2);
}

__global__ void cosine_kernel(const float* __restrict__ u, const float* __restrict__ v,
                              float* __restrict__ out){
    int b = blockIdx.x, t = threadIdx.x;
    float du=0.f, nu=0.f, nv=0.f;
    for(int j=t;j<512;j+=64){
        float a = u[b*512+j], bb = v[b*512+j];
        du += a*bb; nu += a*a; nv += bb*bb;
    }
    for(int m=32;m;m>>=1){
        du += __shfl_xor(du,m); nu += __shfl_xor(nu,m); nv += __shfl_xor(nv,m);
    }
    if(t==0) out[b] = du / (fmaxf(sqrtf(nu),1e-8f)*fmaxf(sqrtf(nv),1e-8f));
}

// =======================================================================
extern "C" void kernel_launch(void* const* d_in, const int* in_sizes, int n_in,
                              void* d_out, int out_size, void* d_ws, size_t ws_size,
                              hipStream_t stream){
    (void)in_sizes; (void)n_in; (void)out_size; (void)ws_size;
    const float* hgt_Wk   = (const float*)d_in[12];
    const float* hgt_Wq   = (const float*)d_in[13];
    const float* hgt_Wv   = (const float*)d_in[14];
    const float* hgt_Wo   = (const float*)d_in[15];
    const float* hgt_arel = (const float*)d_in[16];
    const float* hgt_mrel = (const float*)d_in[17];
    const float* hgt_prel = (const float*)d_in[18];
    const float* hgt_skip = (const float*)d_in[19];
    const float* pool_W   = (const float*)d_in[20];
    const float* pool_att = (const float*)d_in[21];
    const float* pool_bias= (const float*)d_in[22];
    const float* t_wq     = (const float*)d_in[23];
    const float* t_wk     = (const float*)d_in[24];
    const float* t_wv     = (const float*)d_in[25];
    const float* t_wo     = (const float*)d_in[26];
    const float* ln_g     = (const float*)d_in[27];
    const float* ln_b     = (const float*)d_in[28];
    float* out = (float*)d_out;

    char* base = (char*)d_ws;
    size_t off = 0;
    auto allocb = [&](size_t nbytes)->void*{
        void* p = (void*)(base + off);
        off += ((nbytes + 255) & ~(size_t)255);
        return p;
    };
    const size_t MAT = 65536;
    // ---- persistent ----
    u16* bwtk_h = (u16*)allocb(16*MAT*2); u16* bwtk_l = (u16*)allocb(16*MAT*2);
    u16* bwtv_h = (u16*)allocb(16*MAT*2); u16* bwtv_l = (u16*)allocb(16*MAT*2);
    u16* bwq_h  = (u16*)allocb(8*MAT*2);  u16* bwq_l  = (u16*)allocb(8*MAT*2);
    u16* bwo_h  = (u16*)allocb(8*MAT*2);  u16* bwo_l  = (u16*)allocb(8*MAT*2);
    u16* btw_h  = (u16*)allocb(4*MAT*2);  u16* btw_l  = (u16*)allocb(4*MAT*2);
    float* ubuf = (float*)allocb(BB*512*4);
    float* vbuf = (float*)allocb(BB*512*4);
    float* xa_i = (float*)allocb((size_t)NI*DD*4);
    float* xa_d = (float*)allocb((size_t)ND*DD*4);
    float* xb_i = (float*)allocb((size_t)NI*DD*4);
    float* xb_d = (float*)allocb((size_t)ND*DD*4);
    // ---- per-branch CSR ----
    uint32_t* ccnt   = (uint32_t*)allocb((size_t)2*NROW*4);
    uint32_t* rowptr = (uint32_t*)allocb((size_t)(2*NROW+1)*4);
    uint32_t* einfo  = (uint32_t*)allocb((size_t)2*EHGT*4);
    size_t region = off;
    // ---- conv scratch (q/ka/vm doubled: per-dir) ----
    float* q_i  = (float*)allocb((size_t)2*NI*DD*4);
    float* q_d  = (float*)allocb((size_t)2*ND*DD*4);
    u16* ka16 = (u16*)allocb((size_t)8*NI*DD*2);   // [dir][r][NI][DD]; also combine f32 temp
    u16* vm16 = (u16*)allocb((size_t)8*NI*DD*2);
    float* xacc_i= (float*)allocb((size_t)NI*DD*4);
    float* xacc_d= (float*)allocb((size_t)ND*DD*4);
    u16* bcur_h = (u16*)allocb((size_t)NROW*DD*2);
    u16* bcur_l = (u16*)allocb((size_t)NROW*DD*2);
    u16* bagg_h = (u16*)allocb((size_t)NROW*DD*2);
    u16* bagg_l = (u16*)allocb((size_t)NROW*DD*2);
    // ---- pooling/transformer overlay ----
    off = region;
    float* hvec = (float*)allocb(NROW*4);
    float* pscore = (float*)allocb(NROW*4);
    int* seln   = (int*)allocb(BB*KPOOL*4);
    float* sels = (float*)allocb(BB*KPOOL*4);
    float* xp   = (float*)allocb((size_t)BB*KPOOL*DD*4);
    float* o2   = (float*)allocb((size_t)BB*KPOOL*DD*4);
    float* gatt = (float*)allocb((size_t)BB*KPOOL*DD*4);
    u16* bxp_h = (u16*)allocb((size_t)BB*KPOOL*DD*2);
    u16* bxp_l = (u16*)allocb((size_t)BB*KPOOL*DD*2);
    u16* qbh = (u16*)allocb((size_t)BB*KPOOL*DD*2);
    u16* kbh = (u16*)allocb((size_t)BB*KPOOL*DD*2);
    u16* vbh = (u16*)allocb((size_t)BB*KPOOL*DD*2);
    u16* bao_h = (u16*)allocb((size_t)BB*KPOOL*DD*2);
    u16* bao_l = (u16*)allocb((size_t)BB*KPOOL*DD*2);

    const int st_tab[2][4] = {{0,1,0,0},{0,0,1,0}};
    const int dt_tab[2][4] = {{0,0,1,0},{0,1,0,0}};
    const int MR = BB*KPOOL;

    fill_u32<<<(2*BB*512+255)/256,256,0,stream>>>((uint32_t*)ubuf, 0u, 2*BB*512);
    float* wtkF = (float*)ka16;
    float* wtvF = (float*)ka16 + 16*MAT;
    combine_all<<<dim3(256,32),256,0,stream>>>(hgt_Wk, hgt_Wv, hgt_arel, hgt_mrel, wtkF, wtvF);
    WCArgs wc;
    wc.in[0]=wtkF;   wc.oh[0]=bwtk_h; wc.ol[0]=bwtk_l; wc.cnt[0]=16;
    wc.in[1]=wtvF;   wc.oh[1]=bwtv_h; wc.ol[1]=bwtv_l; wc.cnt[1]=16;
    wc.in[2]=hgt_Wq; wc.oh[2]=bwq_h;  wc.ol[2]=bwq_l;  wc.cnt[2]=8;
    wc.in[3]=hgt_Wo; wc.oh[3]=bwo_h;  wc.ol[3]=bwo_l;  wc.cnt[3]=8;
    wc.in[4]=t_wq;   wc.oh[4]=btw_h;          wc.ol[4]=btw_l;          wc.cnt[4]=1;
    wc.in[5]=t_wk;   wc.oh[5]=btw_h+1*MAT;    wc.ol[5]=btw_l+1*MAT;    wc.cnt[5]=1;
    wc.in[6]=t_wv;   wc.oh[6]=btw_h+2*MAT;    wc.ol[6]=btw_l+2*MAT;    wc.cnt[6]=1;
    wc.in[7]=t_wo;   wc.oh[7]=btw_h+3*MAT;    wc.ol[7]=btw_l+3*MAT;    wc.cnt[7]=1;
    wc.nr = 8;
    wcvt_split<<<dim3(256,52),256,0,stream>>>(wc);

    for(int bi=0;bi<2;bi++){
        int ib = bi*6;
        const float* x_inst = (const float*)d_in[ib+0];
        const float* x_data = (const float*)d_in[ib+1];
        const int* ecp = (const int*)d_in[ib+2];
        const int* eip = (const int*)d_in[ib+3];
        const int* eop = (const int*)d_in[ib+4];
        const int* ekp = (const int*)d_in[ib+5];
        const int* rows_f[4] = {ecp, eip, eop, ekp};
        const int* cols_f[4] = {ecp+EC, eip+EI, eop+EO, ekp+EK};

        // ---- CSR build (both dirs, one pass) ----
        CB2 cb;
        for(int r=0;r<4;r++){
            cb.row[r]   = rows_f[r]; cb.col[r]   = cols_f[r]; cb.dt[r]   = dt_tab[0][r]; cb.st[r]   = st_tab[0][r];
            cb.row[4+r] = cols_f[r]; cb.col[4+r] = rows_f[r]; cb.dt[4+r] = dt_tab[1][r]; cb.st[4+r] = st_tab[1][r];
        }
        cb.cnt = ccnt; cb.rowptr = rowptr; cb.einfo = einfo;
        fill_u32<<<(2*NROW+255)/256,256,0,stream>>>(ccnt, 0u, 2*NROW);
        csr_hist2<<<(2*EHGT+255)/256,256,0,stream>>>(cb);
        scan_rowptr2<<<1,1024,0,stream>>>(ccnt, rowptr);
        csr_scatter2<<<(2*EHGT+255)/256,256,0,stream>>>(cb);

        const float* cur_i = x_inst;
        const float* cur_d = x_data;
        cvt_split<<<((NROW*DD/4)+255)/256,256,0,stream>>>(cur_i, NI*DD, cur_d, ND*DD, bcur_h, bcur_l);
        for(int l=0;l<LL;l++){
            float* nxt_i = (l==0) ? xa_i : xb_i;
            float* nxt_d = (l==0) ? xa_d : xb_d;

            // --- fused both-dir mega GEMM: 2×{Q(2, f32, split) + KA(4, bf16) + VM(4, bf16)} ---
            GArgs g1; int nb1 = 0, ndx = 0;
            auto addg = [&](int srctype, const u16* Bh, const u16* Bl, float* Cm, u16* Om, int M, int mode, int prec){
                GDesc& d = g1.d[ndx];
                size_t ao = srctype ? (size_t)NI*DD : 0;
                d.Ah = bcur_h + ao; d.Al = bcur_l + ao;
                d.Bh = Bh; d.Bl = Bl; d.C = Cm;
                d.Oh = Om; d.Ol = nullptr; d.X = nullptr; d.Xacc = nullptr; d.skipp = nullptr;
                d.mblks = M/128; d.mode = mode; d.prec = prec;
                nb1 += M/128; ndx++;
            };
            for(int dir=0;dir<2;dir++){
                int wb = l*2 + dir;
                addg(0, bwq_h + (size_t)(wb*2+0)*MAT, bwq_l + (size_t)(wb*2+0)*MAT,
                     q_i + (size_t)dir*NI*DD, nullptr, NI, 0, 0);
                addg(1, bwq_h + (size_t)(wb*2+1)*MAT, bwq_l + (size_t)(wb*2+1)*MAT,
                     q_d + (size_t)dir*ND*DD, nullptr, ND, 0, 0);
                for(int r=0;r<4;r++){
                    int st = st_tab[dir][r];
                    addg(st, bwtk_h + (size_t)(wb*4+r)*MAT, bwtk_l + (size_t)(wb*4+r)*MAT,
                         nullptr, ka16 + (size_t)(dir*4 + r)*NI*DD, st ? ND : NI, 4, 1);
                }
                for(int r=0;r<4;r++){
                    int st = st_tab[dir][r];
                    addg(st, bwtv_h + (size_t)(wb*4+r)*MAT, bwtv_l + (size_t)(wb*4+r)*MAT,
                         nullptr, vm16 + (size_t)(dir*4 + r)*NI*DD, st ? ND : NI, 4, 1);
                }
            }
            g1.nd = ndx;
            gemm_mfma<<<dim3(nb1,2),256,0,stream>>>(g1);

            for(int dir=0;dir<2;dir++){
                int wb = l*2 + dir;

                // --- fused edge phase ---
                hgt_fused<<<NROW/4,256,0,stream>>>(rowptr + (size_t)dir*NROW, einfo,
                    q_i + (size_t)dir*NI*DD, q_d + (size_t)dir*ND*DD,
                    ka16 + (size_t)dir*4*NI*DD, vm16 + (size_t)dir*4*NI*DD,
                    hgt_prel + (size_t)wb*4*HH, bagg_h, bagg_l);

                // --- Wo GEMMs with fused skip/relu epilogue (split) ---
                GArgs g3; g3.nd = 2;
                for(int t=0;t<2;t++){
                    GDesc& d = g3.d[t];
                    size_t ao = t ? (size_t)NI*DD : 0;
                    d.Ah = bagg_h + ao; d.Al = bagg_l + ao;
                    d.Bh = bwo_h + (size_t)(wb*2+t)*MAT; d.Bl = bwo_l + (size_t)(wb*2+t)*MAT;
                    d.C = t ? nxt_d : nxt_i;
                    d.Oh = bcur_h + ao; d.Ol = bcur_l + ao;
                    d.X = t ? cur_d : cur_i;
                    d.Xacc = t ? xacc_d : xacc_i;
                    d.skipp = hgt_skip + wb*2 + t;
                    d.mblks = (t ? ND : NI)/128;
                    d.mode = dir ? 3 : 2;
                    d.prec = 0;
                }
                gemm_mfma<<<dim3(NI/128 + ND/128,2),256,0,stream>>>(g3);
            }
            cur_i = nxt_i;
            cur_d = nxt_d;
        }

        // -------- SAGPooling (CSR-based, no atomics) --------
        pool_h2<<<NROW/4,256,0,stream>>>(cur_i, cur_d, pool_W, hvec);
        pool_csr<<<NROW/4,256,0,stream>>>(rowptr, einfo, hvec, pool_att, pscore);
        topk_rank<<<dim3(384,BB),256,0,stream>>>(pscore, pool_bias, seln, sels);
        gather_xp<<<BB*KPOOL,256,0,stream>>>(seln, sels, cur_i, cur_d, xp, bxp_h, bxp_l);

        // -------- transformer --------
        GArgs g4; g4.nd = 3;
        for(int t=0;t<3;t++){
            GDesc& d = g4.d[t];
            d.Ah=bxp_h; d.Al=bxp_l;
            d.Bh=btw_h + (size_t)t*MAT; d.Bl=btw_l + (size_t)t*MAT;
            d.C = nullptr;
            d.Oh = (t==0)? qbh : (t==1)? kbh : vbh;
            d.Ol = nullptr;
            d.X = nullptr; d.Xacc = nullptr; d.skipp = nullptr;
            d.mblks = MR/128; d.mode = 4; d.prec = 0;
        }
        gemm_mfma<<<dim3(3*(MR/128),2),256,0,stream>>>(g4);
        attn_mfma<<<dim3(BB*HH, KPOOL/64),256,0,stream>>>(qbh, kbh, vbh, bao_h, bao_l);
        GArgs g5; g5.nd = 1;
        {
            GDesc& d = g5.d[0];
            d.Ah=bao_h; d.Al=bao_l;
            d.Bh=btw_h + (size_t)3*MAT; d.Bl=btw_l + (size_t)3*MAT;
            d.C=o2; d.Oh=nullptr; d.Ol=nullptr; d.X=nullptr; d.Xacc=nullptr; d.skipp=nullptr;
            d.mblks=MR/128; d.mode=0; d.prec=0;
        }
        gemm_mfma<<<dim3(MR/128,2),256,0,stream>>>(g5);
        ln_kernel<<<MR,256,0,stream>>>(xp, o2, ln_g, ln_b, gatt);
        feat_reduce2<<<dim3(BB,12),256,0,stream>>>(xp, gatt, bi ? vbuf : ubuf);
    }

    cosine_kernel<<<BB,64,0,stream>>>(ubuf, vbuf, out);
}

// Round 23
// 917.877 us; speedup vs baseline: 2.1187x; 1.0361x over previous
//
#include <hip/hip_runtime.h>
#include <math.h>
#include <stdint.h>

#define LL 2
#define HH 4
#define DHH 64
#define DD 256
#define BB 8
#define NI 8192
#define ND 4096
#define NROW 12288
#define KPOOL 768
#define EC 65536
#define EI 32768
#define EO 32768
#define EK 8192
#define EHGT (EC+EI+EO+EK)

typedef unsigned short u16;
typedef short bf16x8 __attribute__((ext_vector_type(8)));
typedef float f32x4 __attribute__((ext_vector_type(4)));
typedef unsigned short u16x4 __attribute__((ext_vector_type(4)));

__device__ inline float gelu_f(float x){ return 0.5f*x*(1.f+erff(x*0.70710678118654752f)); }
__device__ inline u16 f2b(float x){ uint32_t u=__float_as_uint(x); return (u16)((u + 0x7fffu + ((u>>16)&1u))>>16); }
__device__ inline float b2f(u16 h){ return __uint_as_float(((uint32_t)h)<<16); }

// ---------------- generic fill ----------------
__global__ void fill_u32(uint32_t* p, uint32_t v, int n){
    int i = blockIdx.x*256 + threadIdx.x;
    if(i<n) p[i]=v;
}

// ---------------- activation split-convert ----------------
__global__ void cvt_split(const float* __restrict__ A, int nA, const float* __restrict__ B, int nB,
                          u16* __restrict__ oh, u16* __restrict__ ol){
    int i = (blockIdx.x*256 + threadIdx.x)*4;
    int tot = nA + nB;
    if(i >= tot) return;
    float4 v = (i < nA) ? *(const float4*)(A + i) : *(const float4*)(B + (i - nA));
    float vv[4] = {v.x, v.y, v.z, v.w};
    u16x4 h4, l4;
    #pragma unroll
    for(int j=0;j<4;j++){
        float x = vv[j];
        u16 h = f2b(x);
        h4[j] = h;
        l4[j] = f2b(x - b2f(h));
    }
    *(u16x4*)(oh + i) = h4;
    *(u16x4*)(ol + i) = l4;
}

// ---------------- weight transpose + split ----------------
struct WCArgs { const float* in[8]; u16* oh[8]; u16* ol[8]; int cnt[8]; int nr; };
__global__ void wcvt_split(WCArgs a){
    int mat = blockIdx.y, ri = 0;
    while(ri < a.nr-1 && mat >= a.cnt[ri]){ mat -= a.cnt[ri]; ri++; }
    const float* in = a.in[ri] + (size_t)mat*65536;
    u16* oh = a.oh[ri] + (size_t)mat*65536;
    u16* ol = a.ol[ri] + (size_t)mat*65536;
    int n = blockIdx.x, k = threadIdx.x;
    float x = in[(size_t)k*DD + n];
    u16 h = f2b(x);
    oh[n*DD + k] = h;
    ol[n*DD + k] = f2b(x - b2f(h));
}

// ---------------- Wo weights: gate-folded, K-concatenated transpose+split ----------------
// out[(l*2+t)][n][dir*256+k] = 0.5*sigmoid(skip[l,dir,t]) * Wo[(l*2+dir)*2+t][k][n]
__global__ void wcvt_wo(const float* __restrict__ Wo, const float* __restrict__ skip,
                        u16* __restrict__ oh, u16* __restrict__ ol){
    int combo = blockIdx.y;          // l*2 + t
    int l = combo >> 1, t = combo & 1;
    int n = blockIdx.x, k = threadIdx.x;
    #pragma unroll
    for(int dir=0;dir<2;dir++){
        int wi = (l*2+dir)*2 + t;
        float gg = 1.f/(1.f+expf(-skip[wi]));
        float x = 0.5f*gg*Wo[(size_t)wi*65536 + (size_t)k*DD + n];
        size_t o = (size_t)combo*131072 + (size_t)n*512 + dir*256 + k;
        u16 hh = f2b(x);
        oh[o] = hh;
        ol[o] = f2b(x - b2f(hh));
    }
}

// ---------------- MFMA batched GEMM with fused, LDS-restaged epilogues ----------------
// prec=0: split hi/lo (3 MFMA/step); prec=1: hi-only (1 MFMA/step, half staging)
// mode 0: C=f32   mode 4: Oh=plain bf16
// mode 6: v=relu(acc + cx*X), cx = 1-0.5*(sig(skipp[0])+sig(skipp[2])); C=v; Oh/Ol=split(v)
struct GDesc { const u16* Ah; const u16* Al; const u16* Bh; const u16* Bl;
               float* C; u16* Oh; u16* Ol;
               const float* X; const float* skipp;
               int mblks; int mode; int prec; int kdim; };
struct GArgs { GDesc d[20]; int nd; };

__global__ __launch_bounds__(256) void gemm_mfma(GArgs ga){
    __shared__ u16 SBUF[2*128*64];
    char* Abuf = (char*)SBUF;
    char* Bbuf = (char*)(SBUF + 128*64);
    int mb = blockIdx.x, di = 0;
    while(di < ga.nd-1 && mb >= ga.d[di].mblks){ mb -= ga.d[di].mblks; di++; }
    GDesc g = ga.d[di];
    const int prec = g.prec;
    const int KD = g.kdim;
    const int m0 = mb*128, n0 = blockIdx.y*128;
    const int tid = threadIdx.x;
    const int lane = tid & 63, wid = tid >> 6;
    const int wm = (wid>>1)*64, wn = (wid&1)*64;
    const int l15 = lane & 15, l4 = lane >> 4;
    const int srow = tid >> 1, hf = tid & 1;
    const int ssw = (srow&7)<<4;
    const int c0 = (hf*32) ^ ssw;
    const int c1 = (hf*32+16) ^ ssw;
    const int c2 = (64+hf*32) ^ ssw;
    const int c3 = (64+hf*32+16) ^ ssw;
    const int rbyte = srow*128;
    const u16* __restrict__ Aph = g.Ah + (size_t)(m0 + srow)*KD + hf*16;
    const u16* __restrict__ Apl = g.Al + (size_t)(m0 + srow)*KD + hf*16;
    const u16* __restrict__ Bph = g.Bh + (size_t)(n0 + srow)*KD + hf*16;
    const u16* __restrict__ Bpl = g.Bl + (size_t)(n0 + srow)*KD + hf*16;
    f32x4 acc[4][4] = {};
    bf16x8 r0, r1, r2, r3, r4, r5, r6, r7;
    r0 = *(const bf16x8*)(Aph);
    r1 = *(const bf16x8*)(Aph + 8);
    r4 = *(const bf16x8*)(Bph);
    r5 = *(const bf16x8*)(Bph + 8);
    if(!prec){
        r2 = *(const bf16x8*)(Apl);
        r3 = *(const bf16x8*)(Apl + 8);
        r6 = *(const bf16x8*)(Bpl);
        r7 = *(const bf16x8*)(Bpl + 8);
    }
    for(int k0=0;k0<KD;k0+=32){
        __syncthreads();
        *(bf16x8*)(Abuf + rbyte + c0) = r0; *(bf16x8*)(Abuf + rbyte + c1) = r1;
        *(bf16x8*)(Bbuf + rbyte + c0) = r4; *(bf16x8*)(Bbuf + rbyte + c1) = r5;
        if(!prec){
            *(bf16x8*)(Abuf + rbyte + c2) = r2; *(bf16x8*)(Abuf + rbyte + c3) = r3;
            *(bf16x8*)(Bbuf + rbyte + c2) = r6; *(bf16x8*)(Bbuf + rbyte + c3) = r7;
        }
        __syncthreads();
        if(k0 + 32 < KD){
            int kn = k0 + 32;
            r0 = *(const bf16x8*)(Aph + kn);     r1 = *(const bf16x8*)(Aph + kn + 8);
            r4 = *(const bf16x8*)(Bph + kn);     r5 = *(const bf16x8*)(Bph + kn + 8);
            if(!prec){
                r2 = *(const bf16x8*)(Apl + kn); r3 = *(const bf16x8*)(Apl + kn + 8);
                r6 = *(const bf16x8*)(Bpl + kn); r7 = *(const bf16x8*)(Bpl + kn + 8);
            }
        }
        bf16x8 afh[4], bfh[4];
        #pragma unroll
        for(int i=0;i<4;i++){
            int ar = wm + i*16 + l15;
            int abase = ar*128;
            afh[i] = *(const bf16x8*)(Abuf + abase + ((l4*16) ^ ((ar&7)<<4)));
            int br = wn + i*16 + l15;
            int bbase = br*128;
            bfh[i] = *(const bf16x8*)(Bbuf + bbase + ((l4*16) ^ ((br&7)<<4)));
        }
        #pragma unroll
        for(int i=0;i<4;i++)
            #pragma unroll
            for(int j=0;j<4;j++)
                acc[i][j] = __builtin_amdgcn_mfma_f32_16x16x32_bf16(afh[i], bfh[j], acc[i][j], 0,0,0);
        if(!prec){
            bf16x8 afl[4], bfl[4];
            #pragma unroll
            for(int i=0;i<4;i++){
                int ar = wm + i*16 + l15;
                int abase = ar*128;
                afl[i] = *(const bf16x8*)(Abuf + abase + ((64 + l4*16) ^ ((ar&7)<<4)));
                int br = wn + i*16 + l15;
                int bbase = br*128;
                bfl[i] = *(const bf16x8*)(Bbuf + bbase + ((64 + l4*16) ^ ((br&7)<<4)));
            }
            #pragma unroll
            for(int i=0;i<4;i++)
                #pragma unroll
                for(int j=0;j<4;j++){
                    acc[i][j] = __builtin_amdgcn_mfma_f32_16x16x32_bf16(afh[i], bfl[j], acc[i][j], 0,0,0);
                    acc[i][j] = __builtin_amdgcn_mfma_f32_16x16x32_bf16(afl[i], bfh[j], acc[i][j], 0,0,0);
                }
        }
    }
    // ---- coalesced epilogue via LDS restage (two 64-row passes) ----
    const int mode = g.mode;
    float cx = 0.f;
    if(mode == 6){
        float g0 = 1.f/(1.f + expf(-g.skipp[0]));
        float g1 = 1.f/(1.f + expf(-g.skipp[2]));
        cx = 1.f - 0.5f*(g0 + g1);
    }
    float* LDSf = (float*)SBUF;
    const int lrow = tid >> 5;
    const int cc4 = (tid & 31)*4;
    #pragma unroll
    for(int half=0; half<2; half++){
        __syncthreads();
        if((wid>>1) == half){
            #pragma unroll
            for(int i=0;i<4;i++)
                #pragma unroll
                for(int j=0;j<4;j++)
                    #pragma unroll
                    for(int r=0;r<4;r++)
                        LDSf[(i*16 + l4*4 + r)*128 + wn + j*16 + l15] = acc[i][j][r];
        }
        __syncthreads();
        #pragma unroll
        for(int k=0;k<8;k++){
            int row = lrow + k*8;
            size_t o = (size_t)(m0 + half*64 + row)*DD + n0 + cc4;
            float4 v = *(const float4*)&LDSf[row*128 + cc4];
            float vv[4] = {v.x, v.y, v.z, v.w};
            if(mode==0){
                *(float4*)(g.C + o) = v;
            } else if(mode==4){
                u16x4 h4;
                #pragma unroll
                for(int j=0;j<4;j++) h4[j] = f2b(vv[j]);
                *(u16x4*)(g.Oh + o) = h4;
            } else {   // mode 6
                float4 x = *(const float4*)(g.X + o);
                float xx[4] = {x.x, x.y, x.z, x.w};
                float4 cv;
                float* cvv = (float*)&cv;
                u16x4 h4, lo4;
                #pragma unroll
                for(int j=0;j<4;j++){
                    float v3 = vv[j] + cx*xx[j];
                    v3 = v3 > 0.f ? v3 : 0.f;
                    cvv[j] = v3;
                    u16 hh = f2b(v3); h4[j]=hh; lo4[j]=f2b(v3-b2f(hh));
                }
                *(float4*)(g.C + o) = cv;
                *(u16x4*)(g.Oh + o) = h4;
                *(u16x4*)(g.Ol + o) = lo4;
            }
        }
    }
}

// ---------- combine ----------
__global__ void combine_all(const float* __restrict__ Wk, const float* __restrict__ Wv,
                            const float* __restrict__ Ra, const float* __restrict__ Rm,
                            float* __restrict__ wtk, float* __restrict__ wtv){
    const int st_tab[2][4] = {{0,1,0,0},{0,0,1,0}};
    int combo = blockIdx.y;
    int idx = combo >> 1, kv = combo & 1;
    int r = idx & 3, wb = idx >> 2, dir = wb & 1;
    int st = st_tab[dir][r];
    const float* W = (kv ? Wv : Wk) + (size_t)(wb*2 + st)*65536;
    const float* R = (kv ? Rm : Ra) + (size_t)idx*16384;
    float* o = (kv ? wtv : wtk) + (size_t)idx*65536;
    int d = blockIdx.x, c = threadIdx.x;
    int h = c >> 6, f = c & 63;
    const float* Wrow = W + d*DD + h*64;
    const float* Rh = R + h*4096 + f;
    float s = 0.f;
    #pragma unroll 8
    for(int k=0;k<64;k++) s += Wrow[k]*Rh[k*64];
    o[d*DD + c] = s;
}

// ---------------- CSR build (both directions in one pass) ----------------
__device__ inline void edge_decode(int e, int& r, int& el){
    if(e < EC){ r=0; el=e; }
    else if(e < EC+EI){ r=1; el=e-EC; }
    else if(e < EC+EI+EO){ r=2; el=e-(EC+EI); }
    else { r=3; el=e-(EC+EI+EO); }
}

struct CB2 {
    const int* row[8]; const int* col[8];
    int dt[8]; int st[8];
    uint32_t* cnt; uint32_t* rowptr; uint32_t* einfo;
};

__global__ void csr_hist2(CB2 a){
    int ge = blockIdx.x*256 + threadIdx.x;
    if(ge >= 2*EHGT) return;
    int dir = ge >= EHGT;
    int e = ge - dir*EHGT;
    int r, el; edge_decode(e, r, el);
    int idx = dir*4 + r;
    int c = a.col[idx][el];
    int dst = dir*NROW + (a.dt[idx] ? (NI + c) : c);
    atomicAdd(&a.cnt[dst], 1u);
}

__global__ __launch_bounds__(1024) void scan_rowptr2(uint32_t* cnt, uint32_t* rowptr){
    __shared__ uint32_t part[1024];
    int t = threadIdx.x;
    int base = t*24;
    uint32_t lpre[24];
    uint32_t sum = 0;
    #pragma unroll
    for(int i=0;i<24;i++){
        uint32_t c = cnt[base+i];
        lpre[i] = sum; sum += c;
        cnt[base+i] = 0;
    }
    part[t] = sum;
    __syncthreads();
    for(int offs=1; offs<1024; offs<<=1){
        uint32_t v = (t>=offs) ? part[t-offs] : 0u;
        __syncthreads();
        part[t] += v;
        __syncthreads();
    }
    uint32_t pre = (t==0) ? 0u : part[t-1];
    #pragma unroll
    for(int i=0;i<24;i++) rowptr[base+i] = pre + lpre[i];
    if(t==1023) rowptr[2*NROW] = part[1023];
}

__global__ void csr_scatter2(CB2 a){
    int ge = blockIdx.x*256 + threadIdx.x;
    if(ge >= 2*EHGT) return;
    int dir = ge >= EHGT;
    int e = ge - dir*EHGT;
    int r, el; edge_decode(e, r, el);
    int idx = dir*4 + r;
    int c = a.col[idx][el];
    int dst = dir*NROW + (a.dt[idx] ? (NI + c) : c);
    int src = a.row[idx][el];
    uint32_t p = a.rowptr[dst] + atomicAdd(&a.cnt[dst], 1u);
    uint32_t vmidx = (uint32_t)(r*NI + src);
    uint32_t hom = a.st[idx] ? (uint32_t)(NI + src) : (uint32_t)src;
    a.einfo[p] = vmidx | (hom << 16);
}

// ---------------- fused HGT edge phase, BOTH dirs: wave per dst, online softmax ----------------
// grid x = 2*NROW/4; dir = bx >= NROW/4. bagg is [NROW][512], dir gives col offset.
__global__ __launch_bounds__(256) void hgt_fused(const uint32_t* __restrict__ rowptr,
                                                 const uint32_t* __restrict__ einfo,
                                                 const float* __restrict__ q_i,
                                                 const float* __restrict__ q_d,
                                                 const u16* __restrict__ ka,
                                                 const u16* __restrict__ vm,
                                                 const float* __restrict__ prel,
                                                 u16* __restrict__ bagg_h,
                                                 u16* __restrict__ bagg_l){
    int wv = threadIdx.x >> 6, lane = threadIdx.x & 63;
    int bx = blockIdx.x;
    int dir = bx >= (NROW/4);
    bx -= dir*(NROW/4);
    int rowi = bx*4 + wv;
    uint32_t p0 = rowptr[(size_t)dir*NROW + rowi], p1 = rowptr[(size_t)dir*NROW + rowi + 1];
    int h = lane >> 4;
    const float* qi = q_i + (size_t)dir*NI*DD;
    const float* qd = q_d + (size_t)dir*ND*DD;
    const u16* kad = ka + (size_t)dir*4*NI*DD;
    const u16* vmd = vm + (size_t)dir*4*NI*DD;
    const float* pr = prel + dir*4*HH;
    const float* qrow = (rowi < NI) ? (qi + (size_t)rowi*DD) : (qd + (size_t)(rowi-NI)*DD);
    float4 q4 = *(const float4*)(qrow + lane*4);
    float pr0 = pr[0*HH+h]*0.125f, pr1 = pr[1*HH+h]*0.125f;
    float pr2 = pr[2*HH+h]*0.125f, pr3 = pr[3*HH+h]*0.125f;
    float m = -INFINITY, den = 0.f;
    float4 o4 = {0.f,0.f,0.f,0.f};
    for(uint32_t p = p0; p < p1; p++){
        uint32_t vmidx = einfo[p] & 0xffffu;
        int r = vmidx >> 13;
        uint2 kr = *(const uint2*)(kad + (size_t)vmidx*DD + lane*4);
        uint2 vr = *(const uint2*)(vmd + (size_t)vmidx*DD + lane*4);
        float k0 = __uint_as_float(kr.x << 16), k1 = __uint_as_float(kr.x & 0xffff0000u);
        float k2 = __uint_as_float(kr.y << 16), k3 = __uint_as_float(kr.y & 0xffff0000u);
        float v0 = __uint_as_float(vr.x << 16), v1 = __uint_as_float(vr.x & 0xffff0000u);
        float v2 = __uint_as_float(vr.y << 16), v3 = __uint_as_float(vr.y & 0xffff0000u);
        float d = q4.x*k0 + q4.y*k1 + q4.z*k2 + q4.w*k3;
        d += __shfl_xor(d, 1); d += __shfl_xor(d, 2);
        d += __shfl_xor(d, 4); d += __shfl_xor(d, 8);
        float pf = (r==0) ? pr0 : (r==1) ? pr1 : (r==2) ? pr2 : pr3;
        float s = d * pf;
        float nm = fmaxf(m, s);
        float sc_ = expf(m - nm);
        float pe = expf(s - nm);
        den = den*sc_ + pe;
        o4.x = o4.x*sc_ + pe*v0;
        o4.y = o4.y*sc_ + pe*v1;
        o4.z = o4.z*sc_ + pe*v2;
        o4.w = o4.w*sc_ + pe*v3;
        m = nm;
    }
    float inv = 1.f/(den + 1e-16f);
    float vals[4] = {o4.x*inv, o4.y*inv, o4.z*inv, o4.w*inv};
    u16x4 h4, l4;
    #pragma unroll
    for(int j=0;j<4;j++){
        float g = gelu_f(vals[j]);
        u16 hh = f2b(g);
        h4[j] = hh;
        l4[j] = f2b(g - b2f(hh));
    }
    size_t ob = (size_t)rowi*512 + dir*256 + lane*4;
    *(u16x4*)(bagg_h + ob) = h4;
    *(u16x4*)(bagg_l + ob) = l4;
}

// ---------------- pooling ----------------
__global__ void pool_h2(const float* __restrict__ xi, const float* __restrict__ xd,
                        const float* __restrict__ w, float* __restrict__ h){
    int node = blockIdx.x*4 + (threadIdx.x>>6);
    int lane = threadIdx.x & 63;
    const float* xr = (node < NI) ? (xi + (size_t)node*DD) : (xd + (size_t)(node-NI)*DD);
    float s = 0.f;
    for(int j=lane;j<DD;j+=64) s += xr[j]*w[j];
    for(int m=32;m;m>>=1) s += __shfl_xor(s, m);
    if(lane==0) h[node] = s;
}

// GAT-style pooling score via fwd CSR + implicit self-loop; wave per dst node
__global__ __launch_bounds__(256) void pool_csr(const uint32_t* __restrict__ rowptr,
                                                const uint32_t* __restrict__ einfo,
                                                const float* __restrict__ h,
                                                const float* __restrict__ att,
                                                float* __restrict__ score){
    int w = blockIdx.x*4 + (threadIdx.x >> 6);
    int lane = threadIdx.x & 63;
    if(w >= NROW) return;
    uint32_t p0 = rowptr[w], p1 = rowptr[w+1];
    float a0 = att[0], a1 = att[1];
    float hn = h[w];
    float es = a0*hn + a1*hn;
    es = es >= 0.f ? es : 0.2f*es;
    float m = -INFINITY;
    for(uint32_t p = p0+lane; p < p1; p += 64){
        float hs = h[einfo[p] >> 16];
        float e = a0*hs + a1*hn;
        e = e >= 0.f ? e : 0.2f*e;
        m = fmaxf(m, e);
    }
    #pragma unroll
    for(int s=32;s;s>>=1) m = fmaxf(m, __shfl_xor(m, s));
    m = fmaxf(m, es);
    float lden = 0.f, lnum = 0.f;
    for(uint32_t p = p0+lane; p < p1; p += 64){
        float hs = h[einfo[p] >> 16];
        float e = a0*hs + a1*hn;
        e = e >= 0.f ? e : 0.2f*e;
        float a = expf(e - m);
        lden += a; lnum += a*hs;
    }
    #pragma unroll
    for(int s=32;s;s>>=1){ lden += __shfl_xor(lden, s); lnum += __shfl_xor(lnum, s); }
    float aself = expf(es - m);
    lden += aself; lnum += aself*hn;
    if(lane==0) score[w] = lnum/(lden + 1e-16f);
}

// ---------------- top-768 of 1536 per graph: wave-per-candidate rank selection ----------------
__global__ __launch_bounds__(256) void topk_rank(const float* __restrict__ score,
                                                 const float* __restrict__ bias,
                                                 int* __restrict__ sel_node,
                                                 float* __restrict__ sel_scale){
    int b = blockIdx.y;
    int wid = threadIdx.x >> 6, lane = threadIdx.x & 63;
    int i = blockIdx.x*4 + wid;
    int nodei = (i<1024) ? (b*1024 + i) : (NI + b*512 + (i-1024));
    float ki = score[nodei];
    int r = 0;
    #pragma unroll
    for(int s=0;s<24;s++){
        int j = s*64 + lane;
        int nodej = (j<1024) ? (b*1024 + j) : (NI + b*512 + (j-1024));
        float kj = score[nodej];
        r += (kj > ki) || (kj == ki && j < i);
    }
    #pragma unroll
    for(int m=32;m;m>>=1) r += __shfl_xor(r, m);
    if(lane==0 && r < KPOOL){
        sel_node[b*KPOOL + r] = nodei;
        sel_scale[b*KPOOL + r] = tanhf(ki + bias[0]);
    }
}

__global__ void gather_xp(const int* __restrict__ sel, const float* __restrict__ scale,
                          const float* __restrict__ xi, const float* __restrict__ xd,
                          float* __restrict__ xp, u16* __restrict__ bh, u16* __restrict__ bl){
    int i = blockIdx.x*256 + threadIdx.x;
    int rowp = i >> 8, c = i & 255;
    int node = sel[rowp];
    float s = scale[rowp];
    float v = (node < NI) ? xi[(size_t)node*DD + c] : xd[(size_t)(node-NI)*DD + c];
    float x = v*s;
    xp[i] = x;
    u16 hh = f2b(x);
    bh[i] = hh;
    bl[i] = f2b(x - b2f(hh));
}

// ---------------- MFMA flash attention: block per (bh, 64 q rows), plain-bf16 QKV ----------------
__global__ __launch_bounds__(256) void attn_mfma(const u16* __restrict__ Qh,
                                                 const u16* __restrict__ Kh,
                                                 const u16* __restrict__ Vh,
                                                 u16* __restrict__ aoh, u16* __restrict__ aol){
    __shared__ u16 KhS[64*64], VtS[64*64];
    char* KhB = (char*)KhS; char* VtB = (char*)VtS;
    int bh = blockIdx.x;
    int b = bh >> 2, h = bh & 3;
    int q0 = blockIdx.y * 64;
    int tid = threadIdx.x;
    int lane = tid & 63;
    int w = tid >> 6;
    int l15 = lane & 15, l4 = lane >> 4;
    size_t qrow = (size_t)(b*KPOOL + q0 + w*16 + l15);
    bf16x8 qh[2];
    #pragma unroll
    for(int c=0;c<2;c++)
        qh[c] = *(const bf16x8*)(Qh + qrow*DD + h*64 + c*32 + l4*8);
    float mreg = -INFINITY, lreg = 0.f;
    f32x4 O[4] = {};
    for(int k0=0;k0<KPOOL;k0+=64){
        __syncthreads();
        {
            int row = tid >> 2, q4 = tid & 3;
            size_t gbase = ((size_t)(b*KPOOL + k0 + row))*DD + h*64 + q4*16;
            bf16x8 k0v = *(const bf16x8*)(Kh + gbase);
            bf16x8 k1v = *(const bf16x8*)(Kh + gbase + 8);
            int sw = (row&7)<<4;
            int colb = q4*32;
            *(bf16x8*)(KhB + row*128 + (colb ^ sw))      = k0v;
            *(bf16x8*)(KhB + row*128 + ((colb+16) ^ sw)) = k1v;
            int row0 = (tid >> 3)*2, dhg = (tid & 7)*8;
            size_t vbase = ((size_t)(b*KPOOL + k0 + row0))*DD + h*64 + dhg;
            bf16x8 va = *(const bf16x8*)(Vh + vbase);
            bf16x8 vb = *(const bf16x8*)(Vh + vbase + DD);
            #pragma unroll
            for(int j=0;j<8;j++){
                int dh = dhg + j;
                uint32_t pk = (uint32_t)(u16)(short)va[j] | ((uint32_t)(u16)(short)vb[j] << 16);
                *(uint32_t*)(VtB + dh*128 + ((row0*2) ^ ((dh&7)<<4))) = pk;
            }
        }
        __syncthreads();
        f32x4 s[4] = {};
        #pragma unroll
        for(int t=0;t<4;t++){
            int arow = t*16 + l15;
            int sw = (arow&7)<<4;
            const char* bh_ = KhB + arow*128;
            bf16x8 kh0 = *(const bf16x8*)(bh_ + ((l4*16) ^ sw));
            bf16x8 kh1 = *(const bf16x8*)(bh_ + ((l4*16 + 64) ^ sw));
            s[t] = __builtin_amdgcn_mfma_f32_16x16x32_bf16(kh0, qh[0], s[t], 0,0,0);
            s[t] = __builtin_amdgcn_mfma_f32_16x16x32_bf16(kh1, qh[1], s[t], 0,0,0);
        }
        float cm = -INFINITY;
        #pragma unroll
        for(int t=0;t<4;t++)
            #pragma unroll
            for(int r=0;r<4;r++){ s[t][r] *= 0.125f; cm = fmaxf(cm, s[t][r]); }
        cm = fmaxf(cm, __shfl_xor(cm,16));
        cm = fmaxf(cm, __shfl_xor(cm,32));
        float nm = fmaxf(mreg, cm);
        float es = expf(mreg - nm);
        float ps = 0.f;
        #pragma unroll
        for(int t=0;t<4;t++)
            #pragma unroll
            for(int r=0;r<4;r++){ float pv = expf(s[t][r] - nm); s[t][r] = pv; ps += pv; }
        ps += __shfl_xor(ps,16);
        ps += __shfl_xor(ps,32);
        lreg = lreg*es + ps;
        mreg = nm;
        #pragma unroll
        for(int d=0;d<4;d++){ O[d][0]*=es; O[d][1]*=es; O[d][2]*=es; O[d][3]*=es; }
        #pragma unroll
        for(int c32=0;c32<2;c32++){
            bf16x8 pb;
            #pragma unroll
            for(int j=0;j<8;j++){
                int srcl = ((((lane>>4)*2 + (j>>2)) & 3) << 4) | l15;
                float v0 = __shfl(s[c32*2+0][j&3], srcl, 64);
                float v1 = __shfl(s[c32*2+1][j&3], srcl, 64);
                float v = (lane < 32) ? v0 : v1;
                pb[j] = (short)f2b(v);
            }
            #pragma unroll
            for(int dhb=0; dhb<4; dhb++){
                int vrow = dhb*16 + l15;
                bf16x8 va = *(const bf16x8*)(VtB + vrow*128 + ((c32*64 + l4*16) ^ ((vrow&7)<<4)));
                O[dhb] = __builtin_amdgcn_mfma_f32_16x16x32_bf16(va, pb, O[dhb], 0,0,0);
            }
        }
    }
    float inv = 1.f/lreg;
    #pragma unroll
    for(int dhb=0;dhb<4;dhb++)
        #pragma unroll
        for(int r=0;r<4;r++){
            float val = O[dhb][r]*inv;
            size_t o = qrow*DD + h*64 + dhb*16 + l4*4 + r;
            u16 hh = f2b(val);
            aoh[o] = hh;
            aol[o] = f2b(val - b2f(hh));
        }
}

// layernorm row kernel
__global__ __launch_bounds__(256) void ln_kernel(const float* __restrict__ xp, const float* __restrict__ o2,
                                                 const float* __restrict__ lg, const float* __restrict__ lb,
                                                 float* __restrict__ gatt){
    __shared__ float red[256];
    int r = blockIdx.x, c = threadIdx.x;
    float y = xp[(size_t)r*DD + c] + o2[(size_t)r*DD + c];
    red[c] = y; __syncthreads();
    for(int s=128;s;s>>=1){ if(c<s) red[c] += red[c+s]; __syncthreads(); }
    float mu = red[0]*(1.f/DD);
    __syncthreads();
    float d = y - mu;
    red[c] = d*d; __syncthreads();
    for(int s=128;s;s>>=1){ if(c<s) red[c] += red[c+s]; __syncthreads(); }
    float var = red[0]*(1.f/DD);
    gatt[(size_t)r*DD + c] = lg[c]*d/sqrtf(var+1e-5f) + lb[c];
}

__global__ void feat_reduce2(const float* __restrict__ xp, const float* __restrict__ gatt,
                             float* __restrict__ out){
    int b = blockIdx.x, c = threadIdx.x;
    int j0 = blockIdx.y*64;
    float s1=0.f, s2=0.f;
    for(int j=j0;j<j0+64;j++){
        size_t base = ((size_t)(b*KPOOL + j))*DD + c;
        s1 += xp[base];
        s2 += gatt[base];
    }
    atomicAdd(&out[b*512 + c], s1);
    atomicAdd(&out[b*512 + 256 + c], s2);
}

__global__ void cosine_kernel(const float* __restrict__ u, const float* __restrict__ v,
                              float* __restrict__ out){
    int b = blockIdx.x, t = threadIdx.x;
    float du=0.f, nu=0.f, nv=0.f;
    for(int j=t;j<512;j+=64){
        float a = u[b*512+j], bb = v[b*512+j];
        du += a*bb; nu += a*a; nv += bb*bb;
    }
    for(int m=32;m;m>>=1){
        du += __shfl_xor(du,m); nu += __shfl_xor(nu,m); nv += __shfl_xor(nv,m);
    }
    if(t==0) out[b] = du / (fmaxf(sqrtf(nu),1e-8f)*fmaxf(sqrtf(nv),1e-8f));
}

// =======================================================================
extern "C" void kernel_launch(void* const* d_in, const int* in_sizes, int n_in,
                              void* d_out, int out_size, void* d_ws, size_t ws_size,
                              hipStream_t stream){
    (void)in_sizes; (void)n_in; (void)out_size; (void)ws_size;
    const float* hgt_Wk   = (const float*)d_in[12];
    const float* hgt_Wq   = (const float*)d_in[13];
    const float* hgt_Wv   = (const float*)d_in[14];
    const float* hgt_Wo   = (const float*)d_in[15];
    const float* hgt_arel = (const float*)d_in[16];
    const float* hgt_mrel = (const float*)d_in[17];
    const float* hgt_prel = (const float*)d_in[18];
    const float* hgt_skip = (const float*)d_in[19];
    const float* pool_W   = (const float*)d_in[20];
    const float* pool_att = (const float*)d_in[21];
    const float* pool_bias= (const float*)d_in[22];
    const float* t_wq     = (const float*)d_in[23];
    const float* t_wk     = (const float*)d_in[24];
    const float* t_wv     = (const float*)d_in[25];
    const float* t_wo     = (const float*)d_in[26];
    const float* ln_g     = (const float*)d_in[27];
    const float* ln_b     = (const float*)d_in[28];
    float* out = (float*)d_out;

    char* base = (char*)d_ws;
    size_t off = 0;
    auto allocb = [&](size_t nbytes)->void*{
        void* p = (void*)(base + off);
        off += ((nbytes + 255) & ~(size_t)255);
        return p;
    };
    const size_t MAT = 65536;
    // ---- persistent ----
    u16* bwtk_h = (u16*)allocb(16*MAT*2); u16* bwtk_l = (u16*)allocb(16*MAT*2);
    u16* bwtv_h = (u16*)allocb(16*MAT*2); u16* bwtv_l = (u16*)allocb(16*MAT*2);
    u16* bwq_h  = (u16*)allocb(8*MAT*2);  u16* bwq_l  = (u16*)allocb(8*MAT*2);
    u16* bwoc_h = (u16*)allocb(4*131072*2); u16* bwoc_l = (u16*)allocb(4*131072*2);
    u16* btw_h  = (u16*)allocb(4*MAT*2);  u16* btw_l  = (u16*)allocb(4*MAT*2);
    float* ubuf = (float*)allocb(BB*512*4);
    float* vbuf = (float*)allocb(BB*512*4);
    float* xa_i = (float*)allocb((size_t)NI*DD*4);
    float* xa_d = (float*)allocb((size_t)ND*DD*4);
    float* xb_i = (float*)allocb((size_t)NI*DD*4);
    float* xb_d = (float*)allocb((size_t)ND*DD*4);
    // ---- per-branch CSR ----
    uint32_t* ccnt   = (uint32_t*)allocb((size_t)2*NROW*4);
    uint32_t* rowptr = (uint32_t*)allocb((size_t)(2*NROW+1)*4);
    uint32_t* einfo  = (uint32_t*)allocb((size_t)2*EHGT*4);
    size_t region = off;
    // ---- conv scratch (q/ka/vm per-dir) ----
    float* q_i  = (float*)allocb((size_t)2*NI*DD*4);
    float* q_d  = (float*)allocb((size_t)2*ND*DD*4);
    u16* ka16 = (u16*)allocb((size_t)8*NI*DD*2);   // [dir][r][NI][DD]; also combine f32 temp
    u16* vm16 = (u16*)allocb((size_t)8*NI*DD*2);
    u16* bcur_h = (u16*)allocb((size_t)NROW*DD*2);
    u16* bcur_l = (u16*)allocb((size_t)NROW*DD*2);
    u16* bagg_h = (u16*)allocb((size_t)NROW*512*2);   // [NROW][512] K-concat (dir0|dir1)
    u16* bagg_l = (u16*)allocb((size_t)NROW*512*2);
    // ---- pooling/transformer overlay ----
    off = region;
    float* hvec = (float*)allocb(NROW*4);
    float* pscore = (float*)allocb(NROW*4);
    int* seln   = (int*)allocb(BB*KPOOL*4);
    float* sels = (float*)allocb(BB*KPOOL*4);
    float* xp   = (float*)allocb((size_t)BB*KPOOL*DD*4);
    float* o2   = (float*)allocb((size_t)BB*KPOOL*DD*4);
    float* gatt = (float*)allocb((size_t)BB*KPOOL*DD*4);
    u16* bxp_h = (u16*)allocb((size_t)BB*KPOOL*DD*2);
    u16* bxp_l = (u16*)allocb((size_t)BB*KPOOL*DD*2);
    u16* qbh = (u16*)allocb((size_t)BB*KPOOL*DD*2);
    u16* kbh = (u16*)allocb((size_t)BB*KPOOL*DD*2);
    u16* vbh = (u16*)allocb((size_t)BB*KPOOL*DD*2);
    u16* bao_h = (u16*)allocb((size_t)BB*KPOOL*DD*2);
    u16* bao_l = (u16*)allocb((size_t)BB*KPOOL*DD*2);

    const int st_tab[2][4] = {{0,1,0,0},{0,0,1,0}};
    const int dt_tab[2][4] = {{0,0,1,0},{0,1,0,0}};
    const int MR = BB*KPOOL;

    fill_u32<<<(2*BB*512+255)/256,256,0,stream>>>((uint32_t*)ubuf, 0u, 2*BB*512);
    float* wtkF = (float*)ka16;
    float* wtvF = (float*)ka16 + 16*MAT;
    combine_all<<<dim3(256,32),256,0,stream>>>(hgt_Wk, hgt_Wv, hgt_arel, hgt_mrel, wtkF, wtvF);
    WCArgs wc;
    wc.in[0]=wtkF;   wc.oh[0]=bwtk_h; wc.ol[0]=bwtk_l; wc.cnt[0]=16;
    wc.in[1]=wtvF;   wc.oh[1]=bwtv_h; wc.ol[1]=bwtv_l; wc.cnt[1]=16;
    wc.in[2]=hgt_Wq; wc.oh[2]=bwq_h;  wc.ol[2]=bwq_l;  wc.cnt[2]=8;
    wc.in[3]=t_wq;   wc.oh[3]=btw_h;          wc.ol[3]=btw_l;          wc.cnt[3]=1;
    wc.in[4]=t_wk;   wc.oh[4]=btw_h+1*MAT;    wc.ol[4]=btw_l+1*MAT;    wc.cnt[4]=1;
    wc.in[5]=t_wv;   wc.oh[5]=btw_h+2*MAT;    wc.ol[5]=btw_l+2*MAT;    wc.cnt[5]=1;
    wc.in[6]=t_wo;   wc.oh[6]=btw_h+3*MAT;    wc.ol[6]=btw_l+3*MAT;    wc.cnt[6]=1;
    wc.nr = 7;
    wcvt_split<<<dim3(256,44),256,0,stream>>>(wc);
    wcvt_wo<<<dim3(256,4),256,0,stream>>>(hgt_Wo, hgt_skip, bwoc_h, bwoc_l);

    for(int bi=0;bi<2;bi++){
        int ib = bi*6;
        const float* x_inst = (const float*)d_in[ib+0];
        const float* x_data = (const float*)d_in[ib+1];
        const int* ecp = (const int*)d_in[ib+2];
        const int* eip = (const int*)d_in[ib+3];
        const int* eop = (const int*)d_in[ib+4];
        const int* ekp = (const int*)d_in[ib+5];
        const int* rows_f[4] = {ecp, eip, eop, ekp};
        const int* cols_f[4] = {ecp+EC, eip+EI, eop+EO, ekp+EK};

        // ---- CSR build (both dirs, one pass) ----
        CB2 cb;
        for(int r=0;r<4;r++){
            cb.row[r]   = rows_f[r]; cb.col[r]   = cols_f[r]; cb.dt[r]   = dt_tab[0][r]; cb.st[r]   = st_tab[0][r];
            cb.row[4+r] = cols_f[r]; cb.col[4+r] = rows_f[r]; cb.dt[4+r] = dt_tab[1][r]; cb.st[4+r] = st_tab[1][r];
        }
        cb.cnt = ccnt; cb.rowptr = rowptr; cb.einfo = einfo;
        fill_u32<<<(2*NROW+255)/256,256,0,stream>>>(ccnt, 0u, 2*NROW);
        csr_hist2<<<(2*EHGT+255)/256,256,0,stream>>>(cb);
        scan_rowptr2<<<1,1024,0,stream>>>(ccnt, rowptr);
        csr_scatter2<<<(2*EHGT+255)/256,256,0,stream>>>(cb);

        const float* cur_i = x_inst;
        const float* cur_d = x_data;
        cvt_split<<<((NROW*DD/4)+255)/256,256,0,stream>>>(cur_i, NI*DD, cur_d, ND*DD, bcur_h, bcur_l);
        for(int l=0;l<LL;l++){
            float* nxt_i = (l==0) ? xa_i : xb_i;
            float* nxt_d = (l==0) ? xa_d : xb_d;

            // --- fused both-dir mega GEMM: 2×{Q(2, f32, split) + KA(4, bf16) + VM(4, bf16)} ---
            GArgs g1; int nb1 = 0, ndx = 0;
            auto addg = [&](int srctype, const u16* Bh, const u16* Bl, float* Cm, u16* Om, int M, int mode, int prec){
                GDesc& d = g1.d[ndx];
                size_t ao = srctype ? (size_t)NI*DD : 0;
                d.Ah = bcur_h + ao; d.Al = bcur_l + ao;
                d.Bh = Bh; d.Bl = Bl; d.C = Cm;
                d.Oh = Om; d.Ol = nullptr; d.X = nullptr; d.skipp = nullptr;
                d.mblks = M/128; d.mode = mode; d.prec = prec; d.kdim = 256;
                nb1 += M/128; ndx++;
            };
            for(int dir=0;dir<2;dir++){
                int wb = l*2 + dir;
                addg(0, bwq_h + (size_t)(wb*2+0)*MAT, bwq_l + (size_t)(wb*2+0)*MAT,
                     q_i + (size_t)dir*NI*DD, nullptr, NI, 0, 0);
                addg(1, bwq_h + (size_t)(wb*2+1)*MAT, bwq_l + (size_t)(wb*2+1)*MAT,
                     q_d + (size_t)dir*ND*DD, nullptr, ND, 0, 0);
                for(int r=0;r<4;r++){
                    int st = st_tab[dir][r];
                    addg(st, bwtk_h + (size_t)(wb*4+r)*MAT, bwtk_l + (size_t)(wb*4+r)*MAT,
                         nullptr, ka16 + (size_t)(dir*4 + r)*NI*DD, st ? ND : NI, 4, 1);
                }
                for(int r=0;r<4;r++){
                    int st = st_tab[dir][r];
                    addg(st, bwtv_h + (size_t)(wb*4+r)*MAT, bwtv_l + (size_t)(wb*4+r)*MAT,
                         nullptr, vm16 + (size_t)(dir*4 + r)*NI*DD, st ? ND : NI, 4, 1);
                }
            }
            g1.nd = ndx;
            gemm_mfma<<<dim3(nb1,2),256,0,stream>>>(g1);

            // --- fused edge phase, both dirs in one dispatch ---
            hgt_fused<<<2*(NROW/4),256,0,stream>>>(rowptr, einfo,
                q_i, q_d, ka16, vm16, hgt_prel + (size_t)l*2*4*HH, bagg_h, bagg_l);

            // --- fused Wo GEMM: K=512 concat, gate-folded weights, mode 6 epilogue ---
            GArgs g3; g3.nd = 2;
            for(int t=0;t<2;t++){
                GDesc& d = g3.d[t];
                d.Ah = bagg_h + (t ? (size_t)NI*512 : 0);
                d.Al = bagg_l + (t ? (size_t)NI*512 : 0);
                d.Bh = bwoc_h + (size_t)(l*2+t)*131072;
                d.Bl = bwoc_l + (size_t)(l*2+t)*131072;
                d.C = t ? nxt_d : nxt_i;
                d.Oh = bcur_h + (t ? (size_t)NI*DD : 0);
                d.Ol = bcur_l + (t ? (size_t)NI*DD : 0);
                d.X = t ? cur_d : cur_i;
                d.skipp = hgt_skip + l*4 + t;
                d.mblks = (t ? ND : NI)/128;
                d.mode = 6; d.prec = 0; d.kdim = 512;
            }
            gemm_mfma<<<dim3(NI/128 + ND/128,2),256,0,stream>>>(g3);

            cur_i = nxt_i;
            cur_d = nxt_d;
        }

        // -------- SAGPooling (CSR-based, no atomics) --------
        pool_h2<<<NROW/4,256,0,stream>>>(cur_i, cur_d, pool_W, hvec);
        pool_csr<<<NROW/4,256,0,stream>>>(rowptr, einfo, hvec, pool_att, pscore);
        topk_rank<<<dim3(384,BB),256,0,stream>>>(pscore, pool_bias, seln, sels);
        gather_xp<<<BB*KPOOL,256,0,stream>>>(seln, sels, cur_i, cur_d, xp, bxp_h, bxp_l);

        // -------- transformer --------
        GArgs g4; g4.nd = 3;
        for(int t=0;t<3;t++){
            GDesc& d = g4.d[t];
            d.Ah=bxp_h; d.Al=bxp_l;
            d.Bh=btw_h + (size_t)t*MAT; d.Bl=btw_l + (size_t)t*MAT;
            d.C = nullptr;
            d.Oh = (t==0)? qbh : (t==1)? kbh : vbh;
            d.Ol = nullptr;
            d.X = nullptr; d.skipp = nullptr;
            d.mblks = MR/128; d.mode = 4; d.prec = 0; d.kdim = 256;
        }
        gemm_mfma<<<dim3(3*(MR/128),2),256,0,stream>>>(g4);
        attn_mfma<<<dim3(BB*HH, KPOOL/64),256,0,stream>>>(qbh, kbh, vbh, bao_h, bao_l);
        GArgs g5; g5.nd = 1;
        {
            GDesc& d = g5.d[0];
            d.Ah=bao_h; d.Al=bao_l;
            d.Bh=btw_h + (size_t)3*MAT; d.Bl=btw_l + (size_t)3*MAT;
            d.C=o2; d.Oh=nullptr; d.Ol=nullptr; d.X=nullptr; d.skipp=nullptr;
            d.mblks=MR/128; d.mode=0; d.prec=0; d.kdim=256;
        }
        gemm_mfma<<<dim3(MR/128,2),256,0,stream>>>(g5);
        ln_kernel<<<MR,256,0,stream>>>(xp, o2, ln_g, ln_b, gatt);
        feat_reduce2<<<dim3(BB,12),256,0,stream>>>(xp, gatt, bi ? vbuf : ubuf);
    }

    cosine_kernel<<<BB,64,0,stream>>>(ubuf, vbuf, out);
}

// Round 25
// 888.911 us; speedup vs baseline: 2.1878x; 1.0326x over previous
//
#include <hip/hip_runtime.h>
#include <math.h>
#include <stdint.h>

#define LL 2
#define HH 4
#define DHH 64
#define DD 256
#define BB 8
#define NI 8192
#define ND 4096
#define NROW 12288
#define KPOOL 768
#define EC 65536
#define EI 32768
#define EO 32768
#define EK 8192
#define EHGT (EC+EI+EO+EK)

typedef unsigned short u16;
typedef short bf16x8 __attribute__((ext_vector_type(8)));
typedef float f32x4 __attribute__((ext_vector_type(4)));
typedef unsigned short u16x4 __attribute__((ext_vector_type(4)));

__device__ inline float gelu_f(float x){ return 0.5f*x*(1.f+erff(x*0.70710678118654752f)); }
__device__ inline u16 f2b(float x){ uint32_t u=__float_as_uint(x); return (u16)((u + 0x7fffu + ((u>>16)&1u))>>16); }
__device__ inline float b2f(u16 h){ return __uint_as_float(((uint32_t)h)<<16); }

// ---------------- generic fill ----------------
__global__ void fill_u32(uint32_t* p, uint32_t v, int n){
    int i = blockIdx.x*256 + threadIdx.x;
    if(i<n) p[i]=v;
}

// ---------------- activation split-convert + packed f32 copy ----------------
__global__ void cvt_split(const float* __restrict__ A, int nA, const float* __restrict__ B, int nB,
                          u16* __restrict__ oh, u16* __restrict__ ol, float* __restrict__ xc){
    int i = (blockIdx.x*256 + threadIdx.x)*4;
    int tot = nA + nB;
    if(i >= tot) return;
    float4 v = (i < nA) ? *(const float4*)(A + i) : *(const float4*)(B + (i - nA));
    float vv[4] = {v.x, v.y, v.z, v.w};
    u16x4 h4, l4;
    #pragma unroll
    for(int j=0;j<4;j++){
        float x = vv[j];
        u16 h = f2b(x);
        h4[j] = h;
        l4[j] = f2b(x - b2f(h));
    }
    *(u16x4*)(oh + i) = h4;
    *(u16x4*)(ol + i) = l4;
    *(float4*)(xc + i) = v;
}

// ---------------- weight transpose + split ----------------
struct WCArgs { const float* in[8]; u16* oh[8]; u16* ol[8]; int cnt[8]; int nr; };
__global__ void wcvt_split(WCArgs a){
    int mat = blockIdx.y, ri = 0;
    while(ri < a.nr-1 && mat >= a.cnt[ri]){ mat -= a.cnt[ri]; ri++; }
    const float* in = a.in[ri] + (size_t)mat*65536;
    u16* oh = a.oh[ri] + (size_t)mat*65536;
    u16* ol = a.ol[ri] + (size_t)mat*65536;
    int n = blockIdx.x, k = threadIdx.x;
    float x = in[(size_t)k*DD + n];
    u16 h = f2b(x);
    oh[n*DD + k] = h;
    ol[n*DD + k] = f2b(x - b2f(h));
}

// ---------------- Wo weights: gate-folded, K-concatenated transpose+split ----------------
__global__ void wcvt_wo(const float* __restrict__ Wo, const float* __restrict__ skip,
                        u16* __restrict__ oh, u16* __restrict__ ol){
    int combo = blockIdx.y;          // l*2 + t
    int l = combo >> 1, t = combo & 1;
    int n = blockIdx.x, k = threadIdx.x;
    #pragma unroll
    for(int dir=0;dir<2;dir++){
        int wi = (l*2+dir)*2 + t;
        float gg = 1.f/(1.f+expf(-skip[wi]));
        float x = 0.5f*gg*Wo[(size_t)wi*65536 + (size_t)k*DD + n];
        size_t o = (size_t)combo*131072 + (size_t)n*512 + dir*256 + k;
        u16 hh = f2b(x);
        oh[o] = hh;
        ol[o] = f2b(x - b2f(hh));
    }
}

// ---------------- MFMA batched GEMM with fused epilogues; branch via blockIdx.z ----------------
// prec=0: split hi/lo (3 MFMA/step); prec=1: hi-only
// mode 0: C=f32   mode 4: Oh=plain bf16
// mode 6: v=relu(acc + cx*X); C=v; Oh/Ol=split(v)
struct GDesc { const u16* Ah; const u16* Al; const u16* Bh; const u16* Bl;
               float* C; u16* Oh; u16* Ol;
               const float* X; const float* skipp;
               size_t strA; size_t strC; size_t strO; size_t strX;
               int mblks; int mode; int prec; int kdim; };
struct GArgs { GDesc d[20]; int nd; };

__global__ __launch_bounds__(256) void gemm_mfma(GArgs ga){
    __shared__ u16 SBUF[2*128*64];
    char* Abuf = (char*)SBUF;
    char* Bbuf = (char*)(SBUF + 128*64);
    int mb = blockIdx.x, di = 0;
    while(di < ga.nd-1 && mb >= ga.d[di].mblks){ mb -= ga.d[di].mblks; di++; }
    GDesc g = ga.d[di];
    const size_t br = blockIdx.z;
    const u16* gAh = g.Ah + br*g.strA;
    const u16* gAl = g.Al + br*g.strA;
    const int prec = g.prec;
    const int KD = g.kdim;
    const int m0 = mb*128, n0 = blockIdx.y*128;
    const int tid = threadIdx.x;
    const int lane = tid & 63, wid = tid >> 6;
    const int wm = (wid>>1)*64, wn = (wid&1)*64;
    const int l15 = lane & 15, l4 = lane >> 4;
    const int srow = tid >> 1, hf = tid & 1;
    const int ssw = (srow&7)<<4;
    const int c0 = (hf*32) ^ ssw;
    const int c1 = (hf*32+16) ^ ssw;
    const int c2 = (64+hf*32) ^ ssw;
    const int c3 = (64+hf*32+16) ^ ssw;
    const int rbyte = srow*128;
    const u16* __restrict__ Aph = gAh + (size_t)(m0 + srow)*KD + hf*16;
    const u16* __restrict__ Apl = gAl + (size_t)(m0 + srow)*KD + hf*16;
    const u16* __restrict__ Bph = g.Bh + (size_t)(n0 + srow)*KD + hf*16;
    const u16* __restrict__ Bpl = g.Bl + (size_t)(n0 + srow)*KD + hf*16;
    f32x4 acc[4][4] = {};
    bf16x8 r0, r1, r2, r3, r4, r5, r6, r7;
    r0 = *(const bf16x8*)(Aph);
    r1 = *(const bf16x8*)(Aph + 8);
    r4 = *(const bf16x8*)(Bph);
    r5 = *(const bf16x8*)(Bph + 8);
    if(!prec){
        r2 = *(const bf16x8*)(Apl);
        r3 = *(const bf16x8*)(Apl + 8);
        r6 = *(const bf16x8*)(Bpl);
        r7 = *(const bf16x8*)(Bpl + 8);
    }
    for(int k0=0;k0<KD;k0+=32){
        __syncthreads();
        *(bf16x8*)(Abuf + rbyte + c0) = r0; *(bf16x8*)(Abuf + rbyte + c1) = r1;
        *(bf16x8*)(Bbuf + rbyte + c0) = r4; *(bf16x8*)(Bbuf + rbyte + c1) = r5;
        if(!prec){
            *(bf16x8*)(Abuf + rbyte + c2) = r2; *(bf16x8*)(Abuf + rbyte + c3) = r3;
            *(bf16x8*)(Bbuf + rbyte + c2) = r6; *(bf16x8*)(Bbuf + rbyte + c3) = r7;
        }
        __syncthreads();
        if(k0 + 32 < KD){
            int kn = k0 + 32;
            r0 = *(const bf16x8*)(Aph + kn);     r1 = *(const bf16x8*)(Aph + kn + 8);
            r4 = *(const bf16x8*)(Bph + kn);     r5 = *(const bf16x8*)(Bph + kn + 8);
            if(!prec){
                r2 = *(const bf16x8*)(Apl + kn); r3 = *(const bf16x8*)(Apl + kn + 8);
                r6 = *(const bf16x8*)(Bpl + kn); r7 = *(const bf16x8*)(Bpl + kn + 8);
            }
        }
        bf16x8 afh[4], bfh[4];
        #pragma unroll
        for(int i=0;i<4;i++){
            int ar = wm + i*16 + l15;
            int abase = ar*128;
            afh[i] = *(const bf16x8*)(Abuf + abase + ((l4*16) ^ ((ar&7)<<4)));
            int br_ = wn + i*16 + l15;
            int bbase = br_*128;
            bfh[i] = *(const bf16x8*)(Bbuf + bbase + ((l4*16) ^ ((br_&7)<<4)));
        }
        #pragma unroll
        for(int i=0;i<4;i++)
            #pragma unroll
            for(int j=0;j<4;j++)
                acc[i][j] = __builtin_amdgcn_mfma_f32_16x16x32_bf16(afh[i], bfh[j], acc[i][j], 0,0,0);
        if(!prec){
            bf16x8 afl[4], bfl[4];
            #pragma unroll
            for(int i=0;i<4;i++){
                int ar = wm + i*16 + l15;
                int abase = ar*128;
                afl[i] = *(const bf16x8*)(Abuf + abase + ((64 + l4*16) ^ ((ar&7)<<4)));
                int br_ = wn + i*16 + l15;
                int bbase = br_*128;
                bfl[i] = *(const bf16x8*)(Bbuf + bbase + ((64 + l4*16) ^ ((br_&7)<<4)));
            }
            #pragma unroll
            for(int i=0;i<4;i++)
                #pragma unroll
                for(int j=0;j<4;j++){
                    acc[i][j] = __builtin_amdgcn_mfma_f32_16x16x32_bf16(afh[i], bfl[j], acc[i][j], 0,0,0);
                    acc[i][j] = __builtin_amdgcn_mfma_f32_16x16x32_bf16(afl[i], bfh[j], acc[i][j], 0,0,0);
                }
        }
    }
    // ---- coalesced epilogue via LDS restage ----
    const int mode = g.mode;
    float* Cb = g.C + br*g.strC;
    u16* Ohb = g.Oh + br*g.strO;
    u16* Olb = g.Ol + br*g.strO;
    const float* Xb = g.X + br*g.strX;
    float cx = 0.f;
    if(mode == 6){
        float g0 = 1.f/(1.f + expf(-g.skipp[0]));
        float g1 = 1.f/(1.f + expf(-g.skipp[2]));
        cx = 1.f - 0.5f*(g0 + g1);
    }
    float* LDSf = (float*)SBUF;
    const int lrow = tid >> 5;
    const int cc4 = (tid & 31)*4;
    #pragma unroll
    for(int half=0; half<2; half++){
        __syncthreads();
        if((wid>>1) == half){
            #pragma unroll
            for(int i=0;i<4;i++)
                #pragma unroll
                for(int j=0;j<4;j++)
                    #pragma unroll
                    for(int r=0;r<4;r++)
                        LDSf[(i*16 + l4*4 + r)*128 + wn + j*16 + l15] = acc[i][j][r];
        }
        __syncthreads();
        #pragma unroll
        for(int k=0;k<8;k++){
            int row = lrow + k*8;
            size_t o = (size_t)(m0 + half*64 + row)*DD + n0 + cc4;
            float4 v = *(const float4*)&LDSf[row*128 + cc4];
            float vv[4] = {v.x, v.y, v.z, v.w};
            if(mode==0){
                *(float4*)(Cb + o) = v;
            } else if(mode==4){
                u16x4 h4;
                #pragma unroll
                for(int j=0;j<4;j++) h4[j] = f2b(vv[j]);
                *(u16x4*)(Ohb + o) = h4;
            } else {   // mode 6
                float4 x = *(const float4*)(Xb + o);
                float xx[4] = {x.x, x.y, x.z, x.w};
                float4 cv;
                float* cvv = (float*)&cv;
                u16x4 h4, lo4;
                #pragma unroll
                for(int j=0;j<4;j++){
                    float v3 = vv[j] + cx*xx[j];
                    v3 = v3 > 0.f ? v3 : 0.f;
                    cvv[j] = v3;
                    u16 hh = f2b(v3); h4[j]=hh; lo4[j]=f2b(v3-b2f(hh));
                }
                *(float4*)(Cb + o) = cv;
                *(u16x4*)(Ohb + o) = h4;
                *(u16x4*)(Olb + o) = lo4;
            }
        }
    }
}

// ---------- combine ----------
__global__ void combine_all(const float* __restrict__ Wk, const float* __restrict__ Wv,
                            const float* __restrict__ Ra, const float* __restrict__ Rm,
                            float* __restrict__ wtk, float* __restrict__ wtv){
    const int st_tab[2][4] = {{0,1,0,0},{0,0,1,0}};
    int combo = blockIdx.y;
    int idx = combo >> 1, kv = combo & 1;
    int r = idx & 3, wb = idx >> 2, dir = wb & 1;
    int st = st_tab[dir][r];
    const float* W = (kv ? Wv : Wk) + (size_t)(wb*2 + st)*65536;
    const float* R = (kv ? Rm : Ra) + (size_t)idx*16384;
    float* o = (kv ? wtv : wtk) + (size_t)idx*65536;
    int d = blockIdx.x, c = threadIdx.x;
    int h = c >> 6, f = c & 63;
    const float* Wrow = W + d*DD + h*64;
    const float* Rh = R + h*4096 + f;
    float s = 0.f;
    #pragma unroll 8
    for(int k=0;k<64;k++) s += Wrow[k]*Rh[k*64];
    o[d*DD + c] = s;
}

// ---------------- CSR build ----------------
__device__ inline void edge_decode(int e, int& r, int& el){
    if(e < EC){ r=0; el=e; }
    else if(e < EC+EI){ r=1; el=e-EC; }
    else if(e < EC+EI+EO){ r=2; el=e-(EC+EI); }
    else { r=3; el=e-(EC+EI+EO); }
}

struct CB2 {
    const int* row[8]; const int* col[8];
    int dt[8]; int st[8];
    uint32_t* cnt; uint32_t* rowptr; uint32_t* einfo;
};

__global__ void csr_hist2(CB2 a){
    int ge = blockIdx.x*256 + threadIdx.x;
    if(ge >= 2*EHGT) return;
    int dir = ge >= EHGT;
    int e = ge - dir*EHGT;
    int r, el; edge_decode(e, r, el);
    int idx = dir*4 + r;
    int c = a.col[idx][el];
    int dst = dir*NROW + (a.dt[idx] ? (NI + c) : c);
    atomicAdd(&a.cnt[dst], 1u);
}

__global__ __launch_bounds__(1024) void scan_rowptr2(uint32_t* cnt, uint32_t* rowptr){
    __shared__ uint32_t part[1024];
    int t = threadIdx.x;
    int base = t*24;
    uint32_t lpre[24];
    uint32_t sum = 0;
    #pragma unroll
    for(int i=0;i<24;i++){
        uint32_t c = cnt[base+i];
        lpre[i] = sum; sum += c;
        cnt[base+i] = 0;
    }
    part[t] = sum;
    __syncthreads();
    for(int offs=1; offs<1024; offs<<=1){
        uint32_t v = (t>=offs) ? part[t-offs] : 0u;
        __syncthreads();
        part[t] += v;
        __syncthreads();
    }
    uint32_t pre = (t==0) ? 0u : part[t-1];
    #pragma unroll
    for(int i=0;i<24;i++) rowptr[base+i] = pre + lpre[i];
    if(t==1023) rowptr[2*NROW] = part[1023];
}

__global__ void csr_scatter2(CB2 a){
    int ge = blockIdx.x*256 + threadIdx.x;
    if(ge >= 2*EHGT) return;
    int dir = ge >= EHGT;
    int e = ge - dir*EHGT;
    int r, el; edge_decode(e, r, el);
    int idx = dir*4 + r;
    int c = a.col[idx][el];
    int dst = dir*NROW + (a.dt[idx] ? (NI + c) : c);
    int src = a.row[idx][el];
    uint32_t p = a.rowptr[dst] + atomicAdd(&a.cnt[dst], 1u);
    uint32_t vmidx = (uint32_t)(r*NI + src);
    uint32_t hom = a.st[idx] ? (uint32_t)(NI + src) : (uint32_t)src;
    a.einfo[p] = vmidx | (hom << 16);
}

// ---------------- fused HGT edge phase, BOTH branches (one dir): wave per dst ----------------
// grid x = 2br * NROW/4. bagg is [br][NROW][512], dir gives col offset.
__global__ __launch_bounds__(256) void hgt_fused(const uint32_t* __restrict__ rowptr,
                                                 const uint32_t* __restrict__ einfo,
                                                 const float* __restrict__ q_i,
                                                 const float* __restrict__ q_d,
                                                 const u16* __restrict__ ka,
                                                 const u16* __restrict__ vm,
                                                 const float* __restrict__ prel,
                                                 u16* __restrict__ bagg_h,
                                                 u16* __restrict__ bagg_l,
                                                 int dir){
    int wv = threadIdx.x >> 6, lane = threadIdx.x & 63;
    int bx = blockIdx.x;
    int brx = 0;
    if(bx >= (NROW/4)){ brx = 1; bx -= (NROW/4); }
    int rowi = bx*4 + wv;
    const uint32_t* rp = rowptr + (size_t)brx*(2*NROW+1) + (size_t)dir*NROW;
    uint32_t p0 = rp[rowi], p1 = rp[rowi+1];
    const uint32_t* ei = einfo + (size_t)brx*(2*EHGT);
    int h = lane >> 4;
    const float* qi = q_i + (size_t)brx*NI*DD;
    const float* qd = q_d + (size_t)brx*ND*DD;
    const u16* kad = ka + (size_t)brx*4*NI*DD;
    const u16* vmd = vm + (size_t)brx*4*NI*DD;
    const float* qrow = (rowi < NI) ? (qi + (size_t)rowi*DD) : (qd + (size_t)(rowi-NI)*DD);
    float4 q4 = *(const float4*)(qrow + lane*4);
    float pr0 = prel[0*HH+h]*0.125f, pr1 = prel[1*HH+h]*0.125f;
    float pr2 = prel[2*HH+h]*0.125f, pr3 = prel[3*HH+h]*0.125f;
    float m = -INFINITY, den = 0.f;
    float4 o4 = {0.f,0.f,0.f,0.f};
    for(uint32_t p = p0; p < p1; p++){
        uint32_t vmidx = ei[p] & 0xffffu;
        int r = vmidx >> 13;
        uint2 kr = *(const uint2*)(kad + (size_t)vmidx*DD + lane*4);
        uint2 vr = *(const uint2*)(vmd + (size_t)vmidx*DD + lane*4);
        float k0 = __uint_as_float(kr.x << 16), k1 = __uint_as_float(kr.x & 0xffff0000u);
        float k2 = __uint_as_float(kr.y << 16), k3 = __uint_as_float(kr.y & 0xffff0000u);
        float v0 = __uint_as_float(vr.x << 16), v1 = __uint_as_float(vr.x & 0xffff0000u);
        float v2 = __uint_as_float(vr.y << 16), v3 = __uint_as_float(vr.y & 0xffff0000u);
        float d = q4.x*k0 + q4.y*k1 + q4.z*k2 + q4.w*k3;
        d += __shfl_xor(d, 1); d += __shfl_xor(d, 2);
        d += __shfl_xor(d, 4); d += __shfl_xor(d, 8);
        float pf = (r==0) ? pr0 : (r==1) ? pr1 : (r==2) ? pr2 : pr3;
        float s = d * pf;
        float nm = fmaxf(m, s);
        float sc_ = expf(m - nm);
        float pe = expf(s - nm);
        den = den*sc_ + pe;
        o4.x = o4.x*sc_ + pe*v0;
        o4.y = o4.y*sc_ + pe*v1;
        o4.z = o4.z*sc_ + pe*v2;
        o4.w = o4.w*sc_ + pe*v3;
        m = nm;
    }
    float inv = 1.f/(den + 1e-16f);
    float vals[4] = {o4.x*inv, o4.y*inv, o4.z*inv, o4.w*inv};
    u16x4 h4, l4;
    #pragma unroll
    for(int j=0;j<4;j++){
        float g = gelu_f(vals[j]);
        u16 hh = f2b(g);
        h4[j] = hh;
        l4[j] = f2b(g - b2f(hh));
    }
    size_t ob = (size_t)brx*NROW*512 + (size_t)rowi*512 + dir*256 + lane*4;
    *(u16x4*)(bagg_h + ob) = h4;
    *(u16x4*)(bagg_l + ob) = l4;
}

// ---------------- pooling ----------------
__global__ void pool_h2(const float* __restrict__ xi, const float* __restrict__ xd,
                        const float* __restrict__ w, float* __restrict__ h){
    int node = blockIdx.x*4 + (threadIdx.x>>6);
    int lane = threadIdx.x & 63;
    const float* xr = (node < NI) ? (xi + (size_t)node*DD) : (xd + (size_t)(node-NI)*DD);
    float s = 0.f;
    for(int j=lane;j<DD;j+=64) s += xr[j]*w[j];
    for(int m=32;m;m>>=1) s += __shfl_xor(s, m);
    if(lane==0) h[node] = s;
}

__global__ __launch_bounds__(256) void pool_csr(const uint32_t* __restrict__ rowptr,
                                                const uint32_t* __restrict__ einfo,
                                                const float* __restrict__ h,
                                                const float* __restrict__ att,
                                                float* __restrict__ score){
    int w = blockIdx.x*4 + (threadIdx.x >> 6);
    int lane = threadIdx.x & 63;
    if(w >= NROW) return;
    uint32_t p0 = rowptr[w], p1 = rowptr[w+1];
    float a0 = att[0], a1 = att[1];
    float hn = h[w];
    float es = a0*hn + a1*hn;
    es = es >= 0.f ? es : 0.2f*es;
    float m = -INFINITY;
    for(uint32_t p = p0+lane; p < p1; p += 64){
        float hs = h[einfo[p] >> 16];
        float e = a0*hs + a1*hn;
        e = e >= 0.f ? e : 0.2f*e;
        m = fmaxf(m, e);
    }
    #pragma unroll
    for(int s=32;s;s>>=1) m = fmaxf(m, __shfl_xor(m, s));
    m = fmaxf(m, es);
    float lden = 0.f, lnum = 0.f;
    for(uint32_t p = p0+lane; p < p1; p += 64){
        float hs = h[einfo[p] >> 16];
        float e = a0*hs + a1*hn;
        e = e >= 0.f ? e : 0.2f*e;
        float a = expf(e - m);
        lden += a; lnum += a*hs;
    }
    #pragma unroll
    for(int s=32;s;s>>=1){ lden += __shfl_xor(lden, s); lnum += __shfl_xor(lnum, s); }
    float aself = expf(es - m);
    lden += aself; lnum += aself*hn;
    if(lane==0) score[w] = lnum/(lden + 1e-16f);
}

// ---------------- top-768 of 1536 per graph: wave-per-candidate rank ----------------
__global__ __launch_bounds__(256) void topk_rank(const float* __restrict__ score,
                                                 const float* __restrict__ bias,
                                                 int* __restrict__ sel_node,
                                                 float* __restrict__ sel_scale){
    int b = blockIdx.y;
    int wid = threadIdx.x >> 6, lane = threadIdx.x & 63;
    int i = blockIdx.x*4 + wid;
    int nodei = (i<1024) ? (b*1024 + i) : (NI + b*512 + (i-1024));
    float ki = score[nodei];
    int r = 0;
    #pragma unroll
    for(int s=0;s<24;s++){
        int j = s*64 + lane;
        int nodej = (j<1024) ? (b*1024 + j) : (NI + b*512 + (j-1024));
        float kj = score[nodej];
        r += (kj > ki) || (kj == ki && j < i);
    }
    #pragma unroll
    for(int m=32;m;m>>=1) r += __shfl_xor(r, m);
    if(lane==0 && r < KPOOL){
        sel_node[b*KPOOL + r] = nodei;
        sel_scale[b*KPOOL + r] = tanhf(ki + bias[0]);
    }
}

__global__ void gather_xp(const int* __restrict__ sel, const float* __restrict__ scale,
                          const float* __restrict__ xi, const float* __restrict__ xd,
                          float* __restrict__ xp, u16* __restrict__ bh, u16* __restrict__ bl){
    int i = blockIdx.x*256 + threadIdx.x;
    int rowp = i >> 8, c = i & 255;
    int node = sel[rowp];
    float s = scale[rowp];
    float v = (node < NI) ? xi[(size_t)node*DD + c] : xd[(size_t)(node-NI)*DD + c];
    float x = v*s;
    xp[i] = x;
    u16 hh = f2b(x);
    bh[i] = hh;
    bl[i] = f2b(x - b2f(hh));
}

// ---------------- MFMA flash attention ----------------
__global__ __launch_bounds__(256) void attn_mfma(const u16* __restrict__ Qh,
                                                 const u16* __restrict__ Kh,
                                                 const u16* __restrict__ Vh,
                                                 u16* __restrict__ aoh, u16* __restrict__ aol){
    __shared__ u16 KhS[64*64], VtS[64*64];
    char* KhB = (char*)KhS; char* VtB = (char*)VtS;
    int bh = blockIdx.x;
    int b = bh >> 2, h = bh & 3;
    int q0 = blockIdx.y * 64;
    int tid = threadIdx.x;
    int lane = tid & 63;
    int w = tid >> 6;
    int l15 = lane & 15, l4 = lane >> 4;
    size_t qrow = (size_t)(b*KPOOL + q0 + w*16 + l15);
    bf16x8 qh[2];
    #pragma unroll
    for(int c=0;c<2;c++)
        qh[c] = *(const bf16x8*)(Qh + qrow*DD + h*64 + c*32 + l4*8);
    float mreg = -INFINITY, lreg = 0.f;
    f32x4 O[4] = {};
    for(int k0=0;k0<KPOOL;k0+=64){
        __syncthreads();
        {
            int row = tid >> 2, q4 = tid & 3;
            size_t gbase = ((size_t)(b*KPOOL + k0 + row))*DD + h*64 + q4*16;
            bf16x8 k0v = *(const bf16x8*)(Kh + gbase);
            bf16x8 k1v = *(const bf16x8*)(Kh + gbase + 8);
            int sw = (row&7)<<4;
            int colb = q4*32;
            *(bf16x8*)(KhB + row*128 + (colb ^ sw))      = k0v;
            *(bf16x8*)(KhB + row*128 + ((colb+16) ^ sw)) = k1v;
            int row0 = (tid >> 3)*2, dhg = (tid & 7)*8;
            size_t vbase = ((size_t)(b*KPOOL + k0 + row0))*DD + h*64 + dhg;
            bf16x8 va = *(const bf16x8*)(Vh + vbase);
            bf16x8 vb = *(const bf16x8*)(Vh + vbase + DD);
            #pragma unroll
            for(int j=0;j<8;j++){
                int dh = dhg + j;
                uint32_t pk = (uint32_t)(u16)(short)va[j] | ((uint32_t)(u16)(short)vb[j] << 16);
                *(uint32_t*)(VtB + dh*128 + ((row0*2) ^ ((dh&7)<<4))) = pk;
            }
        }
        __syncthreads();
        f32x4 s[4] = {};
        #pragma unroll
        for(int t=0;t<4;t++){
            int arow = t*16 + l15;
            int sw = (arow&7)<<4;
            const char* bh_ = KhB + arow*128;
            bf16x8 kh0 = *(const bf16x8*)(bh_ + ((l4*16) ^ sw));
            bf16x8 kh1 = *(const bf16x8*)(bh_ + ((l4*16 + 64) ^ sw));
            s[t] = __builtin_amdgcn_mfma_f32_16x16x32_bf16(kh0, qh[0], s[t], 0,0,0);
            s[t] = __builtin_amdgcn_mfma_f32_16x16x32_bf16(kh1, qh[1], s[t], 0,0,0);
        }
        float cm = -INFINITY;
        #pragma unroll
        for(int t=0;t<4;t++)
            #pragma unroll
            for(int r=0;r<4;r++){ s[t][r] *= 0.125f; cm = fmaxf(cm, s[t][r]); }
        cm = fmaxf(cm, __shfl_xor(cm,16));
        cm = fmaxf(cm, __shfl_xor(cm,32));
        float nm = fmaxf(mreg, cm);
        float es = expf(mreg - nm);
        float ps = 0.f;
        #pragma unroll
        for(int t=0;t<4;t++)
            #pragma unroll
            for(int r=0;r<4;r++){ float pv = expf(s[t][r] - nm); s[t][r] = pv; ps += pv; }
        ps += __shfl_xor(ps,16);
        ps += __shfl_xor(ps,32);
        lreg = lreg*es + ps;
        mreg = nm;
        #pragma unroll
        for(int d=0;d<4;d++){ O[d][0]*=es; O[d][1]*=es; O[d][2]*=es; O[d][3]*=es; }
        #pragma unroll
        for(int c32=0;c32<2;c32++){
            bf16x8 pb;
            #pragma unroll
            for(int j=0;j<8;j++){
                int srcl = ((((lane>>4)*2 + (j>>2)) & 3) << 4) | l15;
                float v0 = __shfl(s[c32*2+0][j&3], srcl, 64);
                float v1 = __shfl(s[c32*2+1][j&3], srcl, 64);
                float v = (lane < 32) ? v0 : v1;
                pb[j] = (short)f2b(v);
            }
            #pragma unroll
            for(int dhb=0; dhb<4; dhb++){
                int vrow = dhb*16 + l15;
                bf16x8 va = *(const bf16x8*)(VtB + vrow*128 + ((c32*64 + l4*16) ^ ((vrow&7)<<4)));
                O[dhb] = __builtin_amdgcn_mfma_f32_16x16x32_bf16(va, pb, O[dhb], 0,0,0);
            }
        }
    }
    float inv = 1.f/lreg;
    #pragma unroll
    for(int dhb=0;dhb<4;dhb++)
        #pragma unroll
        for(int r=0;r<4;r++){
            float val = O[dhb][r]*inv;
            size_t o = qrow*DD + h*64 + dhb*16 + l4*4 + r;
            u16 hh = f2b(val);
            aoh[o] = hh;
            aol[o] = f2b(val - b2f(hh));
        }
}

// layernorm row kernel
__global__ __launch_bounds__(256) void ln_kernel(const float* __restrict__ xp, const float* __restrict__ o2,
                                                 const float* __restrict__ lg, const float* __restrict__ lb,
                                                 float* __restrict__ gatt){
    __shared__ float red[256];
    int r = blockIdx.x, c = threadIdx.x;
    float y = xp[(size_t)r*DD + c] + o2[(size_t)r*DD + c];
    red[c] = y; __syncthreads();
    for(int s=128;s;s>>=1){ if(c<s) red[c] += red[c+s]; __syncthreads(); }
    float mu = red[0]*(1.f/DD);
    __syncthreads();
    float d = y - mu;
    red[c] = d*d; __syncthreads();
    for(int s=128;s;s>>=1){ if(c<s) red[c] += red[c+s]; __syncthreads(); }
    float var = red[0]*(1.f/DD);
    gatt[(size_t)r*DD + c] = lg[c]*d/sqrtf(var+1e-5f) + lb[c];
}

__global__ void feat_reduce2(const float* __restrict__ xp, const float* __restrict__ gatt,
                             float* __restrict__ out){
    int b = blockIdx.x, c = threadIdx.x;
    int j0 = blockIdx.y*64;
    float s1=0.f, s2=0.f;
    for(int j=j0;j<j0+64;j++){
        size_t base = ((size_t)(b*KPOOL + j))*DD + c;
        s1 += xp[base];
        s2 += gatt[base];
    }
    atomicAdd(&out[b*512 + c], s1);
    atomicAdd(&out[b*512 + 256 + c], s2);
}

__global__ void cosine_kernel(const float* __restrict__ u, const float* __restrict__ v,
                              float* __restrict__ out){
    int b = blockIdx.x, t = threadIdx.x;
    float du=0.f, nu=0.f, nv=0.f;
    for(int j=t;j<512;j+=64){
        float a = u[b*512+j], bb = v[b*512+j];
        du += a*bb; nu += a*a; nv += bb*bb;
    }
    for(int m=32;m;m>>=1){
        du += __shfl_xor(du,m); nu += __shfl_xor(nu,m); nv += __shfl_xor(nv,m);
    }
    if(t==0) out[b] = du / (fmaxf(sqrtf(nu),1e-8f)*fmaxf(sqrtf(nv),1e-8f));
}

// =======================================================================
extern "C" void kernel_launch(void* const* d_in, const int* in_sizes, int n_in,
                              void* d_out, int out_size, void* d_ws, size_t ws_size,
                              hipStream_t stream){
    (void)in_sizes; (void)n_in; (void)out_size; (void)ws_size;
    const float* hgt_Wk   = (const float*)d_in[12];
    const float* hgt_Wq   = (const float*)d_in[13];
    const float* hgt_Wv   = (const float*)d_in[14];
    const float* hgt_Wo   = (const float*)d_in[15];
    const float* hgt_arel = (const float*)d_in[16];
    const float* hgt_mrel = (const float*)d_in[17];
    const float* hgt_prel = (const float*)d_in[18];
    const float* hgt_skip = (const float*)d_in[19];
    const float* pool_W   = (const float*)d_in[20];
    const float* pool_att = (const float*)d_in[21];
    const float* pool_bias= (const float*)d_in[22];
    const float* t_wq     = (const float*)d_in[23];
    const float* t_wk     = (const float*)d_in[24];
    const float* t_wv     = (const float*)d_in[25];
    const float* t_wo     = (const float*)d_in[26];
    const float* ln_g     = (const float*)d_in[27];
    const float* ln_b     = (const float*)d_in[28];
    float* out = (float*)d_out;

    char* base = (char*)d_ws;
    size_t off = 0;
    auto allocb = [&](size_t nbytes)->void*{
        void* p = (void*)(base + off);
        off += ((nbytes + 255) & ~(size_t)255);
        return p;
    };
    const size_t MAT = 65536;
    const size_t BRN = (size_t)NROW*DD;       // per-branch node-feature elements
    // ---- persistent ----
    u16* bwtk_h = (u16*)allocb(16*MAT*2); u16* bwtk_l = (u16*)allocb(16*MAT*2);
    u16* bwtv_h = (u16*)allocb(16*MAT*2); u16* bwtv_l = (u16*)allocb(16*MAT*2);
    u16* bwq_h  = (u16*)allocb(8*MAT*2);  u16* bwq_l  = (u16*)allocb(8*MAT*2);
    u16* bwoc_h = (u16*)allocb(4*131072*2); u16* bwoc_l = (u16*)allocb(4*131072*2);
    u16* btw_h  = (u16*)allocb(4*MAT*2);  u16* btw_l  = (u16*)allocb(4*MAT*2);
    float* ubuf = (float*)allocb(BB*512*4);
    float* vbuf = (float*)allocb(BB*512*4);
    float* xa   = (float*)allocb(2*BRN*4);     // [br][NROW][DD]
    float* xcur = (float*)allocb(2*BRN*4);     // [br][NROW][DD]
    // ---- CSR (both branches) ----
    uint32_t* ccnt   = (uint32_t*)allocb((size_t)2*NROW*4);
    uint32_t* rowptr = (uint32_t*)allocb((size_t)2*(2*NROW+1)*4);
    uint32_t* einfo  = (uint32_t*)allocb((size_t)2*2*EHGT*4);
    size_t region = off;
    // ---- conv scratch ([br]...) ----
    float* q_i  = (float*)allocb((size_t)2*NI*DD*4);
    float* q_d  = (float*)allocb((size_t)2*ND*DD*4);
    u16* ka16 = (u16*)allocb((size_t)8*NI*DD*2);   // [br][r][NI][DD]; also combine f32 temp
    u16* vm16 = (u16*)allocb((size_t)8*NI*DD*2);
    u16* bcur_h = (u16*)allocb(2*BRN*2);
    u16* bcur_l = (u16*)allocb(2*BRN*2);
    u16* bagg_h = (u16*)allocb((size_t)2*NROW*512*2);
    u16* bagg_l = (u16*)allocb((size_t)2*NROW*512*2);
    // ---- pooling/transformer overlay ----
    off = region;
    float* hvec = (float*)allocb(NROW*4);
    float* pscore = (float*)allocb(NROW*4);
    int* seln   = (int*)allocb(BB*KPOOL*4);
    float* sels = (float*)allocb(BB*KPOOL*4);
    float* xp   = (float*)allocb((size_t)BB*KPOOL*DD*4);
    float* o2   = (float*)allocb((size_t)BB*KPOOL*DD*4);
    float* gatt = (float*)allocb((size_t)BB*KPOOL*DD*4);
    u16* bxp_h = (u16*)allocb((size_t)BB*KPOOL*DD*2);
    u16* bxp_l = (u16*)allocb((size_t)BB*KPOOL*DD*2);
    u16* qbh = (u16*)allocb((size_t)BB*KPOOL*DD*2);
    u16* kbh = (u16*)allocb((size_t)BB*KPOOL*DD*2);
    u16* vbh = (u16*)allocb((size_t)BB*KPOOL*DD*2);
    u16* bao_h = (u16*)allocb((size_t)BB*KPOOL*DD*2);
    u16* bao_l = (u16*)allocb((size_t)BB*KPOOL*DD*2);

    const int st_tab[2][4] = {{0,1,0,0},{0,0,1,0}};
    const int dt_tab[2][4] = {{0,0,1,0},{0,1,0,0}};
    const int MR = BB*KPOOL;

    fill_u32<<<(2*BB*512+255)/256,256,0,stream>>>((uint32_t*)ubuf, 0u, 2*BB*512);
    float* wtkF = (float*)ka16;
    float* wtvF = (float*)ka16 + 16*MAT;
    combine_all<<<dim3(256,32),256,0,stream>>>(hgt_Wk, hgt_Wv, hgt_arel, hgt_mrel, wtkF, wtvF);
    WCArgs wc;
    wc.in[0]=wtkF;   wc.oh[0]=bwtk_h; wc.ol[0]=bwtk_l; wc.cnt[0]=16;
    wc.in[1]=wtvF;   wc.oh[1]=bwtv_h; wc.ol[1]=bwtv_l; wc.cnt[1]=16;
    wc.in[2]=hgt_Wq; wc.oh[2]=bwq_h;  wc.ol[2]=bwq_l;  wc.cnt[2]=8;
    wc.in[3]=t_wq;   wc.oh[3]=btw_h;          wc.ol[3]=btw_l;          wc.cnt[3]=1;
    wc.in[4]=t_wk;   wc.oh[4]=btw_h+1*MAT;    wc.ol[4]=btw_l+1*MAT;    wc.cnt[4]=1;
    wc.in[5]=t_wv;   wc.oh[5]=btw_h+2*MAT;    wc.ol[5]=btw_l+2*MAT;    wc.cnt[5]=1;
    wc.in[6]=t_wo;   wc.oh[6]=btw_h+3*MAT;    wc.ol[6]=btw_l+3*MAT;    wc.cnt[6]=1;
    wc.nr = 7;
    wcvt_split<<<dim3(256,44),256,0,stream>>>(wc);
    wcvt_wo<<<dim3(256,4),256,0,stream>>>(hgt_Wo, hgt_skip, bwoc_h, bwoc_l);

    // ---- per-branch CSR build + activation convert ----
    for(int bi=0;bi<2;bi++){
        int ib = bi*6;
        const float* x_inst = (const float*)d_in[ib+0];
        const float* x_data = (const float*)d_in[ib+1];
        const int* ecp = (const int*)d_in[ib+2];
        const int* eip = (const int*)d_in[ib+3];
        const int* eop = (const int*)d_in[ib+4];
        const int* ekp = (const int*)d_in[ib+5];
        const int* rows_f[4] = {ecp, eip, eop, ekp};
        const int* cols_f[4] = {ecp+EC, eip+EI, eop+EO, ekp+EK};
        CB2 cb;
        for(int r=0;r<4;r++){
            cb.row[r]   = rows_f[r]; cb.col[r]   = cols_f[r]; cb.dt[r]   = dt_tab[0][r]; cb.st[r]   = st_tab[0][r];
            cb.row[4+r] = cols_f[r]; cb.col[4+r] = rows_f[r]; cb.dt[4+r] = dt_tab[1][r]; cb.st[4+r] = st_tab[1][r];
        }
        cb.cnt = ccnt;
        cb.rowptr = rowptr + (size_t)bi*(2*NROW+1);
        cb.einfo = einfo + (size_t)bi*(2*EHGT);
        fill_u32<<<(2*NROW+255)/256,256,0,stream>>>(ccnt, 0u, 2*NROW);
        csr_hist2<<<(2*EHGT+255)/256,256,0,stream>>>(cb);
        scan_rowptr2<<<1,1024,0,stream>>>(ccnt, cb.rowptr);
        csr_scatter2<<<(2*EHGT+255)/256,256,0,stream>>>(cb);
        cvt_split<<<((NROW*DD/4)+255)/256,256,0,stream>>>(x_inst, NI*DD, x_data, ND*DD,
            bcur_h + bi*BRN, bcur_l + bi*BRN, xcur + bi*BRN);
    }

    // ---- branch-fused layer loop (mega per dir to bound workspace) ----
    for(int l=0;l<LL;l++){
        float* curX = (l==0) ? xcur : xa;
        float* nxtX = (l==0) ? xa : xcur;

        for(int dir=0;dir<2;dir++){
            int wb = l*2 + dir;
            // mega GEMM: Q_i, Q_d, 4×KA, 4×VM for this dir; branch via blockIdx.z
            GArgs g1; int nb1 = 0, ndx = 0;
            auto addg = [&](int srctype, const u16* Bh, const u16* Bl, float* Cm, u16* Om,
                            size_t strC, size_t strO, int M, int mode, int prec){
                GDesc& d = g1.d[ndx];
                size_t ao = srctype ? (size_t)NI*DD : 0;
                d.Ah = bcur_h + ao; d.Al = bcur_l + ao;
                d.Bh = Bh; d.Bl = Bl; d.C = Cm;
                d.Oh = Om; d.Ol = nullptr; d.X = nullptr; d.skipp = nullptr;
                d.strA = BRN; d.strC = strC; d.strO = strO; d.strX = 0;
                d.mblks = M/128; d.mode = mode; d.prec = prec; d.kdim = 256;
                nb1 += M/128; ndx++;
            };
            addg(0, bwq_h + (size_t)(wb*2+0)*MAT, bwq_l + (size_t)(wb*2+0)*MAT,
                 q_i, nullptr, (size_t)NI*DD, 0, NI, 0, 0);
            addg(1, bwq_h + (size_t)(wb*2+1)*MAT, bwq_l + (size_t)(wb*2+1)*MAT,
                 q_d, nullptr, (size_t)ND*DD, 0, ND, 0, 0);
            for(int r=0;r<4;r++){
                int st = st_tab[dir][r];
                addg(st, bwtk_h + (size_t)(wb*4+r)*MAT, bwtk_l + (size_t)(wb*4+r)*MAT,
                     nullptr, ka16 + (size_t)r*NI*DD, 0, (size_t)4*NI*DD, st ? ND : NI, 4, 1);
            }
            for(int r=0;r<4;r++){
                int st = st_tab[dir][r];
                addg(st, bwtv_h + (size_t)(wb*4+r)*MAT, bwtv_l + (size_t)(wb*4+r)*MAT,
                     nullptr, vm16 + (size_t)r*NI*DD, 0, (size_t)4*NI*DD, st ? ND : NI, 4, 1);
            }
            g1.nd = ndx;
            gemm_mfma<<<dim3(nb1,2,2),256,0,stream>>>(g1);

            // edge phase: both branches, this dir
            hgt_fused<<<2*(NROW/4),256,0,stream>>>(rowptr, einfo,
                q_i, q_d, ka16, vm16, hgt_prel + (size_t)wb*4*HH, bagg_h, bagg_l, dir);
        }

        // Wo GEMM: K=512 concat, gate-folded; branch via blockIdx.z
        GArgs g3; g3.nd = 2;
        for(int t=0;t<2;t++){
            GDesc& d = g3.d[t];
            size_t ao = t ? (size_t)NI*DD : 0;
            d.Ah = bagg_h + (t ? (size_t)NI*512 : 0);
            d.Al = bagg_l + (t ? (size_t)NI*512 : 0);
            d.Bh = bwoc_h + (size_t)(l*2+t)*131072;
            d.Bl = bwoc_l + (size_t)(l*2+t)*131072;
            d.C = nxtX + ao;
            d.Oh = bcur_h + ao;
            d.Ol = bcur_l + ao;
            d.X = curX + ao;
            d.skipp = hgt_skip + l*4 + t;
            d.strA = (size_t)NROW*512; d.strC = BRN; d.strO = BRN; d.strX = BRN;
            d.mblks = (t ? ND : NI)/128;
            d.mode = 6; d.prec = 0; d.kdim = 512;
        }
        gemm_mfma<<<dim3(NI/128 + ND/128,2,2),256,0,stream>>>(g3);
    }

    // ---- per-branch pooling + transformer ----
    for(int bi=0;bi<2;bi++){
        const float* cur_i = xcur + (size_t)bi*BRN;
        const float* cur_d = cur_i + (size_t)NI*DD;
        const uint32_t* rp = rowptr + (size_t)bi*(2*NROW+1);
        const uint32_t* ei = einfo + (size_t)bi*(2*EHGT);

        pool_h2<<<NROW/4,256,0,stream>>>(cur_i, cur_d, pool_W, hvec);
        pool_csr<<<NROW/4,256,0,stream>>>(rp, ei, hvec, pool_att, pscore);
        topk_rank<<<dim3(384,BB),256,0,stream>>>(pscore, pool_bias, seln, sels);
        gather_xp<<<BB*KPOOL,256,0,stream>>>(seln, sels, cur_i, cur_d, xp, bxp_h, bxp_l);

        GArgs g4; g4.nd = 3;
        for(int t=0;t<3;t++){
            GDesc& d = g4.d[t];
            d.Ah=bxp_h; d.Al=bxp_l;
            d.Bh=btw_h + (size_t)t*MAT; d.Bl=btw_l + (size_t)t*MAT;
            d.C = nullptr;
            d.Oh = (t==0)? qbh : (t==1)? kbh : vbh;
            d.Ol = nullptr;
            d.X = nullptr; d.skipp = nullptr;
            d.strA=0; d.strC=0; d.strO=0; d.strX=0;
            d.mblks = MR/128; d.mode = 4; d.prec = 0; d.kdim = 256;
        }
        gemm_mfma<<<dim3(3*(MR/128),2,1),256,0,stream>>>(g4);
        attn_mfma<<<dim3(BB*HH, KPOOL/64),256,0,stream>>>(qbh, kbh, vbh, bao_h, bao_l);
        GArgs g5; g5.nd = 1;
        {
            GDesc& d = g5.d[0];
            d.Ah=bao_h; d.Al=bao_l;
            d.Bh=btw_h + (size_t)3*MAT; d.Bl=btw_l + (size_t)3*MAT;
            d.C=o2; d.Oh=nullptr; d.Ol=nullptr; d.X=nullptr; d.skipp=nullptr;
            d.strA=0; d.strC=0; d.strO=0; d.strX=0;
            d.mblks=MR/128; d.mode=0; d.prec=0; d.kdim=256;
        }
        gemm_mfma<<<dim3(MR/128,2,1),256,0,stream>>>(g5);
        ln_kernel<<<MR,256,0,stream>>>(xp, o2, ln_g, ln_b, gatt);
        feat_reduce2<<<dim3(BB,12),256,0,stream>>>(xp, gatt, bi ? vbuf : ubuf);
    }

    cosine_kernel<<<BB,64,0,stream>>>(ubuf, vbuf, out);
}

// Round 26
// 834.490 us; speedup vs baseline: 2.3304x; 1.0652x over previous
//
#include <hip/hip_runtime.h>
#include <math.h>
#include <stdint.h>

#define LL 2
#define HH 4
#define DHH 64
#define DD 256
#define BB 8
#define NI 8192
#define ND 4096
#define NROW 12288
#define KPOOL 768
#define EC 65536
#define EI 32768
#define EO 32768
#define EK 8192
#define EHGT (EC+EI+EO+EK)
#define MR (BB*KPOOL)
#define MRD ((size_t)MR*DD)

typedef unsigned short u16;
typedef short bf16x8 __attribute__((ext_vector_type(8)));
typedef float f32x4 __attribute__((ext_vector_type(4)));
typedef unsigned short u16x4 __attribute__((ext_vector_type(4)));

__device__ inline float gelu_f(float x){ return 0.5f*x*(1.f+erff(x*0.70710678118654752f)); }
__device__ inline u16 f2b(float x){ uint32_t u=__float_as_uint(x); return (u16)((u + 0x7fffu + ((u>>16)&1u))>>16); }
__device__ inline float b2f(u16 h){ return __uint_as_float(((uint32_t)h)<<16); }

// ---------------- generic fill ----------------
__global__ void fill_u32(uint32_t* p, uint32_t v, int n){
    int i = blockIdx.x*256 + threadIdx.x;
    if(i<n) p[i]=v;
}

// ---------------- activation split-convert + packed f32 copy ----------------
__global__ void cvt_split(const float* __restrict__ A, int nA, const float* __restrict__ B, int nB,
                          u16* __restrict__ oh, u16* __restrict__ ol, float* __restrict__ xc){
    int i = (blockIdx.x*256 + threadIdx.x)*4;
    int tot = nA + nB;
    if(i >= tot) return;
    float4 v = (i < nA) ? *(const float4*)(A + i) : *(const float4*)(B + (i - nA));
    float vv[4] = {v.x, v.y, v.z, v.w};
    u16x4 h4, l4;
    #pragma unroll
    for(int j=0;j<4;j++){
        float x = vv[j];
        u16 h = f2b(x);
        h4[j] = h;
        l4[j] = f2b(x - b2f(h));
    }
    *(u16x4*)(oh + i) = h4;
    *(u16x4*)(ol + i) = l4;
    *(float4*)(xc + i) = v;
}

// ---------------- weight transpose + split ----------------
struct WCArgs { const float* in[8]; u16* oh[8]; u16* ol[8]; int cnt[8]; int nr; };
__global__ void wcvt_split(WCArgs a){
    int mat = blockIdx.y, ri = 0;
    while(ri < a.nr-1 && mat >= a.cnt[ri]){ mat -= a.cnt[ri]; ri++; }
    const float* in = a.in[ri] + (size_t)mat*65536;
    u16* oh = a.oh[ri] + (size_t)mat*65536;
    u16* ol = a.ol[ri] + (size_t)mat*65536;
    int n = blockIdx.x, k = threadIdx.x;
    float x = in[(size_t)k*DD + n];
    u16 h = f2b(x);
    oh[n*DD + k] = h;
    ol[n*DD + k] = f2b(x - b2f(h));
}

// ---------------- Wo weights: gate-folded, K-concatenated transpose+split ----------------
__global__ void wcvt_wo(const float* __restrict__ Wo, const float* __restrict__ skip,
                        u16* __restrict__ oh, u16* __restrict__ ol){
    int combo = blockIdx.y;          // l*2 + t
    int l = combo >> 1, t = combo & 1;
    int n = blockIdx.x, k = threadIdx.x;
    #pragma unroll
    for(int dir=0;dir<2;dir++){
        int wi = (l*2+dir)*2 + t;
        float gg = 1.f/(1.f+expf(-skip[wi]));
        float x = 0.5f*gg*Wo[(size_t)wi*65536 + (size_t)k*DD + n];
        size_t o = (size_t)combo*131072 + (size_t)n*512 + dir*256 + k;
        u16 hh = f2b(x);
        oh[o] = hh;
        ol[o] = f2b(x - b2f(hh));
    }
}

// ---------------- MFMA batched GEMM with fused epilogues; branch via blockIdx.z ----------------
// prec=0: split hi/lo (3 MFMA/step); prec=1: hi-only
// mode 0: C=f32   mode 4: Oh=plain bf16
// mode 6: v=relu(acc + cx*X); C=v; Oh/Ol=split(v)
struct GDesc { const u16* Ah; const u16* Al; const u16* Bh; const u16* Bl;
               float* C; u16* Oh; u16* Ol;
               const float* X; const float* skipp;
               size_t strA; size_t strC; size_t strO; size_t strX;
               int mblks; int mode; int prec; int kdim; };
struct GArgs { GDesc d[20]; int nd; };

__global__ __launch_bounds__(256) void gemm_mfma(GArgs ga){
    __shared__ u16 SBUF[2*128*64];
    char* Abuf = (char*)SBUF;
    char* Bbuf = (char*)(SBUF + 128*64);
    int mb = blockIdx.x, di = 0;
    while(di < ga.nd-1 && mb >= ga.d[di].mblks){ mb -= ga.d[di].mblks; di++; }
    GDesc g = ga.d[di];
    const size_t br = blockIdx.z;
    const u16* gAh = g.Ah + br*g.strA;
    const u16* gAl = g.Al + br*g.strA;
    const int prec = g.prec;
    const int KD = g.kdim;
    const int m0 = mb*128, n0 = blockIdx.y*128;
    const int tid = threadIdx.x;
    const int lane = tid & 63, wid = tid >> 6;
    const int wm = (wid>>1)*64, wn = (wid&1)*64;
    const int l15 = lane & 15, l4 = lane >> 4;
    const int srow = tid >> 1, hf = tid & 1;
    const int ssw = (srow&7)<<4;
    const int c0 = (hf*32) ^ ssw;
    const int c1 = (hf*32+16) ^ ssw;
    const int c2 = (64+hf*32) ^ ssw;
    const int c3 = (64+hf*32+16) ^ ssw;
    const int rbyte = srow*128;
    const u16* __restrict__ Aph = gAh + (size_t)(m0 + srow)*KD + hf*16;
    const u16* __restrict__ Apl = gAl + (size_t)(m0 + srow)*KD + hf*16;
    const u16* __restrict__ Bph = g.Bh + (size_t)(n0 + srow)*KD + hf*16;
    const u16* __restrict__ Bpl = g.Bl + (size_t)(n0 + srow)*KD + hf*16;
    f32x4 acc[4][4] = {};
    bf16x8 r0, r1, r2, r3, r4, r5, r6, r7;
    r0 = *(const bf16x8*)(Aph);
    r1 = *(const bf16x8*)(Aph + 8);
    r4 = *(const bf16x8*)(Bph);
    r5 = *(const bf16x8*)(Bph + 8);
    if(!prec){
        r2 = *(const bf16x8*)(Apl);
        r3 = *(const bf16x8*)(Apl + 8);
        r6 = *(const bf16x8*)(Bpl);
        r7 = *(const bf16x8*)(Bpl + 8);
    }
    for(int k0=0;k0<KD;k0+=32){
        __syncthreads();
        *(bf16x8*)(Abuf + rbyte + c0) = r0; *(bf16x8*)(Abuf + rbyte + c1) = r1;
        *(bf16x8*)(Bbuf + rbyte + c0) = r4; *(bf16x8*)(Bbuf + rbyte + c1) = r5;
        if(!prec){
            *(bf16x8*)(Abuf + rbyte + c2) = r2; *(bf16x8*)(Abuf + rbyte + c3) = r3;
            *(bf16x8*)(Bbuf + rbyte + c2) = r6; *(bf16x8*)(Bbuf + rbyte + c3) = r7;
        }
        __syncthreads();
        if(k0 + 32 < KD){
            int kn = k0 + 32;
            r0 = *(const bf16x8*)(Aph + kn);     r1 = *(const bf16x8*)(Aph + kn + 8);
            r4 = *(const bf16x8*)(Bph + kn);     r5 = *(const bf16x8*)(Bph + kn + 8);
            if(!prec){
                r2 = *(const bf16x8*)(Apl + kn); r3 = *(const bf16x8*)(Apl + kn + 8);
                r6 = *(const bf16x8*)(Bpl + kn); r7 = *(const bf16x8*)(Bpl + kn + 8);
            }
        }
        bf16x8 afh[4], bfh[4];
        #pragma unroll
        for(int i=0;i<4;i++){
            int ar = wm + i*16 + l15;
            int abase = ar*128;
            afh[i] = *(const bf16x8*)(Abuf + abase + ((l4*16) ^ ((ar&7)<<4)));
            int br_ = wn + i*16 + l15;
            int bbase = br_*128;
            bfh[i] = *(const bf16x8*)(Bbuf + bbase + ((l4*16) ^ ((br_&7)<<4)));
        }
        #pragma unroll
        for(int i=0;i<4;i++)
            #pragma unroll
            for(int j=0;j<4;j++)
                acc[i][j] = __builtin_amdgcn_mfma_f32_16x16x32_bf16(afh[i], bfh[j], acc[i][j], 0,0,0);
        if(!prec){
            bf16x8 afl[4], bfl[4];
            #pragma unroll
            for(int i=0;i<4;i++){
                int ar = wm + i*16 + l15;
                int abase = ar*128;
                afl[i] = *(const bf16x8*)(Abuf + abase + ((64 + l4*16) ^ ((ar&7)<<4)));
                int br_ = wn + i*16 + l15;
                int bbase = br_*128;
                bfl[i] = *(const bf16x8*)(Bbuf + bbase + ((64 + l4*16) ^ ((br_&7)<<4)));
            }
            #pragma unroll
            for(int i=0;i<4;i++)
                #pragma unroll
                for(int j=0;j<4;j++){
                    acc[i][j] = __builtin_amdgcn_mfma_f32_16x16x32_bf16(afh[i], bfl[j], acc[i][j], 0,0,0);
                    acc[i][j] = __builtin_amdgcn_mfma_f32_16x16x32_bf16(afl[i], bfh[j], acc[i][j], 0,0,0);
                }
        }
    }
    // ---- coalesced epilogue via LDS restage ----
    const int mode = g.mode;
    float* Cb = g.C + br*g.strC;
    u16* Ohb = g.Oh + br*g.strO;
    u16* Olb = g.Ol + br*g.strO;
    const float* Xb = g.X + br*g.strX;
    float cx = 0.f;
    if(mode == 6){
        float g0 = 1.f/(1.f + expf(-g.skipp[0]));
        float g1 = 1.f/(1.f + expf(-g.skipp[2]));
        cx = 1.f - 0.5f*(g0 + g1);
    }
    float* LDSf = (float*)SBUF;
    const int lrow = tid >> 5;
    const int cc4 = (tid & 31)*4;
    #pragma unroll
    for(int half=0; half<2; half++){
        __syncthreads();
        if((wid>>1) == half){
            #pragma unroll
            for(int i=0;i<4;i++)
                #pragma unroll
                for(int j=0;j<4;j++)
                    #pragma unroll
                    for(int r=0;r<4;r++)
                        LDSf[(i*16 + l4*4 + r)*128 + wn + j*16 + l15] = acc[i][j][r];
        }
        __syncthreads();
        #pragma unroll
        for(int k=0;k<8;k++){
            int row = lrow + k*8;
            size_t o = (size_t)(m0 + half*64 + row)*DD + n0 + cc4;
            float4 v = *(const float4*)&LDSf[row*128 + cc4];
            float vv[4] = {v.x, v.y, v.z, v.w};
            if(mode==0){
                *(float4*)(Cb + o) = v;
            } else if(mode==4){
                u16x4 h4;
                #pragma unroll
                for(int j=0;j<4;j++) h4[j] = f2b(vv[j]);
                *(u16x4*)(Ohb + o) = h4;
            } else {   // mode 6
                float4 x = *(const float4*)(Xb + o);
                float xx[4] = {x.x, x.y, x.z, x.w};
                float4 cv;
                float* cvv = (float*)&cv;
                u16x4 h4, lo4;
                #pragma unroll
                for(int j=0;j<4;j++){
                    float v3 = vv[j] + cx*xx[j];
                    v3 = v3 > 0.f ? v3 : 0.f;
                    cvv[j] = v3;
                    u16 hh = f2b(v3); h4[j]=hh; lo4[j]=f2b(v3-b2f(hh));
                }
                *(float4*)(Cb + o) = cv;
                *(u16x4*)(Ohb + o) = h4;
                *(u16x4*)(Olb + o) = lo4;
            }
        }
    }
}

// ---------- combine ----------
__global__ void combine_all(const float* __restrict__ Wk, const float* __restrict__ Wv,
                            const float* __restrict__ Ra, const float* __restrict__ Rm,
                            float* __restrict__ wtk, float* __restrict__ wtv){
    const int st_tab[2][4] = {{0,1,0,0},{0,0,1,0}};
    int combo = blockIdx.y;
    int idx = combo >> 1, kv = combo & 1;
    int r = idx & 3, wb = idx >> 2, dir = wb & 1;
    int st = st_tab[dir][r];
    const float* W = (kv ? Wv : Wk) + (size_t)(wb*2 + st)*65536;
    const float* R = (kv ? Rm : Ra) + (size_t)idx*16384;
    float* o = (kv ? wtv : wtk) + (size_t)idx*65536;
    int d = blockIdx.x, c = threadIdx.x;
    int h = c >> 6, f = c & 63;
    const float* Wrow = W + d*DD + h*64;
    const float* Rh = R + h*4096 + f;
    float s = 0.f;
    #pragma unroll 8
    for(int k=0;k<64;k++) s += Wrow[k]*Rh[k*64];
    o[d*DD + c] = s;
}

// ---------------- CSR build ----------------
__device__ inline void edge_decode(int e, int& r, int& el){
    if(e < EC){ r=0; el=e; }
    else if(e < EC+EI){ r=1; el=e-EC; }
    else if(e < EC+EI+EO){ r=2; el=e-(EC+EI); }
    else { r=3; el=e-(EC+EI+EO); }
}

struct CB2 {
    const int* row[8]; const int* col[8];
    int dt[8]; int st[8];
    uint32_t* cnt; uint32_t* rowptr; uint32_t* einfo;
};

__global__ void csr_hist2(CB2 a){
    int ge = blockIdx.x*256 + threadIdx.x;
    if(ge >= 2*EHGT) return;
    int dir = ge >= EHGT;
    int e = ge - dir*EHGT;
    int r, el; edge_decode(e, r, el);
    int idx = dir*4 + r;
    int c = a.col[idx][el];
    int dst = dir*NROW + (a.dt[idx] ? (NI + c) : c);
    atomicAdd(&a.cnt[dst], 1u);
}

__global__ __launch_bounds__(1024) void scan_rowptr2(uint32_t* cnt, uint32_t* rowptr){
    __shared__ uint32_t part[1024];
    int t = threadIdx.x;
    int base = t*24;
    uint32_t lpre[24];
    uint32_t sum = 0;
    #pragma unroll
    for(int i=0;i<24;i++){
        uint32_t c = cnt[base+i];
        lpre[i] = sum; sum += c;
        cnt[base+i] = 0;
    }
    part[t] = sum;
    __syncthreads();
    for(int offs=1; offs<1024; offs<<=1){
        uint32_t v = (t>=offs) ? part[t-offs] : 0u;
        __syncthreads();
        part[t] += v;
        __syncthreads();
    }
    uint32_t pre = (t==0) ? 0u : part[t-1];
    #pragma unroll
    for(int i=0;i<24;i++) rowptr[base+i] = pre + lpre[i];
    if(t==1023) rowptr[2*NROW] = part[1023];
}

__global__ void csr_scatter2(CB2 a){
    int ge = blockIdx.x*256 + threadIdx.x;
    if(ge >= 2*EHGT) return;
    int dir = ge >= EHGT;
    int e = ge - dir*EHGT;
    int r, el; edge_decode(e, r, el);
    int idx = dir*4 + r;
    int c = a.col[idx][el];
    int dst = dir*NROW + (a.dt[idx] ? (NI + c) : c);
    int src = a.row[idx][el];
    uint32_t p = a.rowptr[dst] + atomicAdd(&a.cnt[dst], 1u);
    uint32_t vmidx = (uint32_t)(r*NI + src);
    uint32_t hom = a.st[idx] ? (uint32_t)(NI + src) : (uint32_t)src;
    a.einfo[p] = vmidx | (hom << 16);
}

// ---------------- fused HGT edge phase, BOTH branches (one dir): wave per dst ----------------
__global__ __launch_bounds__(256) void hgt_fused(const uint32_t* __restrict__ rowptr,
                                                 const uint32_t* __restrict__ einfo,
                                                 const float* __restrict__ q_i,
                                                 const float* __restrict__ q_d,
                                                 const u16* __restrict__ ka,
                                                 const u16* __restrict__ vm,
                                                 const float* __restrict__ prel,
                                                 u16* __restrict__ bagg_h,
                                                 u16* __restrict__ bagg_l,
                                                 int dir){
    int wv = threadIdx.x >> 6, lane = threadIdx.x & 63;
    int bx = blockIdx.x;
    int brx = 0;
    if(bx >= (NROW/4)){ brx = 1; bx -= (NROW/4); }
    int rowi = bx*4 + wv;
    const uint32_t* rp = rowptr + (size_t)brx*(2*NROW+1) + (size_t)dir*NROW;
    uint32_t p0 = rp[rowi], p1 = rp[rowi+1];
    const uint32_t* ei = einfo + (size_t)brx*(2*EHGT);
    int h = lane >> 4;
    const float* qi = q_i + (size_t)brx*NI*DD;
    const float* qd = q_d + (size_t)brx*ND*DD;
    const u16* kad = ka + (size_t)brx*4*NI*DD;
    const u16* vmd = vm + (size_t)brx*4*NI*DD;
    const float* qrow = (rowi < NI) ? (qi + (size_t)rowi*DD) : (qd + (size_t)(rowi-NI)*DD);
    float4 q4 = *(const float4*)(qrow + lane*4);
    float pr0 = prel[0*HH+h]*0.125f, pr1 = prel[1*HH+h]*0.125f;
    float pr2 = prel[2*HH+h]*0.125f, pr3 = prel[3*HH+h]*0.125f;
    float m = -INFINITY, den = 0.f;
    float4 o4 = {0.f,0.f,0.f,0.f};
    for(uint32_t p = p0; p < p1; p++){
        uint32_t vmidx = ei[p] & 0xffffu;
        int r = vmidx >> 13;
        uint2 kr = *(const uint2*)(kad + (size_t)vmidx*DD + lane*4);
        uint2 vr = *(const uint2*)(vmd + (size_t)vmidx*DD + lane*4);
        float k0 = __uint_as_float(kr.x << 16), k1 = __uint_as_float(kr.x & 0xffff0000u);
        float k2 = __uint_as_float(kr.y << 16), k3 = __uint_as_float(kr.y & 0xffff0000u);
        float v0 = __uint_as_float(vr.x << 16), v1 = __uint_as_float(vr.x & 0xffff0000u);
        float v2 = __uint_as_float(vr.y << 16), v3 = __uint_as_float(vr.y & 0xffff0000u);
        float d = q4.x*k0 + q4.y*k1 + q4.z*k2 + q4.w*k3;
        d += __shfl_xor(d, 1); d += __shfl_xor(d, 2);
        d += __shfl_xor(d, 4); d += __shfl_xor(d, 8);
        float pf = (r==0) ? pr0 : (r==1) ? pr1 : (r==2) ? pr2 : pr3;
        float s = d * pf;
        float nm = fmaxf(m, s);
        float sc_ = expf(m - nm);
        float pe = expf(s - nm);
        den = den*sc_ + pe;
        o4.x = o4.x*sc_ + pe*v0;
        o4.y = o4.y*sc_ + pe*v1;
        o4.z = o4.z*sc_ + pe*v2;
        o4.w = o4.w*sc_ + pe*v3;
        m = nm;
    }
    float inv = 1.f/(den + 1e-16f);
    float vals[4] = {o4.x*inv, o4.y*inv, o4.z*inv, o4.w*inv};
    u16x4 h4, l4;
    #pragma unroll
    for(int j=0;j<4;j++){
        float g = gelu_f(vals[j]);
        u16 hh = f2b(g);
        h4[j] = hh;
        l4[j] = f2b(g - b2f(hh));
    }
    size_t ob = (size_t)brx*NROW*512 + (size_t)rowi*512 + dir*256 + lane*4;
    *(u16x4*)(bagg_h + ob) = h4;
    *(u16x4*)(bagg_l + ob) = l4;
}

// ---------------- pooling (branch via blockIdx.y) ----------------
__global__ void pool_h2(const float* __restrict__ x, const float* __restrict__ w, float* __restrict__ h){
    int brx = blockIdx.y;
    int node = blockIdx.x*4 + (threadIdx.x>>6);
    int lane = threadIdx.x & 63;
    const float* xr = x + (size_t)brx*((size_t)NROW*DD) + (size_t)node*DD;
    float s = 0.f;
    for(int j=lane;j<DD;j+=64) s += xr[j]*w[j];
    for(int m=32;m;m>>=1) s += __shfl_xor(s, m);
    if(lane==0) h[brx*NROW + node] = s;
}

__global__ __launch_bounds__(256) void pool_csr(const uint32_t* __restrict__ rowptr,
                                                const uint32_t* __restrict__ einfo,
                                                const float* __restrict__ h,
                                                const float* __restrict__ att,
                                                float* __restrict__ score){
    int brx = blockIdx.y;
    int w = blockIdx.x*4 + (threadIdx.x >> 6);
    int lane = threadIdx.x & 63;
    if(w >= NROW) return;
    const uint32_t* rp = rowptr + (size_t)brx*(2*NROW+1);
    const uint32_t* ei = einfo + (size_t)brx*(2*EHGT);
    const float* hb = h + (size_t)brx*NROW;
    uint32_t p0 = rp[w], p1 = rp[w+1];
    float a0 = att[0], a1 = att[1];
    float hn = hb[w];
    float es = a0*hn + a1*hn;
    es = es >= 0.f ? es : 0.2f*es;
    float m = -INFINITY;
    for(uint32_t p = p0+lane; p < p1; p += 64){
        float hs = hb[ei[p] >> 16];
        float e = a0*hs + a1*hn;
        e = e >= 0.f ? e : 0.2f*e;
        m = fmaxf(m, e);
    }
    #pragma unroll
    for(int s=32;s;s>>=1) m = fmaxf(m, __shfl_xor(m, s));
    m = fmaxf(m, es);
    float lden = 0.f, lnum = 0.f;
    for(uint32_t p = p0+lane; p < p1; p += 64){
        float hs = hb[ei[p] >> 16];
        float e = a0*hs + a1*hn;
        e = e >= 0.f ? e : 0.2f*e;
        float a = expf(e - m);
        lden += a; lnum += a*hs;
    }
    #pragma unroll
    for(int s=32;s;s>>=1){ lden += __shfl_xor(lden, s); lnum += __shfl_xor(lnum, s); }
    float aself = expf(es - m);
    lden += aself; lnum += aself*hn;
    if(lane==0) score[brx*NROW + w] = lnum/(lden + 1e-16f);
}

// ---------------- top-768 of 1536 per graph: wave-per-candidate rank (branch via z) ----------------
__global__ __launch_bounds__(256) void topk_rank(const float* __restrict__ score,
                                                 const float* __restrict__ bias,
                                                 int* __restrict__ sel_node,
                                                 float* __restrict__ sel_scale){
    int brx = blockIdx.z;
    int b = blockIdx.y;
    int wid = threadIdx.x >> 6, lane = threadIdx.x & 63;
    int i = blockIdx.x*4 + wid;
    const float* sc = score + (size_t)brx*NROW;
    int nodei = (i<1024) ? (b*1024 + i) : (NI + b*512 + (i-1024));
    float ki = sc[nodei];
    int r = 0;
    #pragma unroll
    for(int s=0;s<24;s++){
        int j = s*64 + lane;
        int nodej = (j<1024) ? (b*1024 + j) : (NI + b*512 + (j-1024));
        float kj = sc[nodej];
        r += (kj > ki) || (kj == ki && j < i);
    }
    #pragma unroll
    for(int m=32;m;m>>=1) r += __shfl_xor(r, m);
    if(lane==0 && r < KPOOL){
        sel_node[(size_t)brx*MR + b*KPOOL + r] = nodei;
        sel_scale[(size_t)brx*MR + b*KPOOL + r] = tanhf(ki + bias[0]);
    }
}

__global__ void gather_xp(const int* __restrict__ sel, const float* __restrict__ scale,
                          const float* __restrict__ x,
                          float* __restrict__ xp, u16* __restrict__ bh, u16* __restrict__ bl){
    int brx = blockIdx.y;
    int i = blockIdx.x*256 + threadIdx.x;
    int rowp = i >> 8, c = i & 255;
    int node = sel[(size_t)brx*MR + rowp];
    float s = scale[(size_t)brx*MR + rowp];
    float v = x[(size_t)brx*((size_t)NROW*DD) + (size_t)node*DD + c];
    float xv = v*s;
    size_t o = (size_t)brx*MRD + i;
    xp[o] = xv;
    u16 hh = f2b(xv);
    bh[o] = hh;
    bl[o] = f2b(xv - b2f(hh));
}

// ---------------- MFMA flash attention (branch via blockIdx.z) ----------------
__global__ __launch_bounds__(256) void attn_mfma(const u16* __restrict__ Qh0,
                                                 const u16* __restrict__ Kh0,
                                                 const u16* __restrict__ Vh0,
                                                 u16* __restrict__ aoh0, u16* __restrict__ aol0){
    __shared__ u16 KhS[64*64], VtS[64*64];
    char* KhB = (char*)KhS; char* VtB = (char*)VtS;
    size_t brof = (size_t)blockIdx.z*MRD;
    const u16* Qh = Qh0 + brof;
    const u16* Kh = Kh0 + brof;
    const u16* Vh = Vh0 + brof;
    u16* aoh = aoh0 + brof;
    u16* aol = aol0 + brof;
    int bh = blockIdx.x;
    int b = bh >> 2, h = bh & 3;
    int q0 = blockIdx.y * 64;
    int tid = threadIdx.x;
    int lane = tid & 63;
    int w = tid >> 6;
    int l15 = lane & 15, l4 = lane >> 4;
    size_t qrow = (size_t)(b*KPOOL + q0 + w*16 + l15);
    bf16x8 qh[2];
    #pragma unroll
    for(int c=0;c<2;c++)
        qh[c] = *(const bf16x8*)(Qh + qrow*DD + h*64 + c*32 + l4*8);
    float mreg = -INFINITY, lreg = 0.f;
    f32x4 O[4] = {};
    for(int k0=0;k0<KPOOL;k0+=64){
        __syncthreads();
        {
            int row = tid >> 2, q4 = tid & 3;
            size_t gbase = ((size_t)(b*KPOOL + k0 + row))*DD + h*64 + q4*16;
            bf16x8 k0v = *(const bf16x8*)(Kh + gbase);
            bf16x8 k1v = *(const bf16x8*)(Kh + gbase + 8);
            int sw = (row&7)<<4;
            int colb = q4*32;
            *(bf16x8*)(KhB + row*128 + (colb ^ sw))      = k0v;
            *(bf16x8*)(KhB + row*128 + ((colb+16) ^ sw)) = k1v;
            int row0 = (tid >> 3)*2, dhg = (tid & 7)*8;
            size_t vbase = ((size_t)(b*KPOOL + k0 + row0))*DD + h*64 + dhg;
            bf16x8 va = *(const bf16x8*)(Vh + vbase);
            bf16x8 vb = *(const bf16x8*)(Vh + vbase + DD);
            #pragma unroll
            for(int j=0;j<8;j++){
                int dh = dhg + j;
                uint32_t pk = (uint32_t)(u16)(short)va[j] | ((uint32_t)(u16)(short)vb[j] << 16);
                *(uint32_t*)(VtB + dh*128 + ((row0*2) ^ ((dh&7)<<4))) = pk;
            }
        }
        __syncthreads();
        f32x4 s[4] = {};
        #pragma unroll
        for(int t=0;t<4;t++){
            int arow = t*16 + l15;
            int sw = (arow&7)<<4;
            const char* bh_ = KhB + arow*128;
            bf16x8 kh0 = *(const bf16x8*)(bh_ + ((l4*16) ^ sw));
            bf16x8 kh1 = *(const bf16x8*)(bh_ + ((l4*16 + 64) ^ sw));
            s[t] = __builtin_amdgcn_mfma_f32_16x16x32_bf16(kh0, qh[0], s[t], 0,0,0);
            s[t] = __builtin_amdgcn_mfma_f32_16x16x32_bf16(kh1, qh[1], s[t], 0,0,0);
        }
        float cm = -INFINITY;
        #pragma unroll
        for(int t=0;t<4;t++)
            #pragma unroll
            for(int r=0;r<4;r++){ s[t][r] *= 0.125f; cm = fmaxf(cm, s[t][r]); }
        cm = fmaxf(cm, __shfl_xor(cm,16));
        cm = fmaxf(cm, __shfl_xor(cm,32));
        float nm = fmaxf(mreg, cm);
        float es = expf(mreg - nm);
        float ps = 0.f;
        #pragma unroll
        for(int t=0;t<4;t++)
            #pragma unroll
            for(int r=0;r<4;r++){ float pv = expf(s[t][r] - nm); s[t][r] = pv; ps += pv; }
        ps += __shfl_xor(ps,16);
        ps += __shfl_xor(ps,32);
        lreg = lreg*es + ps;
        mreg = nm;
        #pragma unroll
        for(int d=0;d<4;d++){ O[d][0]*=es; O[d][1]*=es; O[d][2]*=es; O[d][3]*=es; }
        #pragma unroll
        for(int c32=0;c32<2;c32++){
            bf16x8 pb;
            #pragma unroll
            for(int j=0;j<8;j++){
                int srcl = ((((lane>>4)*2 + (j>>2)) & 3) << 4) | l15;
                float v0 = __shfl(s[c32*2+0][j&3], srcl, 64);
                float v1 = __shfl(s[c32*2+1][j&3], srcl, 64);
                float v = (lane < 32) ? v0 : v1;
                pb[j] = (short)f2b(v);
            }
            #pragma unroll
            for(int dhb=0; dhb<4; dhb++){
                int vrow = dhb*16 + l15;
                bf16x8 va = *(const bf16x8*)(VtB + vrow*128 + ((c32*64 + l4*16) ^ ((vrow&7)<<4)));
                O[dhb] = __builtin_amdgcn_mfma_f32_16x16x32_bf16(va, pb, O[dhb], 0,0,0);
            }
        }
    }
    float inv = 1.f/lreg;
    #pragma unroll
    for(int dhb=0;dhb<4;dhb++)
        #pragma unroll
        for(int r=0;r<4;r++){
            float val = O[dhb][r]*inv;
            size_t o = qrow*DD + h*64 + dhb*16 + l4*4 + r;
            u16 hh = f2b(val);
            aoh[o] = hh;
            aol[o] = f2b(val - b2f(hh));
        }
}

// layernorm row kernel (branch via blockIdx.y)
__global__ __launch_bounds__(256) void ln_kernel(const float* __restrict__ xp, const float* __restrict__ o2,
                                                 const float* __restrict__ lg, const float* __restrict__ lb,
                                                 float* __restrict__ gatt){
    __shared__ float red[256];
    size_t brof = (size_t)blockIdx.y*MRD;
    int r = blockIdx.x, c = threadIdx.x;
    float y = xp[brof + (size_t)r*DD + c] + o2[brof + (size_t)r*DD + c];
    red[c] = y; __syncthreads();
    for(int s=128;s;s>>=1){ if(c<s) red[c] += red[c+s]; __syncthreads(); }
    float mu = red[0]*(1.f/DD);
    __syncthreads();
    float d = y - mu;
    red[c] = d*d; __syncthreads();
    for(int s=128;s;s>>=1){ if(c<s) red[c] += red[c+s]; __syncthreads(); }
    float var = red[0]*(1.f/DD);
    gatt[brof + (size_t)r*DD + c] = lg[c]*d/sqrtf(var+1e-5f) + lb[c];
}

__global__ void feat_reduce2(const float* __restrict__ xp, const float* __restrict__ gatt,
                             float* __restrict__ uv){
    int brx = blockIdx.z;
    int b = blockIdx.x, c = threadIdx.x;
    int j0 = blockIdx.y*64;
    size_t brof = (size_t)brx*MRD;
    float s1=0.f, s2=0.f;
    for(int j=j0;j<j0+64;j++){
        size_t basep = brof + ((size_t)(b*KPOOL + j))*DD + c;
        s1 += xp[basep];
        s2 += gatt[basep];
    }
    float* out = uv + (size_t)brx*BB*512;
    atomicAdd(&out[b*512 + c], s1);
    atomicAdd(&out[b*512 + 256 + c], s2);
}

__global__ void cosine_kernel(const float* __restrict__ u, const float* __restrict__ v,
                              float* __restrict__ out){
    int b = blockIdx.x, t = threadIdx.x;
    float du=0.f, nu=0.f, nv=0.f;
    for(int j=t;j<512;j+=64){
        float a = u[b*512+j], bb = v[b*512+j];
        du += a*bb; nu += a*a; nv += bb*bb;
    }
    for(int m=32;m;m>>=1){
        du += __shfl_xor(du,m); nu += __shfl_xor(nu,m); nv += __shfl_xor(nv,m);
    }
    if(t==0) out[b] = du / (fmaxf(sqrtf(nu),1e-8f)*fmaxf(sqrtf(nv),1e-8f));
}

// =======================================================================
extern "C" void kernel_launch(void* const* d_in, const int* in_sizes, int n_in,
                              void* d_out, int out_size, void* d_ws, size_t ws_size,
                              hipStream_t stream){
    (void)in_sizes; (void)n_in; (void)out_size; (void)ws_size;
    const float* hgt_Wk   = (const float*)d_in[12];
    const float* hgt_Wq   = (const float*)d_in[13];
    const float* hgt_Wv   = (const float*)d_in[14];
    const float* hgt_Wo   = (const float*)d_in[15];
    const float* hgt_arel = (const float*)d_in[16];
    const float* hgt_mrel = (const float*)d_in[17];
    const float* hgt_prel = (const float*)d_in[18];
    const float* hgt_skip = (const float*)d_in[19];
    const float* pool_W   = (const float*)d_in[20];
    const float* pool_att = (const float*)d_in[21];
    const float* pool_bias= (const float*)d_in[22];
    const float* t_wq     = (const float*)d_in[23];
    const float* t_wk     = (const float*)d_in[24];
    const float* t_wv     = (const float*)d_in[25];
    const float* t_wo     = (const float*)d_in[26];
    const float* ln_g     = (const float*)d_in[27];
    const float* ln_b     = (const float*)d_in[28];
    float* out = (float*)d_out;

    char* base = (char*)d_ws;
    size_t off = 0;
    auto allocb = [&](size_t nbytes)->void*{
        void* p = (void*)(base + off);
        off += ((nbytes + 255) & ~(size_t)255);
        return p;
    };
    const size_t MAT = 65536;
    const size_t BRN = (size_t)NROW*DD;       // per-branch node-feature elements
    // ---- persistent ----
    u16* bwtk_h = (u16*)allocb(16*MAT*2); u16* bwtk_l = (u16*)allocb(16*MAT*2);
    u16* bwtv_h = (u16*)allocb(16*MAT*2); u16* bwtv_l = (u16*)allocb(16*MAT*2);
    u16* bwq_h  = (u16*)allocb(8*MAT*2);  u16* bwq_l  = (u16*)allocb(8*MAT*2);
    u16* bwoc_h = (u16*)allocb(4*131072*2); u16* bwoc_l = (u16*)allocb(4*131072*2);
    u16* btw_h  = (u16*)allocb(4*MAT*2);  u16* btw_l  = (u16*)allocb(4*MAT*2);
    float* uv   = (float*)allocb((size_t)2*BB*512*4);
    float* ubuf = uv;
    float* vbuf = uv + BB*512;
    float* xa   = (float*)allocb(2*BRN*4);     // [br][NROW][DD]
    float* xcur = (float*)allocb(2*BRN*4);     // [br][NROW][DD]
    // ---- CSR (both branches) ----
    uint32_t* ccnt   = (uint32_t*)allocb((size_t)2*NROW*4);
    uint32_t* rowptr = (uint32_t*)allocb((size_t)2*(2*NROW+1)*4);
    uint32_t* einfo  = (uint32_t*)allocb((size_t)2*2*EHGT*4);
    size_t region = off;
    // ---- conv scratch ([br]...) ----
    float* q_i  = (float*)allocb((size_t)2*NI*DD*4);
    float* q_d  = (float*)allocb((size_t)2*ND*DD*4);
    u16* ka16 = (u16*)allocb((size_t)8*NI*DD*2);   // [br][r][NI][DD]; also combine f32 temp
    u16* vm16 = (u16*)allocb((size_t)8*NI*DD*2);
    u16* bcur_h = (u16*)allocb(2*BRN*2);
    u16* bcur_l = (u16*)allocb(2*BRN*2);
    u16* bagg_h = (u16*)allocb((size_t)2*NROW*512*2);
    u16* bagg_l = (u16*)allocb((size_t)2*NROW*512*2);
    // ---- pooling/transformer overlay ([br] everywhere) ----
    off = region;
    float* hvec = (float*)allocb((size_t)2*NROW*4);
    float* pscore = (float*)allocb((size_t)2*NROW*4);
    int* seln   = (int*)allocb((size_t)2*MR*4);
    float* sels = (float*)allocb((size_t)2*MR*4);
    float* xp   = (float*)allocb((size_t)2*MRD*4);
    float* o2   = (float*)allocb((size_t)2*MRD*4);
    float* gatt = (float*)allocb((size_t)2*MRD*4);
    u16* bxp_h = (u16*)allocb((size_t)2*MRD*2);
    u16* bxp_l = (u16*)allocb((size_t)2*MRD*2);
    u16* qbh = (u16*)allocb((size_t)2*MRD*2);
    u16* kbh = (u16*)allocb((size_t)2*MRD*2);
    u16* vbh = (u16*)allocb((size_t)2*MRD*2);
    u16* bao_h = (u16*)allocb((size_t)2*MRD*2);
    u16* bao_l = (u16*)allocb((size_t)2*MRD*2);

    const int st_tab[2][4] = {{0,1,0,0},{0,0,1,0}};
    const int dt_tab[2][4] = {{0,0,1,0},{0,1,0,0}};

    fill_u32<<<(2*BB*512+255)/256,256,0,stream>>>((uint32_t*)uv, 0u, 2*BB*512);
    float* wtkF = (float*)ka16;
    float* wtvF = (float*)ka16 + 16*MAT;
    combine_all<<<dim3(256,32),256,0,stream>>>(hgt_Wk, hgt_Wv, hgt_arel, hgt_mrel, wtkF, wtvF);
    WCArgs wc;
    wc.in[0]=wtkF;   wc.oh[0]=bwtk_h; wc.ol[0]=bwtk_l; wc.cnt[0]=16;
    wc.in[1]=wtvF;   wc.oh[1]=bwtv_h; wc.ol[1]=bwtv_l; wc.cnt[1]=16;
    wc.in[2]=hgt_Wq; wc.oh[2]=bwq_h;  wc.ol[2]=bwq_l;  wc.cnt[2]=8;
    wc.in[3]=t_wq;   wc.oh[3]=btw_h;          wc.ol[3]=btw_l;          wc.cnt[3]=1;
    wc.in[4]=t_wk;   wc.oh[4]=btw_h+1*MAT;    wc.ol[4]=btw_l+1*MAT;    wc.cnt[4]=1;
    wc.in[5]=t_wv;   wc.oh[5]=btw_h+2*MAT;    wc.ol[5]=btw_l+2*MAT;    wc.cnt[5]=1;
    wc.in[6]=t_wo;   wc.oh[6]=btw_h+3*MAT;    wc.ol[6]=btw_l+3*MAT;    wc.cnt[6]=1;
    wc.nr = 7;
    wcvt_split<<<dim3(256,44),256,0,stream>>>(wc);
    wcvt_wo<<<dim3(256,4),256,0,stream>>>(hgt_Wo, hgt_skip, bwoc_h, bwoc_l);

    // ---- per-branch CSR build + activation convert ----
    for(int bi=0;bi<2;bi++){
        int ib = bi*6;
        const float* x_inst = (const float*)d_in[ib+0];
        const float* x_data = (const float*)d_in[ib+1];
        const int* ecp = (const int*)d_in[ib+2];
        const int* eip = (const int*)d_in[ib+3];
        const int* eop = (const int*)d_in[ib+4];
        const int* ekp = (const int*)d_in[ib+5];
        const int* rows_f[4] = {ecp, eip, eop, ekp};
        const int* cols_f[4] = {ecp+EC, eip+EI, eop+EO, ekp+EK};
        CB2 cb;
        for(int r=0;r<4;r++){
            cb.row[r]   = rows_f[r]; cb.col[r]   = cols_f[r]; cb.dt[r]   = dt_tab[0][r]; cb.st[r]   = st_tab[0][r];
            cb.row[4+r] = cols_f[r]; cb.col[4+r] = rows_f[r]; cb.dt[4+r] = dt_tab[1][r]; cb.st[4+r] = st_tab[1][r];
        }
        cb.cnt = ccnt;
        cb.rowptr = rowptr + (size_t)bi*(2*NROW+1);
        cb.einfo = einfo + (size_t)bi*(2*EHGT);
        fill_u32<<<(2*NROW+255)/256,256,0,stream>>>(ccnt, 0u, 2*NROW);
        csr_hist2<<<(2*EHGT+255)/256,256,0,stream>>>(cb);
        scan_rowptr2<<<1,1024,0,stream>>>(ccnt, cb.rowptr);
        csr_scatter2<<<(2*EHGT+255)/256,256,0,stream>>>(cb);
        cvt_split<<<((NROW*DD/4)+255)/256,256,0,stream>>>(x_inst, NI*DD, x_data, ND*DD,
            bcur_h + bi*BRN, bcur_l + bi*BRN, xcur + bi*BRN);
    }

    // ---- branch-fused layer loop (mega per dir) ----
    for(int l=0;l<LL;l++){
        float* curX = (l==0) ? xcur : xa;
        float* nxtX = (l==0) ? xa : xcur;

        for(int dir=0;dir<2;dir++){
            int wb = l*2 + dir;
            GArgs g1; int nb1 = 0, ndx = 0;
            auto addg = [&](int srctype, const u16* Bh, const u16* Bl, float* Cm, u16* Om,
                            size_t strC, size_t strO, int M, int mode, int prec){
                GDesc& d = g1.d[ndx];
                size_t ao = srctype ? (size_t)NI*DD : 0;
                d.Ah = bcur_h + ao; d.Al = bcur_l + ao;
                d.Bh = Bh; d.Bl = Bl; d.C = Cm;
                d.Oh = Om; d.Ol = nullptr; d.X = nullptr; d.skipp = nullptr;
                d.strA = BRN; d.strC = strC; d.strO = strO; d.strX = 0;
                d.mblks = M/128; d.mode = mode; d.prec = prec; d.kdim = 256;
                nb1 += M/128; ndx++;
            };
            addg(0, bwq_h + (size_t)(wb*2+0)*MAT, bwq_l + (size_t)(wb*2+0)*MAT,
                 q_i, nullptr, (size_t)NI*DD, 0, NI, 0, 0);
            addg(1, bwq_h + (size_t)(wb*2+1)*MAT, bwq_l + (size_t)(wb*2+1)*MAT,
                 q_d, nullptr, (size_t)ND*DD, 0, ND, 0, 0);
            for(int r=0;r<4;r++){
                int st = st_tab[dir][r];
                addg(st, bwtk_h + (size_t)(wb*4+r)*MAT, bwtk_l + (size_t)(wb*4+r)*MAT,
                     nullptr, ka16 + (size_t)r*NI*DD, 0, (size_t)4*NI*DD, st ? ND : NI, 4, 1);
            }
            for(int r=0;r<4;r++){
                int st = st_tab[dir][r];
                addg(st, bwtv_h + (size_t)(wb*4+r)*MAT, bwtv_l + (size_t)(wb*4+r)*MAT,
                     nullptr, vm16 + (size_t)r*NI*DD, 0, (size_t)4*NI*DD, st ? ND : NI, 4, 1);
            }
            g1.nd = ndx;
            gemm_mfma<<<dim3(nb1,2,2),256,0,stream>>>(g1);

            hgt_fused<<<2*(NROW/4),256,0,stream>>>(rowptr, einfo,
                q_i, q_d, ka16, vm16, hgt_prel + (size_t)wb*4*HH, bagg_h, bagg_l, dir);
        }

        GArgs g3; g3.nd = 2;
        for(int t=0;t<2;t++){
            GDesc& d = g3.d[t];
            size_t ao = t ? (size_t)NI*DD : 0;
            d.Ah = bagg_h + (t ? (size_t)NI*512 : 0);
            d.Al = bagg_l + (t ? (size_t)NI*512 : 0);
            d.Bh = bwoc_h + (size_t)(l*2+t)*131072;
            d.Bl = bwoc_l + (size_t)(l*2+t)*131072;
            d.C = nxtX + ao;
            d.Oh = bcur_h + ao;
            d.Ol = bcur_l + ao;
            d.X = curX + ao;
            d.skipp = hgt_skip + l*4 + t;
            d.strA = (size_t)NROW*512; d.strC = BRN; d.strO = BRN; d.strX = BRN;
            d.mblks = (t ? ND : NI)/128;
            d.mode = 6; d.prec = 0; d.kdim = 512;
        }
        gemm_mfma<<<dim3(NI/128 + ND/128,2,2),256,0,stream>>>(g3);
    }

    // ---- branch-fused pooling + transformer tail ----
    pool_h2<<<dim3(NROW/4,2),256,0,stream>>>(xcur, pool_W, hvec);
    pool_csr<<<dim3(NROW/4,2),256,0,stream>>>(rowptr, einfo, hvec, pool_att, pscore);
    topk_rank<<<dim3(384,BB,2),256,0,stream>>>(pscore, pool_bias, seln, sels);
    gather_xp<<<dim3(MR,2),256,0,stream>>>(seln, sels, xcur, xp, bxp_h, bxp_l);

    GArgs g4; g4.nd = 3;
    for(int t=0;t<3;t++){
        GDesc& d = g4.d[t];
        d.Ah=bxp_h; d.Al=bxp_l;
        d.Bh=btw_h + (size_t)t*MAT; d.Bl=btw_l + (size_t)t*MAT;
        d.C = nullptr;
        d.Oh = (t==0)? qbh : (t==1)? kbh : vbh;
        d.Ol = nullptr;
        d.X = nullptr; d.skipp = nullptr;
        d.strA=MRD; d.strC=0; d.strO=MRD; d.strX=0;
        d.mblks = MR/128; d.mode = 4; d.prec = 0; d.kdim = 256;
    }
    gemm_mfma<<<dim3(3*(MR/128),2,2),256,0,stream>>>(g4);
    attn_mfma<<<dim3(BB*HH, KPOOL/64, 2),256,0,stream>>>(qbh, kbh, vbh, bao_h, bao_l);
    GArgs g5; g5.nd = 1;
    {
        GDesc& d = g5.d[0];
        d.Ah=bao_h; d.Al=bao_l;
        d.Bh=btw_h + (size_t)3*MAT; d.Bl=btw_l + (size_t)3*MAT;
        d.C=o2; d.Oh=nullptr; d.Ol=nullptr; d.X=nullptr; d.skipp=nullptr;
        d.strA=MRD; d.strC=MRD; d.strO=0; d.strX=0;
        d.mblks=MR/128; d.mode=0; d.prec=0; d.kdim=256;
    }
    gemm_mfma<<<dim3(MR/128,2,2),256,0,stream>>>(g5);
    ln_kernel<<<dim3(MR,2),256,0,stream>>>(xp, o2, ln_g, ln_b, gatt);
    feat_reduce2<<<dim3(BB,12,2),256,0,stream>>>(xp, gatt, uv);

    cosine_kernel<<<BB,64,0,stream>>>(ubuf, vbuf, out);
}

// Round 27
// 807.284 us; speedup vs baseline: 2.4090x; 1.0337x over previous
//
#include <hip/hip_runtime.h>
#include <math.h>
#include <stdint.h>

#define LL 2
#define HH 4
#define DHH 64
#define DD 256
#define BB 8
#define NI 8192
#define ND 4096
#define NROW 12288
#define KPOOL 768
#define EC 65536
#define EI 32768
#define EO 32768
#define EK 8192
#define EHGT (EC+EI+EO+EK)
#define MR (BB*KPOOL)
#define MRD ((size_t)MR*DD)

typedef unsigned short u16;
typedef short bf16x8 __attribute__((ext_vector_type(8)));
typedef float f32x4 __attribute__((ext_vector_type(4)));
typedef unsigned short u16x4 __attribute__((ext_vector_type(4)));

__device__ inline float gelu_f(float x){ return 0.5f*x*(1.f+erff(x*0.70710678118654752f)); }
__device__ inline u16 f2b(float x){ uint32_t u=__float_as_uint(x); return (u16)((u + 0x7fffu + ((u>>16)&1u))>>16); }
__device__ inline float b2f(u16 h){ return __uint_as_float(((uint32_t)h)<<16); }

// ---------------- generic fill ----------------
__global__ void fill_u32(uint32_t* p, uint32_t v, int n){
    int i = blockIdx.x*256 + threadIdx.x;
    if(i<n) p[i]=v;
}

// ---------------- activation split-convert + packed f32 copy, BOTH branches ----------------
__global__ void cvt_split2(const float* __restrict__ A0, const float* __restrict__ B0,
                           const float* __restrict__ A1, const float* __restrict__ B1,
                           u16* __restrict__ oh, u16* __restrict__ ol, float* __restrict__ xc){
    int brx = blockIdx.y;
    int i = (blockIdx.x*256 + threadIdx.x)*4;
    if(i >= NROW*DD) return;
    const float* A = brx ? A1 : A0;
    const float* B = brx ? B1 : B0;
    float4 v = (i < NI*DD) ? *(const float4*)(A + i) : *(const float4*)(B + (i - NI*DD));
    float vv[4] = {v.x, v.y, v.z, v.w};
    u16x4 h4, l4;
    #pragma unroll
    for(int j=0;j<4;j++){
        float x = vv[j];
        u16 h = f2b(x);
        h4[j] = h;
        l4[j] = f2b(x - b2f(h));
    }
    size_t o = (size_t)brx*((size_t)NROW*DD) + i;
    *(u16x4*)(oh + o) = h4;
    *(u16x4*)(ol + o) = l4;
    *(float4*)(xc + o) = v;
}

// ---------------- weight transpose + split ----------------
struct WCArgs { const float* in[8]; u16* oh[8]; u16* ol[8]; int cnt[8]; int nr; };
__global__ void wcvt_split(WCArgs a){
    int mat = blockIdx.y, ri = 0;
    while(ri < a.nr-1 && mat >= a.cnt[ri]){ mat -= a.cnt[ri]; ri++; }
    const float* in = a.in[ri] + (size_t)mat*65536;
    u16* oh = a.oh[ri] + (size_t)mat*65536;
    u16* ol = a.ol[ri] + (size_t)mat*65536;
    int n = blockIdx.x, k = threadIdx.x;
    float x = in[(size_t)k*DD + n];
    u16 h = f2b(x);
    oh[n*DD + k] = h;
    ol[n*DD + k] = f2b(x - b2f(h));
}

// ---------------- Wo weights: gate-folded, K-concatenated transpose+split ----------------
__global__ void wcvt_wo(const float* __restrict__ Wo, const float* __restrict__ skip,
                        u16* __restrict__ oh, u16* __restrict__ ol){
    int combo = blockIdx.y;          // l*2 + t
    int l = combo >> 1, t = combo & 1;
    int n = blockIdx.x, k = threadIdx.x;
    #pragma unroll
    for(int dir=0;dir<2;dir++){
        int wi = (l*2+dir)*2 + t;
        float gg = 1.f/(1.f+expf(-skip[wi]));
        float x = 0.5f*gg*Wo[(size_t)wi*65536 + (size_t)k*DD + n];
        size_t o = (size_t)combo*131072 + (size_t)n*512 + dir*256 + k;
        u16 hh = f2b(x);
        oh[o] = hh;
        ol[o] = f2b(x - b2f(hh));
    }
}

// ---------------- MFMA batched GEMM with fused epilogues; branch via blockIdx.z ----------------
// prec=0: split hi/lo (3 MFMA/step); prec=1: hi-only
// mode 0: C=f32   mode 4: Oh=plain bf16
// mode 6: v=relu(acc + cx*X); C=v; Oh/Ol=split(v)
struct GDesc { const u16* Ah; const u16* Al; const u16* Bh; const u16* Bl;
               float* C; u16* Oh; u16* Ol;
               const float* X; const float* skipp;
               size_t strA; size_t strC; size_t strO; size_t strX;
               int mblks; int mode; int prec; int kdim; };
struct GArgs { GDesc d[20]; int nd; };

__global__ __launch_bounds__(256) void gemm_mfma(GArgs ga){
    __shared__ u16 SBUF[2*128*64];
    char* Abuf = (char*)SBUF;
    char* Bbuf = (char*)(SBUF + 128*64);
    int mb = blockIdx.x, di = 0;
    while(di < ga.nd-1 && mb >= ga.d[di].mblks){ mb -= ga.d[di].mblks; di++; }
    GDesc g = ga.d[di];
    const size_t br = blockIdx.z;
    const u16* gAh = g.Ah + br*g.strA;
    const u16* gAl = g.Al + br*g.strA;
    const int prec = g.prec;
    const int KD = g.kdim;
    const int m0 = mb*128, n0 = blockIdx.y*128;
    const int tid = threadIdx.x;
    const int lane = tid & 63, wid = tid >> 6;
    const int wm = (wid>>1)*64, wn = (wid&1)*64;
    const int l15 = lane & 15, l4 = lane >> 4;
    const int srow = tid >> 1, hf = tid & 1;
    const int ssw = (srow&7)<<4;
    const int c0 = (hf*32) ^ ssw;
    const int c1 = (hf*32+16) ^ ssw;
    const int c2 = (64+hf*32) ^ ssw;
    const int c3 = (64+hf*32+16) ^ ssw;
    const int rbyte = srow*128;
    const u16* __restrict__ Aph = gAh + (size_t)(m0 + srow)*KD + hf*16;
    const u16* __restrict__ Apl = gAl + (size_t)(m0 + srow)*KD + hf*16;
    const u16* __restrict__ Bph = g.Bh + (size_t)(n0 + srow)*KD + hf*16;
    const u16* __restrict__ Bpl = g.Bl + (size_t)(n0 + srow)*KD + hf*16;
    f32x4 acc[4][4] = {};
    bf16x8 r0, r1, r2, r3, r4, r5, r6, r7;
    r0 = *(const bf16x8*)(Aph);
    r1 = *(const bf16x8*)(Aph + 8);
    r4 = *(const bf16x8*)(Bph);
    r5 = *(const bf16x8*)(Bph + 8);
    if(!prec){
        r2 = *(const bf16x8*)(Apl);
        r3 = *(const bf16x8*)(Apl + 8);
        r6 = *(const bf16x8*)(Bpl);
        r7 = *(const bf16x8*)(Bpl + 8);
    }
    for(int k0=0;k0<KD;k0+=32){
        __syncthreads();
        *(bf16x8*)(Abuf + rbyte + c0) = r0; *(bf16x8*)(Abuf + rbyte + c1) = r1;
        *(bf16x8*)(Bbuf + rbyte + c0) = r4; *(bf16x8*)(Bbuf + rbyte + c1) = r5;
        if(!prec){
            *(bf16x8*)(Abuf + rbyte + c2) = r2; *(bf16x8*)(Abuf + rbyte + c3) = r3;
            *(bf16x8*)(Bbuf + rbyte + c2) = r6; *(bf16x8*)(Bbuf + rbyte + c3) = r7;
        }
        __syncthreads();
        if(k0 + 32 < KD){
            int kn = k0 + 32;
            r0 = *(const bf16x8*)(Aph + kn);     r1 = *(const bf16x8*)(Aph + kn + 8);
            r4 = *(const bf16x8*)(Bph + kn);     r5 = *(const bf16x8*)(Bph + kn + 8);
            if(!prec){
                r2 = *(const bf16x8*)(Apl + kn); r3 = *(const bf16x8*)(Apl + kn + 8);
                r6 = *(const bf16x8*)(Bpl + kn); r7 = *(const bf16x8*)(Bpl + kn + 8);
            }
        }
        bf16x8 afh[4], bfh[4];
        #pragma unroll
        for(int i=0;i<4;i++){
            int ar = wm + i*16 + l15;
            int abase = ar*128;
            afh[i] = *(const bf16x8*)(Abuf + abase + ((l4*16) ^ ((ar&7)<<4)));
            int br_ = wn + i*16 + l15;
            int bbase = br_*128;
            bfh[i] = *(const bf16x8*)(Bbuf + bbase + ((l4*16) ^ ((br_&7)<<4)));
        }
        #pragma unroll
        for(int i=0;i<4;i++)
            #pragma unroll
            for(int j=0;j<4;j++)
                acc[i][j] = __builtin_amdgcn_mfma_f32_16x16x32_bf16(afh[i], bfh[j], acc[i][j], 0,0,0);
        if(!prec){
            bf16x8 afl[4], bfl[4];
            #pragma unroll
            for(int i=0;i<4;i++){
                int ar = wm + i*16 + l15;
                int abase = ar*128;
                afl[i] = *(const bf16x8*)(Abuf + abase + ((64 + l4*16) ^ ((ar&7)<<4)));
                int br_ = wn + i*16 + l15;
                int bbase = br_*128;
                bfl[i] = *(const bf16x8*)(Bbuf + bbase + ((64 + l4*16) ^ ((br_&7)<<4)));
            }
            #pragma unroll
            for(int i=0;i<4;i++)
                #pragma unroll
                for(int j=0;j<4;j++){
                    acc[i][j] = __builtin_amdgcn_mfma_f32_16x16x32_bf16(afh[i], bfl[j], acc[i][j], 0,0,0);
                    acc[i][j] = __builtin_amdgcn_mfma_f32_16x16x32_bf16(afl[i], bfh[j], acc[i][j], 0,0,0);
                }
        }
    }
    // ---- coalesced epilogue via LDS restage ----
    const int mode = g.mode;
    float* Cb = g.C + br*g.strC;
    u16* Ohb = g.Oh + br*g.strO;
    u16* Olb = g.Ol + br*g.strO;
    const float* Xb = g.X + br*g.strX;
    float cx = 0.f;
    if(mode == 6){
        float g0 = 1.f/(1.f + expf(-g.skipp[0]));
        float g1 = 1.f/(1.f + expf(-g.skipp[2]));
        cx = 1.f - 0.5f*(g0 + g1);
    }
    float* LDSf = (float*)SBUF;
    const int lrow = tid >> 5;
    const int cc4 = (tid & 31)*4;
    #pragma unroll
    for(int half=0; half<2; half++){
        __syncthreads();
        if((wid>>1) == half){
            #pragma unroll
            for(int i=0;i<4;i++)
                #pragma unroll
                for(int j=0;j<4;j++)
                    #pragma unroll
                    for(int r=0;r<4;r++)
                        LDSf[(i*16 + l4*4 + r)*128 + wn + j*16 + l15] = acc[i][j][r];
        }
        __syncthreads();
        #pragma unroll
        for(int k=0;k<8;k++){
            int row = lrow + k*8;
            size_t o = (size_t)(m0 + half*64 + row)*DD + n0 + cc4;
            float4 v = *(const float4*)&LDSf[row*128 + cc4];
            float vv[4] = {v.x, v.y, v.z, v.w};
            if(mode==0){
                *(float4*)(Cb + o) = v;
            } else if(mode==4){
                u16x4 h4;
                #pragma unroll
                for(int j=0;j<4;j++) h4[j] = f2b(vv[j]);
                *(u16x4*)(Ohb + o) = h4;
            } else {   // mode 6
                float4 x = *(const float4*)(Xb + o);
                float xx[4] = {x.x, x.y, x.z, x.w};
                float4 cv;
                float* cvv = (float*)&cv;
                u16x4 h4, lo4;
                #pragma unroll
                for(int j=0;j<4;j++){
                    float v3 = vv[j] + cx*xx[j];
                    v3 = v3 > 0.f ? v3 : 0.f;
                    cvv[j] = v3;
                    u16 hh = f2b(v3); h4[j]=hh; lo4[j]=f2b(v3-b2f(hh));
                }
                *(float4*)(Cb + o) = cv;
                *(u16x4*)(Ohb + o) = h4;
                *(u16x4*)(Olb + o) = lo4;
            }
        }
    }
}

// ---------- combine ----------
__global__ void combine_all(const float* __restrict__ Wk, const float* __restrict__ Wv,
                            const float* __restrict__ Ra, const float* __restrict__ Rm,
                            float* __restrict__ wtk, float* __restrict__ wtv){
    const int st_tab[2][4] = {{0,1,0,0},{0,0,1,0}};
    int combo = blockIdx.y;
    int idx = combo >> 1, kv = combo & 1;
    int r = idx & 3, wb = idx >> 2, dir = wb & 1;
    int st = st_tab[dir][r];
    const float* W = (kv ? Wv : Wk) + (size_t)(wb*2 + st)*65536;
    const float* R = (kv ? Rm : Ra) + (size_t)idx*16384;
    float* o = (kv ? wtv : wtk) + (size_t)idx*65536;
    int d = blockIdx.x, c = threadIdx.x;
    int h = c >> 6, f = c & 63;
    const float* Wrow = W + d*DD + h*64;
    const float* Rh = R + h*4096 + f;
    float s = 0.f;
    #pragma unroll 8
    for(int k=0;k<64;k++) s += Wrow[k]*Rh[k*64];
    o[d*DD + c] = s;
}

// ---------------- CSR build, BOTH branches fused ----------------
__device__ inline void edge_decode(int e, int& r, int& el){
    if(e < EC){ r=0; el=e; }
    else if(e < EC+EI){ r=1; el=e-EC; }
    else if(e < EC+EI+EO){ r=2; el=e-(EC+EI); }
    else { r=3; el=e-(EC+EI+EO); }
}

struct CBB {
    const int* row[16]; const int* col[16];   // [br*8 + dir*4 + r]
    uint32_t* cnt; uint32_t* rowptr; uint32_t* einfo;
};

__global__ void csr_histB(CBB a){
    int brx = blockIdx.y;
    int ge = blockIdx.x*256 + threadIdx.x;
    if(ge >= 2*EHGT) return;
    int dir = ge >= EHGT;
    int e = ge - dir*EHGT;
    int r, el; edge_decode(e, r, el);
    int idx = brx*8 + dir*4 + r;
    int dtv = (dir==0) ? (r==2) : (r==1);
    int c = a.col[idx][el];
    int dst = dir*NROW + (dtv ? (NI + c) : c);
    atomicAdd(&a.cnt[(size_t)brx*2*NROW + dst], 1u);
}

__global__ __launch_bounds__(1024) void scan_rowptrB(uint32_t* cnt, uint32_t* rowptr){
    __shared__ uint32_t part[1024];
    int brx = blockIdx.x;
    uint32_t* cb = cnt + (size_t)brx*2*NROW;
    uint32_t* rp = rowptr + (size_t)brx*(2*NROW+1);
    int t = threadIdx.x;
    int base = t*24;
    uint32_t lpre[24];
    uint32_t sum = 0;
    #pragma unroll
    for(int i=0;i<24;i++){
        uint32_t c = cb[base+i];
        lpre[i] = sum; sum += c;
        cb[base+i] = 0;
    }
    part[t] = sum;
    __syncthreads();
    for(int offs=1; offs<1024; offs<<=1){
        uint32_t v = (t>=offs) ? part[t-offs] : 0u;
        __syncthreads();
        part[t] += v;
        __syncthreads();
    }
    uint32_t pre = (t==0) ? 0u : part[t-1];
    #pragma unroll
    for(int i=0;i<24;i++) rp[base+i] = pre + lpre[i];
    if(t==1023) rp[2*NROW] = part[1023];
}

__global__ void csr_scatterB(CBB a){
    int brx = blockIdx.y;
    int ge = blockIdx.x*256 + threadIdx.x;
    if(ge >= 2*EHGT) return;
    int dir = ge >= EHGT;
    int e = ge - dir*EHGT;
    int r, el; edge_decode(e, r, el);
    int idx = brx*8 + dir*4 + r;
    int dtv = (dir==0) ? (r==2) : (r==1);
    int stv = (dir==0) ? (r==1) : (r==2);
    int c = a.col[idx][el];
    int dst = dir*NROW + (dtv ? (NI + c) : c);
    int src = a.row[idx][el];
    uint32_t p = a.rowptr[(size_t)brx*(2*NROW+1) + dst] +
                 atomicAdd(&a.cnt[(size_t)brx*2*NROW + dst], 1u);
    uint32_t vmidx = (uint32_t)(r*NI + src);
    uint32_t hom = stv ? (uint32_t)(NI + src) : (uint32_t)src;
    a.einfo[(size_t)brx*2*EHGT + p] = vmidx | (hom << 16);
}

// ---------------- fused HGT edge phase, BOTH branches (one dir): wave per dst ----------------
__global__ __launch_bounds__(256) void hgt_fused(const uint32_t* __restrict__ rowptr,
                                                 const uint32_t* __restrict__ einfo,
                                                 const float* __restrict__ q_i,
                                                 const float* __restrict__ q_d,
                                                 const u16* __restrict__ ka,
                                                 const u16* __restrict__ vm,
                                                 const float* __restrict__ prel,
                                                 u16* __restrict__ bagg_h,
                                                 u16* __restrict__ bagg_l,
                                                 int dir){
    int wv = threadIdx.x >> 6, lane = threadIdx.x & 63;
    int bx = blockIdx.x;
    int brx = 0;
    if(bx >= (NROW/4)){ brx = 1; bx -= (NROW/4); }
    int rowi = bx*4 + wv;
    const uint32_t* rp = rowptr + (size_t)brx*(2*NROW+1) + (size_t)dir*NROW;
    uint32_t p0 = rp[rowi], p1 = rp[rowi+1];
    const uint32_t* ei = einfo + (size_t)brx*(2*EHGT);
    int h = lane >> 4;
    const float* qi = q_i + (size_t)brx*NI*DD;
    const float* qd = q_d + (size_t)brx*ND*DD;
    const u16* kad = ka + (size_t)brx*4*NI*DD;
    const u16* vmd = vm + (size_t)brx*4*NI*DD;
    const float* qrow = (rowi < NI) ? (qi + (size_t)rowi*DD) : (qd + (size_t)(rowi-NI)*DD);
    float4 q4 = *(const float4*)(qrow + lane*4);
    float pr0 = prel[0*HH+h]*0.125f, pr1 = prel[1*HH+h]*0.125f;
    float pr2 = prel[2*HH+h]*0.125f, pr3 = prel[3*HH+h]*0.125f;
    float m = -INFINITY, den = 0.f;
    float4 o4 = {0.f,0.f,0.f,0.f};
    for(uint32_t p = p0; p < p1; p++){
        uint32_t vmidx = ei[p] & 0xffffu;
        int r = vmidx >> 13;
        uint2 kr = *(const uint2*)(kad + (size_t)vmidx*DD + lane*4);
        uint2 vr = *(const uint2*)(vmd + (size_t)vmidx*DD + lane*4);
        float k0 = __uint_as_float(kr.x << 16), k1 = __uint_as_float(kr.x & 0xffff0000u);
        float k2 = __uint_as_float(kr.y << 16), k3 = __uint_as_float(kr.y & 0xffff0000u);
        float v0 = __uint_as_float(vr.x << 16), v1 = __uint_as_float(vr.x & 0xffff0000u);
        float v2 = __uint_as_float(vr.y << 16), v3 = __uint_as_float(vr.y & 0xffff0000u);
        float d = q4.x*k0 + q4.y*k1 + q4.z*k2 + q4.w*k3;
        d += __shfl_xor(d, 1); d += __shfl_xor(d, 2);
        d += __shfl_xor(d, 4); d += __shfl_xor(d, 8);
        float pf = (r==0) ? pr0 : (r==1) ? pr1 : (r==2) ? pr2 : pr3;
        float s = d * pf;
        float nm = fmaxf(m, s);
        float sc_ = expf(m - nm);
        float pe = expf(s - nm);
        den = den*sc_ + pe;
        o4.x = o4.x*sc_ + pe*v0;
        o4.y = o4.y*sc_ + pe*v1;
        o4.z = o4.z*sc_ + pe*v2;
        o4.w = o4.w*sc_ + pe*v3;
        m = nm;
    }
    float inv = 1.f/(den + 1e-16f);
    float vals[4] = {o4.x*inv, o4.y*inv, o4.z*inv, o4.w*inv};
    u16x4 h4, l4;
    #pragma unroll
    for(int j=0;j<4;j++){
        float g = gelu_f(vals[j]);
        u16 hh = f2b(g);
        h4[j] = hh;
        l4[j] = f2b(g - b2f(hh));
    }
    size_t ob = (size_t)brx*NROW*512 + (size_t)rowi*512 + dir*256 + lane*4;
    *(u16x4*)(bagg_h + ob) = h4;
    *(u16x4*)(bagg_l + ob) = l4;
}

// ---------------- pooling (branch via blockIdx.y) ----------------
__global__ void pool_h2(const float* __restrict__ x, const float* __restrict__ w, float* __restrict__ h){
    int brx = blockIdx.y;
    int node = blockIdx.x*4 + (threadIdx.x>>6);
    int lane = threadIdx.x & 63;
    const float* xr = x + (size_t)brx*((size_t)NROW*DD) + (size_t)node*DD;
    float s = 0.f;
    for(int j=lane;j<DD;j+=64) s += xr[j]*w[j];
    for(int m=32;m;m>>=1) s += __shfl_xor(s, m);
    if(lane==0) h[brx*NROW + node] = s;
}

__global__ __launch_bounds__(256) void pool_csr(const uint32_t* __restrict__ rowptr,
                                                const uint32_t* __restrict__ einfo,
                                                const float* __restrict__ h,
                                                const float* __restrict__ att,
                                                float* __restrict__ score){
    int brx = blockIdx.y;
    int w = blockIdx.x*4 + (threadIdx.x >> 6);
    int lane = threadIdx.x & 63;
    if(w >= NROW) return;
    const uint32_t* rp = rowptr + (size_t)brx*(2*NROW+1);
    const uint32_t* ei = einfo + (size_t)brx*(2*EHGT);
    const float* hb = h + (size_t)brx*NROW;
    uint32_t p0 = rp[w], p1 = rp[w+1];
    float a0 = att[0], a1 = att[1];
    float hn = hb[w];
    float es = a0*hn + a1*hn;
    es = es >= 0.f ? es : 0.2f*es;
    float m = -INFINITY;
    for(uint32_t p = p0+lane; p < p1; p += 64){
        float hs = hb[ei[p] >> 16];
        float e = a0*hs + a1*hn;
        e = e >= 0.f ? e : 0.2f*e;
        m = fmaxf(m, e);
    }
    #pragma unroll
    for(int s=32;s;s>>=1) m = fmaxf(m, __shfl_xor(m, s));
    m = fmaxf(m, es);
    float lden = 0.f, lnum = 0.f;
    for(uint32_t p = p0+lane; p < p1; p += 64){
        float hs = hb[ei[p] >> 16];
        float e = a0*hs + a1*hn;
        e = e >= 0.f ? e : 0.2f*e;
        float a = expf(e - m);
        lden += a; lnum += a*hs;
    }
    #pragma unroll
    for(int s=32;s;s>>=1){ lden += __shfl_xor(lden, s); lnum += __shfl_xor(lnum, s); }
    float aself = expf(es - m);
    lden += aself; lnum += aself*hn;
    if(lane==0) score[brx*NROW + w] = lnum/(lden + 1e-16f);
}

// ---------------- top-768 of 1536 per graph: wave-per-candidate rank (branch via z) ----------------
__global__ __launch_bounds__(256) void topk_rank(const float* __restrict__ score,
                                                 const float* __restrict__ bias,
                                                 int* __restrict__ sel_node,
                                                 float* __restrict__ sel_scale){
    int brx = blockIdx.z;
    int b = blockIdx.y;
    int wid = threadIdx.x >> 6, lane = threadIdx.x & 63;
    int i = blockIdx.x*4 + wid;
    const float* sc = score + (size_t)brx*NROW;
    int nodei = (i<1024) ? (b*1024 + i) : (NI + b*512 + (i-1024));
    float ki = sc[nodei];
    int r = 0;
    #pragma unroll
    for(int s=0;s<24;s++){
        int j = s*64 + lane;
        int nodej = (j<1024) ? (b*1024 + j) : (NI + b*512 + (j-1024));
        float kj = sc[nodej];
        r += (kj > ki) || (kj == ki && j < i);
    }
    #pragma unroll
    for(int m=32;m;m>>=1) r += __shfl_xor(r, m);
    if(lane==0 && r < KPOOL){
        sel_node[(size_t)brx*MR + b*KPOOL + r] = nodei;
        sel_scale[(size_t)brx*MR + b*KPOOL + r] = tanhf(ki + bias[0]);
    }
}

__global__ void gather_xp(const int* __restrict__ sel, const float* __restrict__ scale,
                          const float* __restrict__ x,
                          float* __restrict__ xp, u16* __restrict__ bh, u16* __restrict__ bl){
    int brx = blockIdx.y;
    int i = blockIdx.x*256 + threadIdx.x;
    int rowp = i >> 8, c = i & 255;
    int node = sel[(size_t)brx*MR + rowp];
    float s = scale[(size_t)brx*MR + rowp];
    float v = x[(size_t)brx*((size_t)NROW*DD) + (size_t)node*DD + c];
    float xv = v*s;
    size_t o = (size_t)brx*MRD + i;
    xp[o] = xv;
    u16 hh = f2b(xv);
    bh[o] = hh;
    bl[o] = f2b(xv - b2f(hh));
}

// ---------------- MFMA flash attention (branch via blockIdx.z) ----------------
__global__ __launch_bounds__(256) void attn_mfma(const u16* __restrict__ Qh0,
                                                 const u16* __restrict__ Kh0,
                                                 const u16* __restrict__ Vh0,
                                                 u16* __restrict__ aoh0, u16* __restrict__ aol0){
    __shared__ u16 KhS[64*64], VtS[64*64];
    char* KhB = (char*)KhS; char* VtB = (char*)VtS;
    size_t brof = (size_t)blockIdx.z*MRD;
    const u16* Qh = Qh0 + brof;
    const u16* Kh = Kh0 + brof;
    const u16* Vh = Vh0 + brof;
    u16* aoh = aoh0 + brof;
    u16* aol = aol0 + brof;
    int bh = blockIdx.x;
    int b = bh >> 2, h = bh & 3;
    int q0 = blockIdx.y * 64;
    int tid = threadIdx.x;
    int lane = tid & 63;
    int w = tid >> 6;
    int l15 = lane & 15, l4 = lane >> 4;
    size_t qrow = (size_t)(b*KPOOL + q0 + w*16 + l15);
    bf16x8 qh[2];
    #pragma unroll
    for(int c=0;c<2;c++)
        qh[c] = *(const bf16x8*)(Qh + qrow*DD + h*64 + c*32 + l4*8);
    float mreg = -INFINITY, lreg = 0.f;
    f32x4 O[4] = {};
    for(int k0=0;k0<KPOOL;k0+=64){
        __syncthreads();
        {
            int row = tid >> 2, q4 = tid & 3;
            size_t gbase = ((size_t)(b*KPOOL + k0 + row))*DD + h*64 + q4*16;
            bf16x8 k0v = *(const bf16x8*)(Kh + gbase);
            bf16x8 k1v = *(const bf16x8*)(Kh + gbase + 8);
            int sw = (row&7)<<4;
            int colb = q4*32;
            *(bf16x8*)(KhB + row*128 + (colb ^ sw))      = k0v;
            *(bf16x8*)(KhB + row*128 + ((colb+16) ^ sw)) = k1v;
            int row0 = (tid >> 3)*2, dhg = (tid & 7)*8;
            size_t vbase = ((size_t)(b*KPOOL + k0 + row0))*DD + h*64 + dhg;
            bf16x8 va = *(const bf16x8*)(Vh + vbase);
            bf16x8 vb = *(const bf16x8*)(Vh + vbase + DD);
            #pragma unroll
            for(int j=0;j<8;j++){
                int dh = dhg + j;
                uint32_t pk = (uint32_t)(u16)(short)va[j] | ((uint32_t)(u16)(short)vb[j] << 16);
                *(uint32_t*)(VtB + dh*128 + ((row0*2) ^ ((dh&7)<<4))) = pk;
            }
        }
        __syncthreads();
        f32x4 s[4] = {};
        #pragma unroll
        for(int t=0;t<4;t++){
            int arow = t*16 + l15;
            int sw = (arow&7)<<4;
            const char* bh_ = KhB + arow*128;
            bf16x8 kh0 = *(const bf16x8*)(bh_ + ((l4*16) ^ sw));
            bf16x8 kh1 = *(const bf16x8*)(bh_ + ((l4*16 + 64) ^ sw));
            s[t] = __builtin_amdgcn_mfma_f32_16x16x32_bf16(kh0, qh[0], s[t], 0,0,0);
            s[t] = __builtin_amdgcn_mfma_f32_16x16x32_bf16(kh1, qh[1], s[t], 0,0,0);
        }
        float cm = -INFINITY;
        #pragma unroll
        for(int t=0;t<4;t++)
            #pragma unroll
            for(int r=0;r<4;r++){ s[t][r] *= 0.125f; cm = fmaxf(cm, s[t][r]); }
        cm = fmaxf(cm, __shfl_xor(cm,16));
        cm = fmaxf(cm, __shfl_xor(cm,32));
        float nm = fmaxf(mreg, cm);
        float es = expf(mreg - nm);
        float ps = 0.f;
        #pragma unroll
        for(int t=0;t<4;t++)
            #pragma unroll
            for(int r=0;r<4;r++){ float pv = expf(s[t][r] - nm); s[t][r] = pv; ps += pv; }
        ps += __shfl_xor(ps,16);
        ps += __shfl_xor(ps,32);
        lreg = lreg*es + ps;
        mreg = nm;
        #pragma unroll
        for(int d=0;d<4;d++){ O[d][0]*=es; O[d][1]*=es; O[d][2]*=es; O[d][3]*=es; }
        #pragma unroll
        for(int c32=0;c32<2;c32++){
            bf16x8 pb;
            #pragma unroll
            for(int j=0;j<8;j++){
                int srcl = ((((lane>>4)*2 + (j>>2)) & 3) << 4) | l15;
                float v0 = __shfl(s[c32*2+0][j&3], srcl, 64);
                float v1 = __shfl(s[c32*2+1][j&3], srcl, 64);
                float v = (lane < 32) ? v0 : v1;
                pb[j] = (short)f2b(v);
            }
            #pragma unroll
            for(int dhb=0; dhb<4; dhb++){
                int vrow = dhb*16 + l15;
                bf16x8 va = *(const bf16x8*)(VtB + vrow*128 + ((c32*64 + l4*16) ^ ((vrow&7)<<4)));
                O[dhb] = __builtin_amdgcn_mfma_f32_16x16x32_bf16(va, pb, O[dhb], 0,0,0);
            }
        }
    }
    float inv = 1.f/lreg;
    #pragma unroll
    for(int dhb=0;dhb<4;dhb++)
        #pragma unroll
        for(int r=0;r<4;r++){
            float val = O[dhb][r]*inv;
            size_t o = qrow*DD + h*64 + dhb*16 + l4*4 + r;
            u16 hh = f2b(val);
            aoh[o] = hh;
            aol[o] = f2b(val - b2f(hh));
        }
}

// layernorm row kernel (branch via blockIdx.y)
__global__ __launch_bounds__(256) void ln_kernel(const float* __restrict__ xp, const float* __restrict__ o2,
                                                 const float* __restrict__ lg, const float* __restrict__ lb,
                                                 float* __restrict__ gatt){
    __shared__ float red[256];
    size_t brof = (size_t)blockIdx.y*MRD;
    int r = blockIdx.x, c = threadIdx.x;
    float y = xp[brof + (size_t)r*DD + c] + o2[brof + (size_t)r*DD + c];
    red[c] = y; __syncthreads();
    for(int s=128;s;s>>=1){ if(c<s) red[c] += red[c+s]; __syncthreads(); }
    float mu = red[0]*(1.f/DD);
    __syncthreads();
    float d = y - mu;
    red[c] = d*d; __syncthreads();
    for(int s=128;s;s>>=1){ if(c<s) red[c] += red[c+s]; __syncthreads(); }
    float var = red[0]*(1.f/DD);
    gatt[brof + (size_t)r*DD + c] = lg[c]*d/sqrtf(var+1e-5f) + lb[c];
}

__global__ void feat_reduce2(const float* __restrict__ xp, const float* __restrict__ gatt,
                             float* __restrict__ uv){
    int brx = blockIdx.z;
    int b = blockIdx.x, c = threadIdx.x;
    int j0 = blockIdx.y*64;
    size_t brof = (size_t)brx*MRD;
    float s1=0.f, s2=0.f;
    for(int j=j0;j<j0+64;j++){
        size_t basep = brof + ((size_t)(b*KPOOL + j))*DD + c;
        s1 += xp[basep];
        s2 += gatt[basep];
    }
    float* out = uv + (size_t)brx*BB*512;
    atomicAdd(&out[b*512 + c], s1);
    atomicAdd(&out[b*512 + 256 + c], s2);
}

__global__ void cosine_kernel(const float* __restrict__ u, const float* __restrict__ v,
                              float* __restrict__ out){
    int b = blockIdx.x, t = threadIdx.x;
    float du=0.f, nu=0.f, nv=0.f;
    for(int j=t;j<512;j+=64){
        float a = u[b*512+j], bb = v[b*512+j];
        du += a*bb; nu += a*a; nv += bb*bb;
    }
    for(int m=32;m;m>>=1){
        du += __shfl_xor(du,m); nu += __shfl_xor(nu,m); nv += __shfl_xor(nv,m);
    }
    if(t==0) out[b] = du / (fmaxf(sqrtf(nu),1e-8f)*fmaxf(sqrtf(nv),1e-8f));
}

// =======================================================================
extern "C" void kernel_launch(void* const* d_in, const int* in_sizes, int n_in,
                              void* d_out, int out_size, void* d_ws, size_t ws_size,
                              hipStream_t stream){
    (void)in_sizes; (void)n_in; (void)out_size; (void)ws_size;
    const float* hgt_Wk   = (const float*)d_in[12];
    const float* hgt_Wq   = (const float*)d_in[13];
    const float* hgt_Wv   = (const float*)d_in[14];
    const float* hgt_Wo   = (const float*)d_in[15];
    const float* hgt_arel = (const float*)d_in[16];
    const float* hgt_mrel = (const float*)d_in[17];
    const float* hgt_prel = (const float*)d_in[18];
    const float* hgt_skip = (const float*)d_in[19];
    const float* pool_W   = (const float*)d_in[20];
    const float* pool_att = (const float*)d_in[21];
    const float* pool_bias= (const float*)d_in[22];
    const float* t_wq     = (const float*)d_in[23];
    const float* t_wk     = (const float*)d_in[24];
    const float* t_wv     = (const float*)d_in[25];
    const float* t_wo     = (const float*)d_in[26];
    const float* ln_g     = (const float*)d_in[27];
    const float* ln_b     = (const float*)d_in[28];
    float* out = (float*)d_out;

    char* base = (char*)d_ws;
    size_t off = 0;
    auto allocb = [&](size_t nbytes)->void*{
        void* p = (void*)(base + off);
        off += ((nbytes + 255) & ~(size_t)255);
        return p;
    };
    const size_t MAT = 65536;
    const size_t BRN = (size_t)NROW*DD;       // per-branch node-feature elements
    // ---- persistent ----
    u16* bwtk_h = (u16*)allocb(16*MAT*2); u16* bwtk_l = (u16*)allocb(16*MAT*2);
    u16* bwtv_h = (u16*)allocb(16*MAT*2); u16* bwtv_l = (u16*)allocb(16*MAT*2);
    u16* bwq_h  = (u16*)allocb(8*MAT*2);  u16* bwq_l  = (u16*)allocb(8*MAT*2);
    u16* bwoc_h = (u16*)allocb(4*131072*2); u16* bwoc_l = (u16*)allocb(4*131072*2);
    u16* btw_h  = (u16*)allocb(4*MAT*2);  u16* btw_l  = (u16*)allocb(4*MAT*2);
    float* uv   = (float*)allocb((size_t)2*BB*512*4);
    float* ubuf = uv;
    float* vbuf = uv + BB*512;
    float* xa   = (float*)allocb(2*BRN*4);     // [br][NROW][DD]
    float* xcur = (float*)allocb(2*BRN*4);     // [br][NROW][DD]
    // ---- CSR (both branches) ----
    uint32_t* ccnt   = (uint32_t*)allocb((size_t)4*NROW*4);
    uint32_t* rowptr = (uint32_t*)allocb((size_t)2*(2*NROW+1)*4);
    uint32_t* einfo  = (uint32_t*)allocb((size_t)2*2*EHGT*4);
    size_t region = off;
    // ---- conv scratch ([br]...) ----
    float* q_i  = (float*)allocb((size_t)2*NI*DD*4);
    float* q_d  = (float*)allocb((size_t)2*ND*DD*4);
    u16* ka16 = (u16*)allocb((size_t)8*NI*DD*2);   // [br][r][NI][DD]; also combine f32 temp
    u16* vm16 = (u16*)allocb((size_t)8*NI*DD*2);
    u16* bcur_h = (u16*)allocb(2*BRN*2);
    u16* bcur_l = (u16*)allocb(2*BRN*2);
    u16* bagg_h = (u16*)allocb((size_t)2*NROW*512*2);
    u16* bagg_l = (u16*)allocb((size_t)2*NROW*512*2);
    // ---- pooling/transformer overlay ([br] everywhere) ----
    off = region;
    float* hvec = (float*)allocb((size_t)2*NROW*4);
    float* pscore = (float*)allocb((size_t)2*NROW*4);
    int* seln   = (int*)allocb((size_t)2*MR*4);
    float* sels = (float*)allocb((size_t)2*MR*4);
    float* xp   = (float*)allocb((size_t)2*MRD*4);
    float* o2   = (float*)allocb((size_t)2*MRD*4);
    float* gatt = (float*)allocb((size_t)2*MRD*4);
    u16* bxp_h = (u16*)allocb((size_t)2*MRD*2);
    u16* bxp_l = (u16*)allocb((size_t)2*MRD*2);
    u16* qbh = (u16*)allocb((size_t)2*MRD*2);
    u16* kbh = (u16*)allocb((size_t)2*MRD*2);
    u16* vbh = (u16*)allocb((size_t)2*MRD*2);
    u16* bao_h = (u16*)allocb((size_t)2*MRD*2);
    u16* bao_l = (u16*)allocb((size_t)2*MRD*2);

    const int st_tab[2][4] = {{0,1,0,0},{0,0,1,0}};

    fill_u32<<<(2*BB*512+255)/256,256,0,stream>>>((uint32_t*)uv, 0u, 2*BB*512);
    float* wtkF = (float*)ka16;
    float* wtvF = (float*)ka16 + 16*MAT;
    combine_all<<<dim3(256,32),256,0,stream>>>(hgt_Wk, hgt_Wv, hgt_arel, hgt_mrel, wtkF, wtvF);
    WCArgs wc;
    wc.in[0]=wtkF;   wc.oh[0]=bwtk_h; wc.ol[0]=bwtk_l; wc.cnt[0]=16;
    wc.in[1]=wtvF;   wc.oh[1]=bwtv_h; wc.ol[1]=bwtv_l; wc.cnt[1]=16;
    wc.in[2]=hgt_Wq; wc.oh[2]=bwq_h;  wc.ol[2]=bwq_l;  wc.cnt[2]=8;
    wc.in[3]=t_wq;   wc.oh[3]=btw_h;          wc.ol[3]=btw_l;          wc.cnt[3]=1;
    wc.in[4]=t_wk;   wc.oh[4]=btw_h+1*MAT;    wc.ol[4]=btw_l+1*MAT;    wc.cnt[4]=1;
    wc.in[5]=t_wv;   wc.oh[5]=btw_h+2*MAT;    wc.ol[5]=btw_l+2*MAT;    wc.cnt[5]=1;
    wc.in[6]=t_wo;   wc.oh[6]=btw_h+3*MAT;    wc.ol[6]=btw_l+3*MAT;    wc.cnt[6]=1;
    wc.nr = 7;
    wcvt_split<<<dim3(256,44),256,0,stream>>>(wc);
    wcvt_wo<<<dim3(256,4),256,0,stream>>>(hgt_Wo, hgt_skip, bwoc_h, bwoc_l);

    // ---- CSR build + activation convert, both branches fused ----
    {
        CBB cb;
        for(int bi=0;bi<2;bi++){
            int ib = bi*6;
            const int* ecp = (const int*)d_in[ib+2];
            const int* eip = (const int*)d_in[ib+3];
            const int* eop = (const int*)d_in[ib+4];
            const int* ekp = (const int*)d_in[ib+5];
            const int* rows_f[4] = {ecp, eip, eop, ekp};
            const int* cols_f[4] = {ecp+EC, eip+EI, eop+EO, ekp+EK};
            for(int r=0;r<4;r++){
                cb.row[bi*8 + r]     = rows_f[r]; cb.col[bi*8 + r]     = cols_f[r];
                cb.row[bi*8 + 4 + r] = cols_f[r]; cb.col[bi*8 + 4 + r] = rows_f[r];
            }
        }
        cb.cnt = ccnt; cb.rowptr = rowptr; cb.einfo = einfo;
        fill_u32<<<(4*NROW+255)/256,256,0,stream>>>(ccnt, 0u, 4*NROW);
        csr_histB<<<dim3((2*EHGT+255)/256,2),256,0,stream>>>(cb);
        scan_rowptrB<<<2,1024,0,stream>>>(ccnt, rowptr);
        csr_scatterB<<<dim3((2*EHGT+255)/256,2),256,0,stream>>>(cb);
        cvt_split2<<<dim3(((NROW*DD/4)+255)/256,2),256,0,stream>>>(
            (const float*)d_in[0], (const float*)d_in[1],
            (const float*)d_in[6], (const float*)d_in[7],
            bcur_h, bcur_l, xcur);
    }

    // ---- branch-fused layer loop (mega per dir) ----
    for(int l=0;l<LL;l++){
        float* curX = (l==0) ? xcur : xa;
        float* nxtX = (l==0) ? xa : xcur;

        for(int dir=0;dir<2;dir++){
            int wb = l*2 + dir;
            GArgs g1; int nb1 = 0, ndx = 0;
            auto addg = [&](int srctype, const u16* Bh, const u16* Bl, float* Cm, u16* Om,
                            size_t strC, size_t strO, int M, int mode, int prec){
                GDesc& d = g1.d[ndx];
                size_t ao = srctype ? (size_t)NI*DD : 0;
                d.Ah = bcur_h + ao; d.Al = bcur_l + ao;
                d.Bh = Bh; d.Bl = Bl; d.C = Cm;
                d.Oh = Om; d.Ol = nullptr; d.X = nullptr; d.skipp = nullptr;
                d.strA = BRN; d.strC = strC; d.strO = strO; d.strX = 0;
                d.mblks = M/128; d.mode = mode; d.prec = prec; d.kdim = 256;
                nb1 += M/128; ndx++;
            };
            addg(0, bwq_h + (size_t)(wb*2+0)*MAT, bwq_l + (size_t)(wb*2+0)*MAT,
                 q_i, nullptr, (size_t)NI*DD, 0, NI, 0, 0);
            addg(1, bwq_h + (size_t)(wb*2+1)*MAT, bwq_l + (size_t)(wb*2+1)*MAT,
                 q_d, nullptr, (size_t)ND*DD, 0, ND, 0, 0);
            for(int r=0;r<4;r++){
                int st = st_tab[dir][r];
                addg(st, bwtk_h + (size_t)(wb*4+r)*MAT, bwtk_l + (size_t)(wb*4+r)*MAT,
                     nullptr, ka16 + (size_t)r*NI*DD, 0, (size_t)4*NI*DD, st ? ND : NI, 4, 1);
            }
            for(int r=0;r<4;r++){
                int st = st_tab[dir][r];
                addg(st, bwtv_h + (size_t)(wb*4+r)*MAT, bwtv_l + (size_t)(wb*4+r)*MAT,
                     nullptr, vm16 + (size_t)r*NI*DD, 0, (size_t)4*NI*DD, st ? ND : NI, 4, 1);
            }
            g1.nd = ndx;
            gemm_mfma<<<dim3(nb1,2,2),256,0,stream>>>(g1);

            hgt_fused<<<2*(NROW/4),256,0,stream>>>(rowptr, einfo,
                q_i, q_d, ka16, vm16, hgt_prel + (size_t)wb*4*HH, bagg_h, bagg_l, dir);
        }

        GArgs g3; g3.nd = 2;
        for(int t=0;t<2;t++){
            GDesc& d = g3.d[t];
            size_t ao = t ? (size_t)NI*DD : 0;
            d.Ah = bagg_h + (t ? (size_t)NI*512 : 0);
            d.Al = bagg_l + (t ? (size_t)NI*512 : 0);
            d.Bh = bwoc_h + (size_t)(l*2+t)*131072;
            d.Bl = bwoc_l + (size_t)(l*2+t)*131072;
            d.C = nxtX + ao;
            d.Oh = bcur_h + ao;
            d.Ol = bcur_l + ao;
            d.X = curX + ao;
            d.skipp = hgt_skip + l*4 + t;
            d.strA = (size_t)NROW*512; d.strC = BRN; d.strO = BRN; d.strX = BRN;
            d.mblks = (t ? ND : NI)/128;
            d.mode = 6; d.prec = 0; d.kdim = 512;
        }
        gemm_mfma<<<dim3(NI/128 + ND/128,2,2),256,0,stream>>>(g3);
    }

    // ---- branch-fused pooling + transformer tail ----
    pool_h2<<<dim3(NROW/4,2),256,0,stream>>>(xcur, pool_W, hvec);
    pool_csr<<<dim3(NROW/4,2),256,0,stream>>>(rowptr, einfo, hvec, pool_att, pscore);
    topk_rank<<<dim3(384,BB,2),256,0,stream>>>(pscore, pool_bias, seln, sels);
    gather_xp<<<dim3(MR,2),256,0,stream>>>(seln, sels, xcur, xp, bxp_h, bxp_l);

    GArgs g4; g4.nd = 3;
    for(int t=0;t<3;t++){
        GDesc& d = g4.d[t];
        d.Ah=bxp_h; d.Al=bxp_l;
        d.Bh=btw_h + (size_t)t*MAT; d.Bl=btw_l + (size_t)t*MAT;
        d.C = nullptr;
        d.Oh = (t==0)? qbh : (t==1)? kbh : vbh;
        d.Ol = nullptr;
        d.X = nullptr; d.skipp = nullptr;
        d.strA=MRD; d.strC=0; d.strO=MRD; d.strX=0;
        d.mblks = MR/128; d.mode = 4; d.prec = 0; d.kdim = 256;
    }
    gemm_mfma<<<dim3(3*(MR/128),2,2),256,0,stream>>>(g4);
    attn_mfma<<<dim3(BB*HH, KPOOL/64, 2),256,0,stream>>>(qbh, kbh, vbh, bao_h, bao_l);
    GArgs g5; g5.nd = 1;
    {
        GDesc& d = g5.d[0];
        d.Ah=bao_h; d.Al=bao_l;
        d.Bh=btw_h + (size_t)3*MAT; d.Bl=btw_l + (size_t)3*MAT;
        d.C=o2; d.Oh=nullptr; d.Ol=nullptr; d.X=nullptr; d.skipp=nullptr;
        d.strA=MRD; d.strC=MRD; d.strO=0; d.strX=0;
        d.mblks=MR/128; d.mode=0; d.prec=0; d.kdim=256;
    }
    gemm_mfma<<<dim3(MR/128,2,2),256,0,stream>>>(g5);
    ln_kernel<<<dim3(MR,2),256,0,stream>>>(xp, o2, ln_g, ln_b, gatt);
    feat_reduce2<<<dim3(BB,12,2),256,0,stream>>>(xp, gatt, uv);

    cosine_kernel<<<BB,64,0,stream>>>(ubuf, vbuf, out);
}